// Round 9
// baseline (487.270 us; speedup 1.0000x reference)
//
#include <hip/hip_runtime.h>
#include <hip/hip_bf16.h>
#include <math.h>

#define BB 16
#define LL 512
#define HH 256
#define NHEAD 8
#define HDIM 32
#define LP1 513
#define NHHD 256
#define NODES_ELEMS (BB*LL*HH)

typedef __attribute__((ext_vector_type(8))) short bf16x8;
typedef __attribute__((ext_vector_type(4))) float f32x4;

__device__ __forceinline__ unsigned short f2bf(float f) {
  union { float f; unsigned u; } x; x.f = f;
  unsigned r = x.u + 0x7fffu + ((x.u >> 16) & 1u);
  return (unsigned short)(r >> 16);
}
__device__ __forceinline__ float bf2f(unsigned short u) {
  union { unsigned u; float f; } x; x.u = (unsigned)u << 16; return x.f;
}

// ---------------------------------------------------------------------------
// fused: nodes = data (fp32) ; datab = bf16(data)
__global__ __launch_bounds__(256) void copy_cvt_kernel(const float* __restrict__ data,
                                                       float* __restrict__ nodes,
                                                       unsigned short* __restrict__ datab) {
  int idx = blockIdx.x * 1024 + threadIdx.x;
#pragma unroll
  for (int u = 0; u < 4; u++) {
    float v = data[idx];
    nodes[idx] = v;
    datab[idx] = f2bf(v);
    idx += 256;
  }
}

// 4 weight transposes in one launch: {sq0, sq1, so0, so1}
__global__ __launch_bounds__(256) void transpose4_kernel(const float* __restrict__ sq_w,
                                                         const float* __restrict__ so_w,
                                                         float* __restrict__ sqT,
                                                         float* __restrict__ soT) {
  int which = blockIdx.y;
  const float* in = (which < 2) ? sq_w + which * 65536 : so_w + (which - 2) * 65536;
  float* out = (which < 2) ? sqT + which * 65536 : soT + (which - 2) * 65536;
  int idx = blockIdx.x * 256 + threadIdx.x;
  int r = idx >> 8, c = idx & 255;
  out[c * 256 + r] = in[idx];
}

// merged elementwise preps: fcwT (256 blk) | bcat_m2 (256 blk) | sk cvt (512 blk)
__global__ __launch_bounds__(256) void prep_misc_kernel(const float* __restrict__ fc_w,
                                                        const float* __restrict__ fcw,
                                                        const float* __restrict__ sk_w,
                                                        unsigned short* __restrict__ fcwT,
                                                        unsigned short* __restrict__ Bcat,
                                                        unsigned short* __restrict__ skwb) {
  int blk = blockIdx.x;
  int t = threadIdx.x;
  if (blk < 256) {
    int idx = blk * 256 + t;           // o*256 + k
    int o = idx >> 8, k = idx & 255;
    fcwT[idx] = f2bf(fc_w[k * 256 + o]);
  } else if (blk < 512) {
    int idx = (blk - 256) * 256 + t;   // n*8192 + d*256 + c
    int n = idx >> 13, d = (idx >> 8) & 31, c = idx & 255;
    Bcat[((size_t)n * 32 + d) * 512 + 256 + c] =
        f2bf(fcw[((size_t)n * 768 + 256 + 2 * c) * 32 + d]);
  } else {
    int idx = (blk - 512) * 256 + t;
    skwb[idx] = f2bf(sk_w[idx]);
  }
}

// edge -> packed bits
__global__ __launch_bounds__(256) void edge_pack_kernel(const int* __restrict__ edge,
                                                        unsigned char* __restrict__ ep) {
  int row = blockIdx.x * 4 + (threadIdx.x >> 6);
  int lane = threadIdx.x & 63;
  const int* adj = edge + ((size_t)row << 9);
  unsigned v = 0;
#pragma unroll
  for (int u = 0; u < 8; u++) v |= (adj[lane + 64 * u] > 0 ? 1u : 0u) << u;
  ep[((size_t)row << 6) + lane] = (unsigned char)v;
}

// Bcat M1: Bcat[(n*32+d)*512 + k] = sum_c WQw[n][c][k] * Fw[n][c][d]
__global__ __launch_bounds__(256) void bcat_m1_kernel(const float* __restrict__ WQw,
                                                      const float* __restrict__ fcw,
                                                      unsigned short* __restrict__ Bcat) {
  __shared__ float wq_s[256][16];
  __shared__ float fw_s[256][32];
  int n = blockIdx.x >> 4, kt = blockIdx.x & 15;
  int t = threadIdx.x;
#pragma unroll
  for (int i = 0; i < 16; i++) {
    int c = i * 16 + (t >> 4), kk = t & 15;
    wq_s[c][kk] = WQw[(size_t)n * 65536 + c * 256 + kt * 16 + kk];
  }
#pragma unroll
  for (int i = 0; i < 32; i++) {
    int idx = i * 256 + t;
    fw_s[idx >> 5][idx & 31] = fcw[(size_t)n * 24576 + idx];
  }
  __syncthreads();
  int kloc = t >> 4, dp = t & 15;
  float a0 = 0.f, a1v = 0.f;
  for (int c = 0; c < 256; c++) {
    float wv = wq_s[c][kloc];
    a0 = fmaf(wv, fw_s[c][dp * 2], a0);
    a1v = fmaf(wv, fw_s[c][dp * 2 + 1], a1v);
  }
  int k = kt * 16 + kloc;
  Bcat[((size_t)n * 32 + dp * 2) * 512 + k] = f2bf(a0);
  Bcat[((size_t)n * 32 + dp * 2 + 1) * 512 + k] = f2bf(a1v);
}

// w1/w2/c1/c2 folded attention weights + bqf, one block per head
__global__ __launch_bounds__(256) void w12bqf_kernel(const float* __restrict__ WQw,
                                                     const float* __restrict__ WQb,
                                                     const float* __restrict__ a1,
                                                     const float* __restrict__ a2,
                                                     const float* __restrict__ fcw,
                                                     float* __restrict__ w1,
                                                     float* __restrict__ w2,
                                                     float* __restrict__ c1,
                                                     float* __restrict__ c2,
                                                     float* __restrict__ bqf) {
  int n = blockIdx.x, t = threadIdx.x;
  float s1 = 0.f, s2 = 0.f;
  for (int c = 0; c < 256; c++) {
    float wv = WQw[((size_t)(n * 256 + c)) * 256 + t];
    s1 = fmaf(a1[n * 768 + c], wv, s1);
    s2 = fmaf(a2[n * 768 + c], wv, s2);
  }
  w1[n * 256 + t] = s1;
  w2[n * 256 + t] = s2;
  if (t < 32) {
    float s = 0.f;
    for (int c = 0; c < 256; c++)
      s = fmaf(WQb[n * 256 + c], fcw[((size_t)n * 768 + c) * 32 + t], s);
    bqf[n * 32 + t] = s;
  }
  __shared__ float r1[256], r2[256];
  r1[t] = a1[n * 768 + t] * WQb[n * 256 + t];
  r2[t] = a2[n * 768 + t] * WQb[n * 256 + t];
  __syncthreads();
  for (int o = 128; o; o >>= 1) {
    if (t < o) { r1[t] += r1[t + o]; r2[t] += r2[t + o]; }
    __syncthreads();
  }
  if (t == 0) { c1[n] = r1[0]; c2[n] = r2[0]; }
}

// ---------------------------------------------------------------------------
// relay mean, phase 1
__global__ __launch_bounds__(256) void relay_part_kernel(const float* __restrict__ data,
                                                         float* __restrict__ part) {
  int b = blockIdx.x >> 3, ch = blockIdx.x & 7;
  int t = threadIdx.x;
  float s = 0.f;
  const float* p = data + ((size_t)b * 512 + ch * 64) * 256 + t;
  for (int l = 0; l < 64; l++) s += p[(size_t)l * 256];
  part[(size_t)blockIdx.x * 256 + t] = s;
}

// relay mean, phase 2: relay fp32 + ktb relay row for it=0
__global__ __launch_bounds__(256) void relay_fin_kernel(const float* __restrict__ part,
                                                        const unsigned short* __restrict__ skw0,
                                                        const float* __restrict__ skb0,
                                                        float* __restrict__ relay,
                                                        unsigned short* __restrict__ ktb) {
  __shared__ float rel[256];
  int b = blockIdx.x, t = threadIdx.x;
  float s = 0.f;
#pragma unroll
  for (int ch = 0; ch < 8; ch++) s += part[((size_t)(b * 8 + ch)) * 256 + t];
  s *= (1.0f / 512.0f);
  relay[b * 256 + t] = s;
  rel[t] = s;
  __syncthreads();
  float acc = 0.f;
  for (int k = 0; k < 256; k++) acc = fmaf(rel[k], bf2f(skw0[(size_t)t * 256 + k]), acc);
  ktb[((size_t)b * LP1) * 256 + t] = f2bf(acc + skb0[t]);
}

// rarf: ra1/ra2 + rf(+fcb+bqf)
__global__ __launch_bounds__(256) void rarf_kernel(const float* __restrict__ relay,
                                                   const float* __restrict__ a1,
                                                   const float* __restrict__ a2,
                                                   const float* __restrict__ fcw,
                                                   const float* __restrict__ fcb,
                                                   const float* __restrict__ bqf,
                                                   float* __restrict__ ra1,
                                                   float* __restrict__ ra2,
                                                   float* __restrict__ rf) {
  int n = blockIdx.x >> 4, b = blockIdx.x & 15;
  int t = threadIdx.x;
  int lane = t & 63, w = t >> 6;
  __shared__ float rel[256];
  __shared__ float red1[4], red2[4];
  __shared__ float pf_s[8][33];
  rel[t] = relay[b * HH + t];
  __syncthreads();
  float p1 = rel[t] * a1[n * 768 + 257 + 2 * t];
  float p2 = rel[t] * a2[n * 768 + 257 + 2 * t];
#pragma unroll
  for (int o = 32; o; o >>= 1) { p1 += __shfl_xor(p1, o); p2 += __shfl_xor(p2, o); }
  if (lane == 0) { red1[w] = p1; red2[w] = p2; }
  int d = t & 31, seg = t >> 5;
  float pf = 0.f;
  for (int u = 0; u < 32; u++) {
    int k = seg * 32 + u;
    pf = fmaf(rel[k], fcw[((size_t)n * 768 + 257 + 2 * k) * 32 + d], pf);
  }
  pf_s[seg][d] = pf;
  __syncthreads();
  if (t == 0) {
    ra1[n * 16 + b] = red1[0] + red1[1] + red1[2] + red1[3];
    ra2[n * 16 + b] = red2[0] + red2[1] + red2[2] + red2[3];
  }
  if (t < 32) {
    float s = 0.f;
    for (int gg = 0; gg < 8; gg++) s += pf_s[gg][t];
    rf[((size_t)n * 16 + b) * 32 + t] = s + fcb[n * 32 + t] + bqf[n * 32 + t];
  }
}

// ---------------------------------------------------------------------------
// Fused LayerNorm + ei/ej; 16 reduction chains batched for ILP
__global__ __launch_bounds__(256) void lnei_kernel(const float* __restrict__ nodes,
                                                   const float* __restrict__ data,
                                                   const float* __restrict__ g,
                                                   const float* __restrict__ bb,
                                                   const float* __restrict__ w1,
                                                   const float* __restrict__ w2,
                                                   const float* __restrict__ a1,
                                                   const float* __restrict__ a2,
                                                   const float* __restrict__ c1,
                                                   const float* __restrict__ c2,
                                                   const float* __restrict__ ra1,
                                                   const float* __restrict__ ra2,
                                                   unsigned short* __restrict__ xnb,
                                                   float* __restrict__ ei,
                                                   float* __restrict__ ej) {
  int r = blockIdx.x * 4 + (threadIdx.x >> 6);
  int b = r >> 9;
  int lane = threadIdx.x & 63;
  float x[4], dv[4];
#pragma unroll
  for (int u = 0; u < 4; u++) {
    int c = lane + 64 * u;
    x[u] = nodes[(size_t)r * 256 + c];
    dv[u] = data[(size_t)r * 256 + c];
  }
  float s = x[0] + x[1] + x[2] + x[3];
#pragma unroll
  for (int o = 32; o; o >>= 1) s += __shfl_xor(s, o);
  float mean = s * (1.0f / 256.0f);
  float v = 0.f;
#pragma unroll
  for (int u = 0; u < 4; u++) { x[u] -= mean; v = fmaf(x[u], x[u], v); }
#pragma unroll
  for (int o = 32; o; o >>= 1) v += __shfl_xor(v, o);
  float rstd = rsqrtf(v * (1.0f / 256.0f) + 1e-5f);
  float xv[4];
#pragma unroll
  for (int u = 0; u < 4; u++) {
    int c = lane + 64 * u;
    xv[u] = x[u] * rstd * g[c] + bb[c];
    xnb[(size_t)r * 256 + c] = f2bf(xv[u]);
  }
  float s1a[8], s2a[8];
#pragma unroll
  for (int n = 0; n < 8; n++) {
    float s1 = 0.f, s2 = 0.f;
#pragma unroll
    for (int u = 0; u < 4; u++) {
      int c = lane + 64 * u;
      s1 = fmaf(xv[u], w1[n * 256 + c], s1);
      s1 = fmaf(dv[u], a1[n * 768 + 256 + 2 * c], s1);
      s2 = fmaf(xv[u], w2[n * 256 + c], s2);
      s2 = fmaf(dv[u], a2[n * 768 + 256 + 2 * c], s2);
    }
    s1a[n] = s1; s2a[n] = s2;
  }
#pragma unroll
  for (int o = 32; o; o >>= 1) {
#pragma unroll
    for (int n = 0; n < 8; n++) {
      s1a[n] += __shfl_xor(s1a[n], o);
      s2a[n] += __shfl_xor(s2a[n], o);
    }
  }
  if (lane == 0) {
#pragma unroll
    for (int n = 0; n < 8; n++) {
      ei[n * 8192 + r] = s1a[n] + c1[n] + ra1[n * 16 + b];
      ej[n * 8192 + r] = s2a[n] + c2[n] + ra2[n * 16 + b];
    }
  }
}

// ---------------------------------------------------------------------------
// G-GEMM: GT[n][b][d][j] = [xn ; data](row j) @ Bcat col (n*32+d)
__global__ __launch_bounds__(256) void g_gemm_kernel(
    const unsigned short* __restrict__ A1, const unsigned short* __restrict__ A2,
    const unsigned short* __restrict__ Bcat, unsigned short* __restrict__ GT) {
  int tileN = blockIdx.x * 64;
  int tileM = blockIdx.y * 128;
  int t = threadIdx.x;
  int wv = t >> 6, lane = t & 63;
  int lo = lane & 15, quad = lane >> 4;
  int rowBase0 = tileM + wv * 32;
  const unsigned short* ap1[2];
  const unsigned short* ap2[2];
#pragma unroll
  for (int rt = 0; rt < 2; rt++) {
    int arow = rowBase0 + rt * 16 + lo;
    ap1[rt] = A1 + (size_t)arow * 256 + quad * 8;
    ap2[rt] = A2 + (size_t)arow * 256 + quad * 8;
  }
  f32x4 acc[2][4] = {};
  for (int k0 = 0; k0 < 512; k0 += 32) {
    bf16x8 af[2];
#pragma unroll
    for (int rt = 0; rt < 2; rt++)
      af[rt] = (k0 < 256) ? *(const bf16x8*)(ap1[rt] + k0)
                          : *(const bf16x8*)(ap2[rt] + k0 - 256);
#pragma unroll
    for (int ct = 0; ct < 4; ct++) {
      bf16x8 bf_ = *(const bf16x8*)(Bcat + (size_t)(tileN + ct * 16 + lo) * 512 + k0 + quad * 8);
#pragma unroll
      for (int rt = 0; rt < 2; rt++)
        acc[rt][ct] = __builtin_amdgcn_mfma_f32_16x16x32_bf16(af[rt], bf_, acc[rt][ct], 0, 0, 0);
    }
  }
#pragma unroll
  for (int rt = 0; rt < 2; rt++) {
#pragma unroll
    for (int ct = 0; ct < 4; ct++) {
      int co = tileN + ct * 16 + lo;
      int n = co >> 5, d = co & 31;
      int jrow = rowBase0 + rt * 16 + quad * 4;
      int b2 = jrow >> 9, jj = jrow & 511;
      ushort4 pk;
      pk.x = f2bf(acc[rt][ct][0]);
      pk.y = f2bf(acc[rt][ct][1]);
      pk.z = f2bf(acc[rt][ct][2]);
      pk.w = f2bf(acc[rt][ct][3]);
      *(ushort4*)&GT[(((size_t)(n * 16 + b2) * 32 + d) << 9) + jj] = pk;
    }
  }
}

// ---------------------------------------------------------------------------
// MEGA: GAT softmax+aggregation (8 heads) -> fc GEMM (nodes) -> kt GEMM (ktb)
// block = (b, 32-row group): 256 blocks, 256 threads / 4 waves
__global__ __launch_bounds__(256) void gat_fc_kt_kernel(
    const unsigned short* __restrict__ GT,    // [8][16][32][512] bf16
    const float* __restrict__ ei, const float* __restrict__ ej,
    const unsigned char* __restrict__ ep,     // [8192][64] packed adj bits
    const float* __restrict__ rf,             // rf + fcb + bqf folded
    const unsigned short* __restrict__ fcwT,  // [256 o][256 k] bf16
    const float* __restrict__ fc_b,
    const unsigned short* __restrict__ skw_it,// [256 o][256 k] bf16
    const float* __restrict__ skb_it,
    const int* __restrict__ mask,
    float* __restrict__ nodes,                // resid in/out
    unsigned short* __restrict__ ktb) {       // [B*513][256] bf16
  __shared__ unsigned short W[32][512];       // softmax weights (XOR-swizzled)
  __shared__ unsigned short tmp[32][264];     // padded: stride 528B -> 2-way (free)
  __shared__ float denom_s[32];
  int blk = blockIdx.x;
  int b = blk >> 4;
  int i0 = (blk & 15) << 5;
  int t = threadIdx.x;
  int wv = t >> 6, lane = t & 63;
  int lo = lane & 15, quad = lane >> 4;
  int rt = wv >> 1, dh = wv & 1;

  // packed adjacency for this wave's 8 rows (reused across 8 heads)
  unsigned pb[8];
#pragma unroll
  for (int rr = 0; rr < 8; rr++)
    pb[rr] = ep[(((size_t)(b * 512 + i0 + wv * 8 + rr)) << 6) + lane];

  bf16x8 bones;
  {
    short ov = (lo == 0) ? (short)0x3F80 : (short)0;
#pragma unroll
    for (int j = 0; j < 8; j++) bones[j] = ov;
  }
  int arow = rt * 16 + lo;
  int rxB = arow & 7;

  for (int n = 0; n < 8; n++) {
    // Phase A: unnormalized softmax weights (reduction-free)
    const float* ejrow = ej + n * 8192 + b * 512;
    float ejv[8];
#pragma unroll
    for (int u = 0; u < 8; u++) ejv[u] = ejrow[lane + 64 * u];
    float mm = ejv[0];
#pragma unroll
    for (int u = 1; u < 8; u++) mm = fmaxf(mm, ejv[u]);
#pragma unroll
    for (int o = 32; o; o >>= 1) mm = fmaxf(mm, __shfl_xor(mm, o));
#pragma unroll
    for (int rr = 0; rr < 8; rr++) {
      int row = wv * 8 + rr;
      float eiv = ei[n * 8192 + b * 512 + i0 + row];
      float M = eiv + mm;
      M = M > 0.f ? M : 0.2f * M;
      unsigned pbv = pb[rr];
      int rx = (row & 7) << 3;
#pragma unroll
      for (int u = 0; u < 8; u++) {
        float e = eiv + ejv[u];
        e = e > 0.f ? e : 0.2f * e;
        float w = ((pbv >> u) & 1) ? __expf(e - M) : 0.f;
        int col = lane + 64 * u;
        W[row][((col >> 3 << 3) ^ rx) + (col & 7)] = f2bf(w);
      }
    }
    __syncthreads();
    // Phase B: MFMA W @ GT (+ ones-column denominator on dh==0 waves)
    const unsigned short* gtb = GT + (((size_t)(n * 16 + b) * 32) << 9);
    f32x4 acc = {}, accd = {};
    for (int k0 = 0; k0 < 512; k0 += 32) {
      int chunk = (k0 >> 3) + quad;
      bf16x8 a0 = *(const bf16x8*)&W[arow][(chunk ^ rxB) << 3];
      bf16x8 bf_ = *(const bf16x8*)(gtb + (((size_t)(dh * 16 + lo)) << 9) + k0 + quad * 8);
      acc = __builtin_amdgcn_mfma_f32_16x16x32_bf16(a0, bf_, acc, 0, 0, 0);
      if (dh == 0)
        accd = __builtin_amdgcn_mfma_f32_16x16x32_bf16(a0, bones, accd, 0, 0, 0);
    }
    if (dh == 0 && lo == 0) {
#pragma unroll
      for (int r = 0; r < 4; r++) denom_s[rt * 16 + quad * 4 + r] = accd[r];
    }
    __syncthreads();   // W reads done (safe to rewrite next head) + denom visible
    int d = dh * 16 + lo;
    float base = rf[((size_t)n * 16 + b) * 32 + d];
#pragma unroll
    for (int r = 0; r < 4; r++) {
      int row = rt * 16 + quad * 4 + r;
      float inv = 1.0f / fmaxf(denom_s[row], 1e-35f);
      float v = acc[r] * inv + base;
      v = v > 0.f ? v : expm1f(v);
      tmp[row][n * 32 + d] = f2bf(v);
    }
  }
  __syncthreads();   // tmp[32][256] complete

  // ---- fc GEMM: out = mask ? nodes + lrelu(tmp @ fc_w + fc_b) : 0
  int ch = wv >> 1, rt2 = wv & 1;   // wave = (col-half, row-tile)
  f32x4 facc[8] = {};
  for (int k0 = 0; k0 < 256; k0 += 32) {
    bf16x8 a0 = *(const bf16x8*)&tmp[rt2 * 16 + lo][k0 + quad * 8];
#pragma unroll
    for (int ct = 0; ct < 8; ct++) {
      int co = ch * 128 + ct * 16 + lo;
      bf16x8 bf_ = *(const bf16x8*)(fcwT + (size_t)co * 256 + k0 + quad * 8);
      facc[ct] = __builtin_amdgcn_mfma_f32_16x16x32_bf16(a0, bf_, facc[ct], 0, 0, 0);
    }
  }
  __syncthreads();   // tmp reads done before overwrite
#pragma unroll
  for (int ct = 0; ct < 8; ct++) {
    int co = ch * 128 + ct * 16 + lo;
    float bv = fc_b[co];
#pragma unroll
    for (int r = 0; r < 4; r++) {
      int row = rt2 * 16 + quad * 4 + r;
      int grow = b * 512 + i0 + row;
      float v = facc[ct][r] + bv;
      v = v > 0.f ? v : 0.01f * v;
      v = (mask[grow] != 0) ? nodes[(size_t)grow * 256 + co] + v : 0.f;
      nodes[(size_t)grow * 256 + co] = v;
      tmp[row][co] = f2bf(v);       // stage y-values for kt GEMM
    }
  }
  __syncthreads();

  // ---- kt GEMM: ktb node rows = tmp @ sk_w^T + sk_b
  f32x4 kacc[8] = {};
  for (int k0 = 0; k0 < 256; k0 += 32) {
    bf16x8 a0 = *(const bf16x8*)&tmp[rt2 * 16 + lo][k0 + quad * 8];
#pragma unroll
    for (int ct = 0; ct < 8; ct++) {
      int co = ch * 128 + ct * 16 + lo;
      bf16x8 bf_ = *(const bf16x8*)(skw_it + (size_t)co * 256 + k0 + quad * 8);
      kacc[ct] = __builtin_amdgcn_mfma_f32_16x16x32_bf16(a0, bf_, kacc[ct], 0, 0, 0);
    }
  }
#pragma unroll
  for (int ct = 0; ct < 8; ct++) {
    int co = ch * 128 + ct * 16 + lo;
    float bv = skb_it[co];
#pragma unroll
    for (int r = 0; r < 4; r++) {
      int row = rt2 * 16 + quad * 4 + r;
      int yrow = b * LP1 + 1 + i0 + row;
      ktb[(size_t)yrow * 256 + co] = f2bf(kacc[ct][r] + bv);
    }
  }
}

// ---------------------------------------------------------------------------
// star attention on bf16 kt, q computed in-block from relay
__global__ __launch_bounds__(256) void star_attn_kernel(const float* __restrict__ relay,
                                                        const float* __restrict__ sqT_it,
                                                        const float* __restrict__ sqb_it,
                                                        const unsigned short* __restrict__ ktb,
                                                        const int* __restrict__ mask,
                                                        float* __restrict__ attstar) {
  int b = blockIdx.x >> 3, n = blockIdx.x & 7;
  int t = threadIdx.x;
  int lane = t & 63, w = t >> 6;
  __shared__ float relb[256];
  __shared__ float qv[32];
  __shared__ float pre[LP1];
  __shared__ float red[4];
  __shared__ float par[8][33];
  relb[t] = relay[b * 256 + t];
  __syncthreads();
  {
    int d = t & 31, g = t >> 5;
    float qp = 0.f;
    for (int k = 0; k < 32; k++)
      qp = fmaf(relb[g * 32 + k], sqT_it[(size_t)(g * 32 + k) * 256 + n * 32 + d], qp);
    par[g][d] = qp;
  }
  __syncthreads();
  if (t < 32) {
    float q = 0.f;
#pragma unroll
    for (int gg = 0; gg < 8; gg++) q += par[gg][t];
    qv[t] = q + sqb_it[n * 32 + t];
  }
  __syncthreads();
  const float scale = 0.17677669529663687f;
  for (int l = t; l < LP1; l += 256) {
    bool masked = (l > 0) && (mask[b * LL + l - 1] == 0);
    float p;
    if (masked) p = -3.4e38f;
    else {
      p = 0.f;
      const unsigned short* krow = ktb + ((size_t)b * LP1 + l) * 256 + n * 32;
#pragma unroll
      for (int d = 0; d < 32; d++) p = fmaf(qv[d], bf2f(krow[d]), p);
      p *= scale;
    }
    pre[l] = p;
  }
  __syncthreads();
  float m = -3.4e38f;
  for (int l = t; l < LP1; l += 256) m = fmaxf(m, pre[l]);
#pragma unroll
  for (int o = 32; o; o >>= 1) m = fmaxf(m, __shfl_xor(m, o));
  if (lane == 0) red[w] = m;
  __syncthreads();
  m = fmaxf(fmaxf(red[0], red[1]), fmaxf(red[2], red[3]));
  __syncthreads();
  float s = 0.f;
  for (int l = t; l < LP1; l += 256) {
    float wv = __expf(pre[l] - m);
    pre[l] = wv;
    s += wv;
  }
#pragma unroll
  for (int o = 32; o; o >>= 1) s += __shfl_xor(s, o);
  if (lane == 0) red[w] = s;
  __syncthreads();
  float denom = red[0] + red[1] + red[2] + red[3];
  int d = t & 31, g = t >> 5;
  float acc = 0.f;
  for (int l = g; l < LP1; l += 8)
    acc = fmaf(pre[l], bf2f(ktb[((size_t)b * LP1 + l) * 256 + n * 32 + d]), acc);
  par[g][d] = acc;
  __syncthreads();
  if (t < 32) {
    float a = 0.f;
    for (int gg = 0; gg < 8; gg++) a += par[gg][t];
    attstar[b * 256 + n * 32 + t] = a / denom;
  }
}

// ---------------------------------------------------------------------------
// relay = lrelu(atts @ soT + sob); + ktb relay row for next iteration
__global__ __launch_bounds__(256) void so_update_kernel(const float* __restrict__ atts,
                                                        const float* __restrict__ soT_it,
                                                        const float* __restrict__ sob_it,
                                                        const unsigned short* __restrict__ skw_nx,
                                                        const float* __restrict__ skb_nx,
                                                        int do_kt,
                                                        float* __restrict__ relay,
                                                        unsigned short* __restrict__ ktb) {
  int b = blockIdx.x, t = threadIdx.x;
  __shared__ float xr[256];
  __shared__ float rel[256];
  xr[t] = atts[b * 256 + t];
  __syncthreads();
  float acc = 0.f;
  for (int k = 0; k < 256; k++) acc = fmaf(xr[k], soT_it[(size_t)k * 256 + t], acc);
  float v = acc + sob_it[t];
  v = v > 0.f ? v : 0.01f * v;
  relay[b * 256 + t] = v;
  rel[t] = v;
  __syncthreads();
  if (do_kt) {
    float a2v = 0.f;
    for (int k = 0; k < 256; k++) a2v = fmaf(rel[k], bf2f(skw_nx[(size_t)t * 256 + k]), a2v);
    ktb[((size_t)b * LP1) * 256 + t] = f2bf(a2v + skb_nx[t]);
  }
}

// ---------------------------------------------------------------------------
extern "C" void kernel_launch(void* const* d_in, const int* in_sizes, int n_in,
                              void* d_out, int out_size, void* d_ws, size_t ws_size,
                              hipStream_t stream) {
  const float* data  = (const float*)d_in[0];
  const float* WQw   = (const float*)d_in[1];
  const float* WQb   = (const float*)d_in[2];
  const float* a1    = (const float*)d_in[3];
  const float* a2    = (const float*)d_in[4];
  const float* fcw_g = (const float*)d_in[5];
  const float* fcb_g = (const float*)d_in[6];
  const float* ng    = (const float*)d_in[7];
  const float* nb    = (const float*)d_in[8];
  const float* sq_w  = (const float*)d_in[9];
  const float* sq_b  = (const float*)d_in[10];
  const float* sk_w  = (const float*)d_in[11];
  const float* sk_b  = (const float*)d_in[12];
  const float* so_w  = (const float*)d_in[13];
  const float* so_b  = (const float*)d_in[14];
  const float* fc_w  = (const float*)d_in[15];
  const float* fc_b  = (const float*)d_in[16];
  const int*   mask  = (const int*)d_in[17];
  const int*   edge  = (const int*)d_in[18];

  float* nodes = (float*)d_out;
  float* relay = nodes + NODES_ELEMS;

  char* p = (char*)d_ws;
  auto alloc = [&](size_t bytes) -> char* {
    char* r = p; p += (bytes + 255) & ~(size_t)255; return r;
  };
  unsigned short* xnb  = (unsigned short*)alloc((size_t)8192 * 256 * 2);
  unsigned short* datab= (unsigned short*)alloc((size_t)8192 * 256 * 2);
  unsigned short* GT   = (unsigned short*)alloc((size_t)8 * 16 * 32 * 512 * 2);
  unsigned short* ktb  = (unsigned short*)alloc((size_t)8208 * 256 * 2);
  unsigned char* ep    = (unsigned char*)alloc((size_t)8192 * 64);
  float* ei            = (float*)alloc(65536 * 4);
  float* ej            = (float*)alloc(65536 * 4);
  float* ra1           = (float*)alloc(128 * 4);
  float* ra2           = (float*)alloc(128 * 4);
  float* rf            = (float*)alloc(4096 * 4);
  float* bqf           = (float*)alloc(256 * 4);
  float* w1            = (float*)alloc(2048 * 4);
  float* w2            = (float*)alloc(2048 * 4);
  float* c1            = (float*)alloc(8 * 4);
  float* c2            = (float*)alloc(8 * 4);
  float* rpart         = (float*)alloc(128 * 256 * 4);
  unsigned short* Bcat = (unsigned short*)alloc((size_t)256 * 512 * 2);
  unsigned short* fcwT = (unsigned short*)alloc((size_t)65536 * 2);
  unsigned short* skwb = (unsigned short*)alloc((size_t)131072 * 2);
  float* sqT           = (float*)alloc((size_t)131072 * 4);
  float* soT           = (float*)alloc((size_t)131072 * 4);
  float* atts          = (float*)alloc(4096 * 4);

  // one-time precomputes
  copy_cvt_kernel<<<2048, 256, 0, stream>>>(data, nodes, datab);
  w12bqf_kernel<<<8, 256, 0, stream>>>(WQw, WQb, a1, a2, fcw_g, w1, w2, c1, c2, bqf);
  bcat_m1_kernel<<<128, 256, 0, stream>>>(WQw, fcw_g, Bcat);
  prep_misc_kernel<<<1024, 256, 0, stream>>>(fc_w, fcw_g, sk_w, fcwT, Bcat, skwb);
  transpose4_kernel<<<dim3(256, 4), 256, 0, stream>>>(sq_w, so_w, sqT, soT);
  edge_pack_kernel<<<2048, 256, 0, stream>>>(edge, ep);
  relay_part_kernel<<<128, 256, 0, stream>>>(data, rpart);
  relay_fin_kernel<<<BB, 256, 0, stream>>>(rpart, skwb, sk_b, relay, ktb);

  for (int it = 0; it < 2; it++) {
    rarf_kernel<<<NHEAD * BB, 256, 0, stream>>>(relay, a1, a2, fcw_g, fcb_g, bqf,
                                                ra1, ra2, rf);
    lnei_kernel<<<2048, 256, 0, stream>>>(nodes, data, ng + it * 256, nb + it * 256,
                                          w1, w2, a1, a2, c1, c2, ra1, ra2,
                                          xnb, ei, ej);
    g_gemm_kernel<<<dim3(4, 64), 256, 0, stream>>>(xnb, datab, Bcat, GT);
    gat_fc_kt_kernel<<<256, 256, 0, stream>>>(GT, ei, ej, ep, rf,
                                              fcwT, fc_b,
                                              skwb + it * 65536, sk_b + it * 256,
                                              mask, nodes, ktb);
    star_attn_kernel<<<BB * NHEAD, 256, 0, stream>>>(relay, sqT + it * 65536,
                                                     sq_b + it * 256, ktb, mask, atts);
    so_update_kernel<<<BB, 256, 0, stream>>>(atts, soT + it * 65536, so_b + it * 256,
                                             skwb + 65536, sk_b + 256, (it == 0) ? 1 : 0,
                                             relay, ktb);
  }
}

// Round 10
// 417.656 us; speedup vs baseline: 1.1667x; 1.1667x over previous
//
#include <hip/hip_runtime.h>
#include <hip/hip_bf16.h>
#include <math.h>

#define BB 16
#define LL 512
#define HH 256
#define NHEAD 8
#define HDIM 32
#define LP1 513
#define NHHD 256
#define NODES_ELEMS (BB*LL*HH)

typedef __attribute__((ext_vector_type(8))) short bf16x8;
typedef __attribute__((ext_vector_type(4))) float f32x4;

__device__ __forceinline__ unsigned short f2bf(float f) {
  union { float f; unsigned u; } x; x.f = f;
  unsigned r = x.u + 0x7fffu + ((x.u >> 16) & 1u);
  return (unsigned short)(r >> 16);
}
__device__ __forceinline__ float bf2f(unsigned short u) {
  union { unsigned u; float f; } x; x.u = (unsigned)u << 16; return x.f;
}

// ---------------------------------------------------------------------------
// fused: nodes = data (fp32) ; datab = bf16(data)
__global__ __launch_bounds__(256) void copy_cvt_kernel(const float* __restrict__ data,
                                                       float* __restrict__ nodes,
                                                       unsigned short* __restrict__ datab) {
  int idx = blockIdx.x * 1024 + threadIdx.x;
#pragma unroll
  for (int u = 0; u < 4; u++) {
    float v = data[idx];
    nodes[idx] = v;
    datab[idx] = f2bf(v);
    idx += 256;
  }
}

// 4 weight transposes in one launch: {sq0, sq1, so0, so1}
__global__ __launch_bounds__(256) void transpose4_kernel(const float* __restrict__ sq_w,
                                                         const float* __restrict__ so_w,
                                                         float* __restrict__ sqT,
                                                         float* __restrict__ soT) {
  int which = blockIdx.y;
  const float* in = (which < 2) ? sq_w + which * 65536 : so_w + (which - 2) * 65536;
  float* out = (which < 2) ? sqT + which * 65536 : soT + (which - 2) * 65536;
  int idx = blockIdx.x * 256 + threadIdx.x;
  int r = idx >> 8, c = idx & 255;
  out[c * 256 + r] = in[idx];
}

// merged elementwise preps: fcwT (256 blk) | bcat_m2 (256 blk) | sk cvt (512 blk)
__global__ __launch_bounds__(256) void prep_misc_kernel(const float* __restrict__ fc_w,
                                                        const float* __restrict__ fcw,
                                                        const float* __restrict__ sk_w,
                                                        unsigned short* __restrict__ fcwT,
                                                        unsigned short* __restrict__ Bcat,
                                                        unsigned short* __restrict__ skwb) {
  int blk = blockIdx.x;
  int t = threadIdx.x;
  if (blk < 256) {
    int idx = blk * 256 + t;           // o*256 + k
    int o = idx >> 8, k = idx & 255;
    fcwT[idx] = f2bf(fc_w[k * 256 + o]);
  } else if (blk < 512) {
    int idx = (blk - 256) * 256 + t;   // n*8192 + d*256 + c
    int n = idx >> 13, d = (idx >> 8) & 31, c = idx & 255;
    Bcat[((size_t)n * 32 + d) * 512 + 256 + c] =
        f2bf(fcw[((size_t)n * 768 + 256 + 2 * c) * 32 + d]);
  } else {
    int idx = (blk - 512) * 256 + t;
    skwb[idx] = f2bf(sk_w[idx]);
  }
}

// edge -> packed bits
__global__ __launch_bounds__(256) void edge_pack_kernel(const int* __restrict__ edge,
                                                        unsigned char* __restrict__ ep) {
  int row = blockIdx.x * 4 + (threadIdx.x >> 6);
  int lane = threadIdx.x & 63;
  const int* adj = edge + ((size_t)row << 9);
  unsigned v = 0;
#pragma unroll
  for (int u = 0; u < 8; u++) v |= (adj[lane + 64 * u] > 0 ? 1u : 0u) << u;
  ep[((size_t)row << 6) + lane] = (unsigned char)v;
}

// Bcat M1: Bcat[(n*32+d)*512 + k] = sum_c WQw[n][c][k] * Fw[n][c][d]
__global__ __launch_bounds__(256) void bcat_m1_kernel(const float* __restrict__ WQw,
                                                      const float* __restrict__ fcw,
                                                      unsigned short* __restrict__ Bcat) {
  __shared__ float wq_s[256][16];
  __shared__ float fw_s[256][32];
  int n = blockIdx.x >> 4, kt = blockIdx.x & 15;
  int t = threadIdx.x;
#pragma unroll
  for (int i = 0; i < 16; i++) {
    int c = i * 16 + (t >> 4), kk = t & 15;
    wq_s[c][kk] = WQw[(size_t)n * 65536 + c * 256 + kt * 16 + kk];
  }
#pragma unroll
  for (int i = 0; i < 32; i++) {
    int idx = i * 256 + t;
    fw_s[idx >> 5][idx & 31] = fcw[(size_t)n * 24576 + idx];
  }
  __syncthreads();
  int kloc = t >> 4, dp = t & 15;
  float a0 = 0.f, a1v = 0.f;
  for (int c = 0; c < 256; c++) {
    float wv = wq_s[c][kloc];
    a0 = fmaf(wv, fw_s[c][dp * 2], a0);
    a1v = fmaf(wv, fw_s[c][dp * 2 + 1], a1v);
  }
  int k = kt * 16 + kloc;
  Bcat[((size_t)n * 32 + dp * 2) * 512 + k] = f2bf(a0);
  Bcat[((size_t)n * 32 + dp * 2 + 1) * 512 + k] = f2bf(a1v);
}

// w1/w2/c1/c2 folded attention weights + bqf, one block per head
__global__ __launch_bounds__(256) void w12bqf_kernel(const float* __restrict__ WQw,
                                                     const float* __restrict__ WQb,
                                                     const float* __restrict__ a1,
                                                     const float* __restrict__ a2,
                                                     const float* __restrict__ fcw,
                                                     float* __restrict__ w1,
                                                     float* __restrict__ w2,
                                                     float* __restrict__ c1,
                                                     float* __restrict__ c2,
                                                     float* __restrict__ bqf) {
  int n = blockIdx.x, t = threadIdx.x;
  float s1 = 0.f, s2 = 0.f;
  for (int c = 0; c < 256; c++) {
    float wv = WQw[((size_t)(n * 256 + c)) * 256 + t];
    s1 = fmaf(a1[n * 768 + c], wv, s1);
    s2 = fmaf(a2[n * 768 + c], wv, s2);
  }
  w1[n * 256 + t] = s1;
  w2[n * 256 + t] = s2;
  if (t < 32) {
    float s = 0.f;
    for (int c = 0; c < 256; c++)
      s = fmaf(WQb[n * 256 + c], fcw[((size_t)n * 768 + c) * 32 + t], s);
    bqf[n * 32 + t] = s;
  }
  __shared__ float r1[256], r2[256];
  r1[t] = a1[n * 768 + t] * WQb[n * 256 + t];
  r2[t] = a2[n * 768 + t] * WQb[n * 256 + t];
  __syncthreads();
  for (int o = 128; o; o >>= 1) {
    if (t < o) { r1[t] += r1[t + o]; r2[t] += r2[t + o]; }
    __syncthreads();
  }
  if (t == 0) { c1[n] = r1[0]; c2[n] = r2[0]; }
}

// ---------------------------------------------------------------------------
// relay mean, phase 1
__global__ __launch_bounds__(256) void relay_part_kernel(const float* __restrict__ data,
                                                         float* __restrict__ part) {
  int b = blockIdx.x >> 3, ch = blockIdx.x & 7;
  int t = threadIdx.x;
  float s = 0.f;
  const float* p = data + ((size_t)b * 512 + ch * 64) * 256 + t;
  for (int l = 0; l < 64; l++) s += p[(size_t)l * 256];
  part[(size_t)blockIdx.x * 256 + t] = s;
}

// relay mean, phase 2: relay fp32 + ktb relay row for it=0
__global__ __launch_bounds__(256) void relay_fin_kernel(const float* __restrict__ part,
                                                        const unsigned short* __restrict__ skw0,
                                                        const float* __restrict__ skb0,
                                                        float* __restrict__ relay,
                                                        unsigned short* __restrict__ ktb) {
  __shared__ float rel[256];
  int b = blockIdx.x, t = threadIdx.x;
  float s = 0.f;
#pragma unroll
  for (int ch = 0; ch < 8; ch++) s += part[((size_t)(b * 8 + ch)) * 256 + t];
  s *= (1.0f / 512.0f);
  relay[b * 256 + t] = s;
  rel[t] = s;
  __syncthreads();
  float acc = 0.f;
  for (int k = 0; k < 256; k++) acc = fmaf(rel[k], bf2f(skw0[(size_t)t * 256 + k]), acc);
  ktb[((size_t)b * LP1) * 256 + t] = f2bf(acc + skb0[t]);
}

// rarf: ra1/ra2 + rf(+fcb+bqf)
__global__ __launch_bounds__(256) void rarf_kernel(const float* __restrict__ relay,
                                                   const float* __restrict__ a1,
                                                   const float* __restrict__ a2,
                                                   const float* __restrict__ fcw,
                                                   const float* __restrict__ fcb,
                                                   const float* __restrict__ bqf,
                                                   float* __restrict__ ra1,
                                                   float* __restrict__ ra2,
                                                   float* __restrict__ rf) {
  int n = blockIdx.x >> 4, b = blockIdx.x & 15;
  int t = threadIdx.x;
  int lane = t & 63, w = t >> 6;
  __shared__ float rel[256];
  __shared__ float red1[4], red2[4];
  __shared__ float pf_s[8][33];
  rel[t] = relay[b * HH + t];
  __syncthreads();
  float p1 = rel[t] * a1[n * 768 + 257 + 2 * t];
  float p2 = rel[t] * a2[n * 768 + 257 + 2 * t];
#pragma unroll
  for (int o = 32; o; o >>= 1) { p1 += __shfl_xor(p1, o); p2 += __shfl_xor(p2, o); }
  if (lane == 0) { red1[w] = p1; red2[w] = p2; }
  int d = t & 31, seg = t >> 5;
  float pf = 0.f;
  for (int u = 0; u < 32; u++) {
    int k = seg * 32 + u;
    pf = fmaf(rel[k], fcw[((size_t)n * 768 + 257 + 2 * k) * 32 + d], pf);
  }
  pf_s[seg][d] = pf;
  __syncthreads();
  if (t == 0) {
    ra1[n * 16 + b] = red1[0] + red1[1] + red1[2] + red1[3];
    ra2[n * 16 + b] = red2[0] + red2[1] + red2[2] + red2[3];
  }
  if (t < 32) {
    float s = 0.f;
    for (int gg = 0; gg < 8; gg++) s += pf_s[gg][t];
    rf[((size_t)n * 16 + b) * 32 + t] = s + fcb[n * 32 + t] + bqf[n * 32 + t];
  }
}

// ---------------------------------------------------------------------------
// Fused LayerNorm + ei/ej; 16 reduction chains batched for ILP
__global__ __launch_bounds__(256) void lnei_kernel(const float* __restrict__ nodes,
                                                   const float* __restrict__ data,
                                                   const float* __restrict__ g,
                                                   const float* __restrict__ bb,
                                                   const float* __restrict__ w1,
                                                   const float* __restrict__ w2,
                                                   const float* __restrict__ a1,
                                                   const float* __restrict__ a2,
                                                   const float* __restrict__ c1,
                                                   const float* __restrict__ c2,
                                                   const float* __restrict__ ra1,
                                                   const float* __restrict__ ra2,
                                                   unsigned short* __restrict__ xnb,
                                                   float* __restrict__ ei,
                                                   float* __restrict__ ej) {
  int r = blockIdx.x * 4 + (threadIdx.x >> 6);
  int b = r >> 9;
  int lane = threadIdx.x & 63;
  float x[4], dv[4];
#pragma unroll
  for (int u = 0; u < 4; u++) {
    int c = lane + 64 * u;
    x[u] = nodes[(size_t)r * 256 + c];
    dv[u] = data[(size_t)r * 256 + c];
  }
  float s = x[0] + x[1] + x[2] + x[3];
#pragma unroll
  for (int o = 32; o; o >>= 1) s += __shfl_xor(s, o);
  float mean = s * (1.0f / 256.0f);
  float v = 0.f;
#pragma unroll
  for (int u = 0; u < 4; u++) { x[u] -= mean; v = fmaf(x[u], x[u], v); }
#pragma unroll
  for (int o = 32; o; o >>= 1) v += __shfl_xor(v, o);
  float rstd = rsqrtf(v * (1.0f / 256.0f) + 1e-5f);
  float xv[4];
#pragma unroll
  for (int u = 0; u < 4; u++) {
    int c = lane + 64 * u;
    xv[u] = x[u] * rstd * g[c] + bb[c];
    xnb[(size_t)r * 256 + c] = f2bf(xv[u]);
  }
  float s1a[8], s2a[8];
#pragma unroll
  for (int n = 0; n < 8; n++) {
    float s1 = 0.f, s2 = 0.f;
#pragma unroll
    for (int u = 0; u < 4; u++) {
      int c = lane + 64 * u;
      s1 = fmaf(xv[u], w1[n * 256 + c], s1);
      s1 = fmaf(dv[u], a1[n * 768 + 256 + 2 * c], s1);
      s2 = fmaf(xv[u], w2[n * 256 + c], s2);
      s2 = fmaf(dv[u], a2[n * 768 + 256 + 2 * c], s2);
    }
    s1a[n] = s1; s2a[n] = s2;
  }
#pragma unroll
  for (int o = 32; o; o >>= 1) {
#pragma unroll
    for (int n = 0; n < 8; n++) {
      s1a[n] += __shfl_xor(s1a[n], o);
      s2a[n] += __shfl_xor(s2a[n], o);
    }
  }
  if (lane == 0) {
#pragma unroll
    for (int n = 0; n < 8; n++) {
      ei[n * 8192 + r] = s1a[n] + c1[n] + ra1[n * 16 + b];
      ej[n * 8192 + r] = s2a[n] + c2[n] + ra2[n * 16 + b];
    }
  }
}

// ---------------------------------------------------------------------------
// G-GEMM: GT[n][b][d][j] = [xn ; data](row j) @ Bcat col (n*32+d)
__global__ __launch_bounds__(256) void g_gemm_kernel(
    const unsigned short* __restrict__ A1, const unsigned short* __restrict__ A2,
    const unsigned short* __restrict__ Bcat, unsigned short* __restrict__ GT) {
  int tileN = blockIdx.x * 64;
  int tileM = blockIdx.y * 128;
  int t = threadIdx.x;
  int wv = t >> 6, lane = t & 63;
  int lo = lane & 15, quad = lane >> 4;
  int rowBase0 = tileM + wv * 32;
  const unsigned short* ap1[2];
  const unsigned short* ap2[2];
#pragma unroll
  for (int rt = 0; rt < 2; rt++) {
    int arow = rowBase0 + rt * 16 + lo;
    ap1[rt] = A1 + (size_t)arow * 256 + quad * 8;
    ap2[rt] = A2 + (size_t)arow * 256 + quad * 8;
  }
  f32x4 acc[2][4] = {};
  for (int k0 = 0; k0 < 512; k0 += 32) {
    bf16x8 af[2];
#pragma unroll
    for (int rt = 0; rt < 2; rt++)
      af[rt] = (k0 < 256) ? *(const bf16x8*)(ap1[rt] + k0)
                          : *(const bf16x8*)(ap2[rt] + k0 - 256);
#pragma unroll
    for (int ct = 0; ct < 4; ct++) {
      bf16x8 bf_ = *(const bf16x8*)(Bcat + (size_t)(tileN + ct * 16 + lo) * 512 + k0 + quad * 8);
#pragma unroll
      for (int rt = 0; rt < 2; rt++)
        acc[rt][ct] = __builtin_amdgcn_mfma_f32_16x16x32_bf16(af[rt], bf_, acc[rt][ct], 0, 0, 0);
    }
  }
#pragma unroll
  for (int rt = 0; rt < 2; rt++) {
#pragma unroll
    for (int ct = 0; ct < 4; ct++) {
      int co = tileN + ct * 16 + lo;
      int n = co >> 5, d = co & 31;
      int jrow = rowBase0 + rt * 16 + quad * 4;
      int b2 = jrow >> 9, jj = jrow & 511;
      ushort4 pk;
      pk.x = f2bf(acc[rt][ct][0]);
      pk.y = f2bf(acc[rt][ct][1]);
      pk.z = f2bf(acc[rt][ct][2]);
      pk.w = f2bf(acc[rt][ct][3]);
      *(ushort4*)&GT[(((size_t)(n * 16 + b2) * 32 + d) << 9) + jj] = pk;
    }
  }
}

// ---------------------------------------------------------------------------
// GAT: reduction-free softmax (upper-bound max, MFMA ones-column denominator)
// 2048 blocks: (n, b, 32-row group)
__global__ __launch_bounds__(256) void gat_agg_kernel(
    const unsigned short* __restrict__ GT,
    const float* __restrict__ ei, const float* __restrict__ ej,
    const unsigned char* __restrict__ ep,
    const float* __restrict__ rf,
    unsigned short* __restrict__ tempb) {
  __shared__ unsigned short W[32][512];
  __shared__ float denom_s[32];
  int blk = blockIdx.x;
  int n = blk >> 8;
  int b = (blk >> 4) & 15;
  int i0 = (blk & 15) << 5;
  int t = threadIdx.x;
  int wv = t >> 6, lane = t & 63;
  int lo = lane & 15, quad = lane >> 4;

  const float* ejrow = ej + n * 8192 + b * 512;
  float ejv[8];
#pragma unroll
  for (int u = 0; u < 8; u++) ejv[u] = ejrow[lane + 64 * u];
  float mm = ejv[0];
#pragma unroll
  for (int u = 1; u < 8; u++) mm = fmaxf(mm, ejv[u]);
#pragma unroll
  for (int o = 32; o; o >>= 1) mm = fmaxf(mm, __shfl_xor(mm, o));

  for (int rr = 0; rr < 8; rr++) {
    int row = wv * 8 + rr;
    float eiv = ei[n * 8192 + b * 512 + i0 + row];
    float M = eiv + mm;
    M = M > 0.f ? M : 0.2f * M;
    unsigned pb = ep[(((size_t)(b * 512 + i0 + row)) << 6) + lane];
    int rx = (row & 7) << 3;
#pragma unroll
    for (int u = 0; u < 8; u++) {
      float e = eiv + ejv[u];
      e = e > 0.f ? e : 0.2f * e;
      float w = ((pb >> u) & 1) ? __expf(e - M) : 0.f;
      int col = lane + 64 * u;
      W[row][((col >> 3 << 3) ^ rx) + (col & 7)] = f2bf(w);
    }
  }
  __syncthreads();

  int rt = wv >> 1, dh = wv & 1;
  int arow = rt * 16 + lo;
  int rx = arow & 7;
  const unsigned short* gtb = GT + (((size_t)(n * 16 + b) * 32) << 9);
  bf16x8 bones;
  {
    short ov = (lo == 0) ? (short)0x3F80 : (short)0;
#pragma unroll
    for (int j = 0; j < 8; j++) bones[j] = ov;
  }
  f32x4 acc = {}, accd = {};
  for (int k0 = 0; k0 < 512; k0 += 32) {
    int chunk = (k0 >> 3) + quad;
    bf16x8 a0 = *(const bf16x8*)&W[arow][(chunk ^ rx) << 3];
    bf16x8 bf_ = *(const bf16x8*)(gtb + (((size_t)(dh * 16 + lo)) << 9) + k0 + quad * 8);
    acc = __builtin_amdgcn_mfma_f32_16x16x32_bf16(a0, bf_, acc, 0, 0, 0);
    if (dh == 0)
      accd = __builtin_amdgcn_mfma_f32_16x16x32_bf16(a0, bones, accd, 0, 0, 0);
  }
  if (dh == 0 && lo == 0) {
#pragma unroll
    for (int r = 0; r < 4; r++) denom_s[rt * 16 + quad * 4 + r] = accd[r];
  }
  __syncthreads();
  int d = dh * 16 + lo;
  float base = rf[((size_t)n * 16 + b) * 32 + d];
#pragma unroll
  for (int r = 0; r < 4; r++) {
    int row = rt * 16 + quad * 4 + r;
    float inv = 1.0f / fmaxf(denom_s[row], 1e-35f);
    float v = acc[r] * inv + base;
    v = v > 0.f ? v : expm1f(v);
    tempb[((size_t)(b * 512 + i0 + row)) * 256 + n * 32 + d] = f2bf(v);
  }
}

// ---------------------------------------------------------------------------
// Fused fc + kt GEMMs: block = (b, 32-row group), 256 blocks
// fc: nodes = mask ? nodes + lrelu(tmpb @ fc_w + fc_b) : 0; stage y bf16 in LDS
// kt: ktb node rows = y @ sk_w^T + sk_b
__global__ __launch_bounds__(256) void fc_kt_kernel(
    const unsigned short* __restrict__ tempb, // [8192][256] bf16
    const unsigned short* __restrict__ fcwT,  // [256 o][256 k] bf16
    const float* __restrict__ fc_b,
    const unsigned short* __restrict__ skw_it,// [256 o][256 k] bf16
    const float* __restrict__ skb_it,
    const int* __restrict__ mask,
    float* __restrict__ nodes,
    unsigned short* __restrict__ ktb) {
  __shared__ unsigned short tmp[32][264];     // y staging, pad -> 2-way (free)
  int blk = blockIdx.x;
  int b = blk >> 4;
  int i0 = (blk & 15) << 5;
  int t = threadIdx.x;
  int wv = t >> 6, lane = t & 63;
  int lo = lane & 15, quad = lane >> 4;
  int ch = wv >> 1, rt2 = wv & 1;   // wave = (col-half, row-tile)

  const unsigned short* arow_p = tempb + ((size_t)(b * 512 + i0 + rt2 * 16 + lo)) * 256 + quad * 8;
  f32x4 facc[8] = {};
  for (int k0 = 0; k0 < 256; k0 += 32) {
    bf16x8 a0 = *(const bf16x8*)(arow_p + k0);
#pragma unroll
    for (int ct = 0; ct < 8; ct++) {
      int co = ch * 128 + ct * 16 + lo;
      bf16x8 bf_ = *(const bf16x8*)(fcwT + (size_t)co * 256 + k0 + quad * 8);
      facc[ct] = __builtin_amdgcn_mfma_f32_16x16x32_bf16(a0, bf_, facc[ct], 0, 0, 0);
    }
  }
#pragma unroll
  for (int ct = 0; ct < 8; ct++) {
    int co = ch * 128 + ct * 16 + lo;
    float bv = fc_b[co];
#pragma unroll
    for (int r = 0; r < 4; r++) {
      int row = rt2 * 16 + quad * 4 + r;
      int grow = b * 512 + i0 + row;
      float v = facc[ct][r] + bv;
      v = v > 0.f ? v : 0.01f * v;
      v = (mask[grow] != 0) ? nodes[(size_t)grow * 256 + co] + v : 0.f;
      nodes[(size_t)grow * 256 + co] = v;
      tmp[row][co] = f2bf(v);
    }
  }
  __syncthreads();

  f32x4 kacc[8] = {};
  for (int k0 = 0; k0 < 256; k0 += 32) {
    bf16x8 a0 = *(const bf16x8*)&tmp[rt2 * 16 + lo][k0 + quad * 8];
#pragma unroll
    for (int ct = 0; ct < 8; ct++) {
      int co = ch * 128 + ct * 16 + lo;
      bf16x8 bf_ = *(const bf16x8*)(skw_it + (size_t)co * 256 + k0 + quad * 8);
      kacc[ct] = __builtin_amdgcn_mfma_f32_16x16x32_bf16(a0, bf_, kacc[ct], 0, 0, 0);
    }
  }
#pragma unroll
  for (int ct = 0; ct < 8; ct++) {
    int co = ch * 128 + ct * 16 + lo;
    float bv = skb_it[co];
#pragma unroll
    for (int r = 0; r < 4; r++) {
      int row = rt2 * 16 + quad * 4 + r;
      int yrow = b * LP1 + 1 + i0 + row;
      ktb[(size_t)yrow * 256 + co] = f2bf(kacc[ct][r] + bv);
    }
  }
}

// ---------------------------------------------------------------------------
// star attention on bf16 kt, q computed in-block from relay
__global__ __launch_bounds__(256) void star_attn_kernel(const float* __restrict__ relay,
                                                        const float* __restrict__ sqT_it,
                                                        const float* __restrict__ sqb_it,
                                                        const unsigned short* __restrict__ ktb,
                                                        const int* __restrict__ mask,
                                                        float* __restrict__ attstar) {
  int b = blockIdx.x >> 3, n = blockIdx.x & 7;
  int t = threadIdx.x;
  int lane = t & 63, w = t >> 6;
  __shared__ float relb[256];
  __shared__ float qv[32];
  __shared__ float pre[LP1];
  __shared__ float red[4];
  __shared__ float par[8][33];
  relb[t] = relay[b * 256 + t];
  __syncthreads();
  {
    int d = t & 31, g = t >> 5;
    float qp = 0.f;
    for (int k = 0; k < 32; k++)
      qp = fmaf(relb[g * 32 + k], sqT_it[(size_t)(g * 32 + k) * 256 + n * 32 + d], qp);
    par[g][d] = qp;
  }
  __syncthreads();
  if (t < 32) {
    float q = 0.f;
#pragma unroll
    for (int gg = 0; gg < 8; gg++) q += par[gg][t];
    qv[t] = q + sqb_it[n * 32 + t];
  }
  __syncthreads();
  const float scale = 0.17677669529663687f;
  for (int l = t; l < LP1; l += 256) {
    bool masked = (l > 0) && (mask[b * LL + l - 1] == 0);
    float p;
    if (masked) p = -3.4e38f;
    else {
      p = 0.f;
      const unsigned short* krow = ktb + ((size_t)b * LP1 + l) * 256 + n * 32;
#pragma unroll
      for (int d = 0; d < 32; d++) p = fmaf(qv[d], bf2f(krow[d]), p);
      p *= scale;
    }
    pre[l] = p;
  }
  __syncthreads();
  float m = -3.4e38f;
  for (int l = t; l < LP1; l += 256) m = fmaxf(m, pre[l]);
#pragma unroll
  for (int o = 32; o; o >>= 1) m = fmaxf(m, __shfl_xor(m, o));
  if (lane == 0) red[w] = m;
  __syncthreads();
  m = fmaxf(fmaxf(red[0], red[1]), fmaxf(red[2], red[3]));
  __syncthreads();
  float s = 0.f;
  for (int l = t; l < LP1; l += 256) {
    float wv = __expf(pre[l] - m);
    pre[l] = wv;
    s += wv;
  }
#pragma unroll
  for (int o = 32; o; o >>= 1) s += __shfl_xor(s, o);
  if (lane == 0) red[w] = s;
  __syncthreads();
  float denom = red[0] + red[1] + red[2] + red[3];
  int d = t & 31, g = t >> 5;
  float acc = 0.f;
  for (int l = g; l < LP1; l += 8)
    acc = fmaf(pre[l], bf2f(ktb[((size_t)b * LP1 + l) * 256 + n * 32 + d]), acc);
  par[g][d] = acc;
  __syncthreads();
  if (t < 32) {
    float a = 0.f;
    for (int gg = 0; gg < 8; gg++) a += par[gg][t];
    attstar[b * 256 + n * 32 + t] = a / denom;
  }
}

// ---------------------------------------------------------------------------
// relay = lrelu(atts @ soT + sob); + ktb relay row for next iteration
__global__ __launch_bounds__(256) void so_update_kernel(const float* __restrict__ atts,
                                                        const float* __restrict__ soT_it,
                                                        const float* __restrict__ sob_it,
                                                        const unsigned short* __restrict__ skw_nx,
                                                        const float* __restrict__ skb_nx,
                                                        int do_kt,
                                                        float* __restrict__ relay,
                                                        unsigned short* __restrict__ ktb) {
  int b = blockIdx.x, t = threadIdx.x;
  __shared__ float xr[256];
  __shared__ float rel[256];
  xr[t] = atts[b * 256 + t];
  __syncthreads();
  float acc = 0.f;
  for (int k = 0; k < 256; k++) acc = fmaf(xr[k], soT_it[(size_t)k * 256 + t], acc);
  float v = acc + sob_it[t];
  v = v > 0.f ? v : 0.01f * v;
  relay[b * 256 + t] = v;
  rel[t] = v;
  __syncthreads();
  if (do_kt) {
    float a2v = 0.f;
    for (int k = 0; k < 256; k++) a2v = fmaf(rel[k], bf2f(skw_nx[(size_t)t * 256 + k]), a2v);
    ktb[((size_t)b * LP1) * 256 + t] = f2bf(a2v + skb_nx[t]);
  }
}

// ---------------------------------------------------------------------------
extern "C" void kernel_launch(void* const* d_in, const int* in_sizes, int n_in,
                              void* d_out, int out_size, void* d_ws, size_t ws_size,
                              hipStream_t stream) {
  const float* data  = (const float*)d_in[0];
  const float* WQw   = (const float*)d_in[1];
  const float* WQb   = (const float*)d_in[2];
  const float* a1    = (const float*)d_in[3];
  const float* a2    = (const float*)d_in[4];
  const float* fcw_g = (const float*)d_in[5];
  const float* fcb_g = (const float*)d_in[6];
  const float* ng    = (const float*)d_in[7];
  const float* nb    = (const float*)d_in[8];
  const float* sq_w  = (const float*)d_in[9];
  const float* sq_b  = (const float*)d_in[10];
  const float* sk_w  = (const float*)d_in[11];
  const float* sk_b  = (const float*)d_in[12];
  const float* so_w  = (const float*)d_in[13];
  const float* so_b  = (const float*)d_in[14];
  const float* fc_w  = (const float*)d_in[15];
  const float* fc_b  = (const float*)d_in[16];
  const int*   mask  = (const int*)d_in[17];
  const int*   edge  = (const int*)d_in[18];

  float* nodes = (float*)d_out;
  float* relay = nodes + NODES_ELEMS;

  char* p = (char*)d_ws;
  auto alloc = [&](size_t bytes) -> char* {
    char* r = p; p += (bytes + 255) & ~(size_t)255; return r;
  };
  unsigned short* xnb  = (unsigned short*)alloc((size_t)8192 * 256 * 2);
  unsigned short* datab= (unsigned short*)alloc((size_t)8192 * 256 * 2);
  unsigned short* GT   = (unsigned short*)alloc((size_t)8 * 16 * 32 * 512 * 2);
  unsigned short* tmpb = (unsigned short*)alloc((size_t)8192 * 256 * 2);
  unsigned short* ktb  = (unsigned short*)alloc((size_t)8208 * 256 * 2);
  unsigned char* ep    = (unsigned char*)alloc((size_t)8192 * 64);
  float* ei            = (float*)alloc(65536 * 4);
  float* ej            = (float*)alloc(65536 * 4);
  float* ra1           = (float*)alloc(128 * 4);
  float* ra2           = (float*)alloc(128 * 4);
  float* rf            = (float*)alloc(4096 * 4);
  float* bqf           = (float*)alloc(256 * 4);
  float* w1            = (float*)alloc(2048 * 4);
  float* w2            = (float*)alloc(2048 * 4);
  float* c1            = (float*)alloc(8 * 4);
  float* c2            = (float*)alloc(8 * 4);
  float* rpart         = (float*)alloc(128 * 256 * 4);
  unsigned short* Bcat = (unsigned short*)alloc((size_t)256 * 512 * 2);
  unsigned short* fcwT = (unsigned short*)alloc((size_t)65536 * 2);
  unsigned short* skwb = (unsigned short*)alloc((size_t)131072 * 2);
  float* sqT           = (float*)alloc((size_t)131072 * 4);
  float* soT           = (float*)alloc((size_t)131072 * 4);
  float* atts          = (float*)alloc(4096 * 4);

  // one-time precomputes
  copy_cvt_kernel<<<2048, 256, 0, stream>>>(data, nodes, datab);
  w12bqf_kernel<<<8, 256, 0, stream>>>(WQw, WQb, a1, a2, fcw_g, w1, w2, c1, c2, bqf);
  bcat_m1_kernel<<<128, 256, 0, stream>>>(WQw, fcw_g, Bcat);
  prep_misc_kernel<<<1024, 256, 0, stream>>>(fc_w, fcw_g, sk_w, fcwT, Bcat, skwb);
  transpose4_kernel<<<dim3(256, 4), 256, 0, stream>>>(sq_w, so_w, sqT, soT);
  edge_pack_kernel<<<2048, 256, 0, stream>>>(edge, ep);
  relay_part_kernel<<<128, 256, 0, stream>>>(data, rpart);
  relay_fin_kernel<<<BB, 256, 0, stream>>>(rpart, skwb, sk_b, relay, ktb);

  for (int it = 0; it < 2; it++) {
    rarf_kernel<<<NHEAD * BB, 256, 0, stream>>>(relay, a1, a2, fcw_g, fcb_g, bqf,
                                                ra1, ra2, rf);
    lnei_kernel<<<2048, 256, 0, stream>>>(nodes, data, ng + it * 256, nb + it * 256,
                                          w1, w2, a1, a2, c1, c2, ra1, ra2,
                                          xnb, ei, ej);
    g_gemm_kernel<<<dim3(4, 64), 256, 0, stream>>>(xnb, datab, Bcat, GT);
    gat_agg_kernel<<<NHEAD * BB * 16, 256, 0, stream>>>(GT, ei, ej, ep, rf, tmpb);
    fc_kt_kernel<<<256, 256, 0, stream>>>(tmpb, fcwT, fc_b,
                                          skwb + it * 65536, sk_b + it * 256,
                                          mask, nodes, ktb);
    star_attn_kernel<<<BB * NHEAD, 256, 0, stream>>>(relay, sqT + it * 65536,
                                                     sq_b + it * 256, ktb, mask, atts);
    so_update_kernel<<<BB, 256, 0, stream>>>(atts, soT + it * 65536, so_b + it * 256,
                                             skwb + 65536, sk_b + 256, (it == 0) ? 1 : 0,
                                             relay, ktb);
  }
}

// Round 11
// 386.327 us; speedup vs baseline: 1.2613x; 1.0811x over previous
//
#include <hip/hip_runtime.h>
#include <hip/hip_bf16.h>
#include <math.h>

#define BB 16
#define LL 512
#define HH 256
#define NHEAD 8
#define HDIM 32
#define LP1 513
#define NODES_ELEMS (BB*LL*HH)

typedef __attribute__((ext_vector_type(8))) short bf16x8;
typedef __attribute__((ext_vector_type(4))) float f32x4;

__device__ __forceinline__ unsigned short f2bf(float f) {
  union { float f; unsigned u; } x; x.f = f;
  unsigned r = x.u + 0x7fffu + ((x.u >> 16) & 1u);
  return (unsigned short)(r >> 16);
}
__device__ __forceinline__ float bf2f(unsigned short u) {
  union { unsigned u; float f; } x; x.u = (unsigned)u << 16; return x.f;
}

// ---------------------------------------------------------------------------
// MEGA-PREP: all independent one-time precomputes in one launch (6288 blocks)
__global__ __launch_bounds__(256) void mega_prep_kernel(
    const float* __restrict__ data, const int* __restrict__ edge,
    const float* __restrict__ fc_w, const float* __restrict__ fcw,
    const float* __restrict__ sk_w, const float* __restrict__ sq_w,
    const float* __restrict__ so_w, const float* __restrict__ WQw,
    const float* __restrict__ WQb, const float* __restrict__ a1,
    const float* __restrict__ a2,
    unsigned short* __restrict__ datab, unsigned char* __restrict__ ep,
    unsigned short* __restrict__ fcwT, unsigned short* __restrict__ Bcat,
    unsigned short* __restrict__ skwb, float* __restrict__ sqT,
    float* __restrict__ soT, float* __restrict__ rpart,
    float* __restrict__ w1, float* __restrict__ w2,
    float* __restrict__ c1, float* __restrict__ c2,
    float* __restrict__ bqf, float* __restrict__ a1o, float* __restrict__ a2o) {
  int blk = blockIdx.x, t = threadIdx.x;
  if (blk < 2048) {                       // data -> bf16
    int idx = blk * 1024 + t;
#pragma unroll
    for (int u = 0; u < 4; u++) { datab[idx] = f2bf(data[idx]); idx += 256; }
  } else if (blk < 4096) {                // edge pack
    int row = (blk - 2048) * 4 + (t >> 6);
    int lane = t & 63;
    const int* adj = edge + ((size_t)row << 9);
    unsigned v = 0;
#pragma unroll
    for (int u = 0; u < 8; u++) v |= (adj[lane + 64 * u] > 0 ? 1u : 0u) << u;
    ep[((size_t)row << 6) + lane] = (unsigned char)v;
  } else if (blk < 5120) {                // fcwT | Bcat m2 | sk cvt
    int b2 = blk - 4096;
    if (b2 < 256) {
      int idx = b2 * 256 + t;
      int o = idx >> 8, k = idx & 255;
      fcwT[idx] = f2bf(fc_w[k * 256 + o]);
    } else if (b2 < 512) {
      int idx = (b2 - 256) * 256 + t;
      int n = idx >> 13, d = (idx >> 8) & 31, c = idx & 255;
      Bcat[((size_t)n * 32 + d) * 512 + 256 + c] =
          f2bf(fcw[((size_t)n * 768 + 256 + 2 * c) * 32 + d]);
    } else {
      int idx = (b2 - 512) * 256 + t;
      skwb[idx] = f2bf(sk_w[idx]);
    }
  } else if (blk < 6144) {                // sq/so transposes
    int q = blk - 5120;
    int which = q >> 8;
    const float* in = (which < 2) ? sq_w + which * 65536 : so_w + (which - 2) * 65536;
    float* out = (which < 2) ? sqT + which * 65536 : soT + (which - 2) * 65536;
    int idx = (q & 255) * 256 + t;
    int r = idx >> 8, c = idx & 255;
    out[c * 256 + r] = in[idx];
  } else if (blk < 6272) {                // relay partials
    int q = blk - 6144;
    int b = q >> 3, ch = q & 7;
    float s = 0.f;
    const float* p = data + ((size_t)b * 512 + ch * 64) * 256 + t;
    for (int l = 0; l < 64; l++) s += p[(size_t)l * 256];
    rpart[(size_t)q * 256 + t] = s;
  } else if (blk < 6280) {                // w1/w2/c1/c2/bqf
    int n = blk - 6272;
    float s1 = 0.f, s2 = 0.f;
    for (int c = 0; c < 256; c++) {
      float wv = WQw[((size_t)(n * 256 + c)) * 256 + t];
      s1 = fmaf(a1[n * 768 + c], wv, s1);
      s2 = fmaf(a2[n * 768 + c], wv, s2);
    }
    w1[n * 256 + t] = s1;
    w2[n * 256 + t] = s2;
    if (t < 32) {
      float s = 0.f;
      for (int c = 0; c < 256; c++)
        s = fmaf(WQb[n * 256 + c], fcw[((size_t)n * 768 + c) * 32 + t], s);
      bqf[n * 32 + t] = s;
    }
    __shared__ float r1[256], r2[256];
    r1[t] = a1[n * 768 + t] * WQb[n * 256 + t];
    r2[t] = a2[n * 768 + t] * WQb[n * 256 + t];
    __syncthreads();
    for (int o = 128; o; o >>= 1) {
      if (t < o) { r1[t] += r1[t + o]; r2[t] += r2[t + o]; }
      __syncthreads();
    }
    if (t == 0) { c1[n] = r1[0]; c2[n] = r2[0]; }
  } else {                                // a1o/a2o odd-stride packing
    int n = blk - 6280;
    a1o[n * 256 + t] = a1[n * 768 + 256 + 2 * t];
    a2o[n * 256 + t] = a2[n * 768 + 256 + 2 * t];
  }
}

// Bcat M1: Bcat[(n*32+d)*512 + k] = sum_c WQw[n][c][k] * Fw[n][c][d]
__global__ __launch_bounds__(256) void bcat_m1_kernel(const float* __restrict__ WQw,
                                                      const float* __restrict__ fcw,
                                                      unsigned short* __restrict__ Bcat) {
  __shared__ float wq_s[256][16];
  __shared__ float fw_s[256][32];
  int n = blockIdx.x >> 4, kt = blockIdx.x & 15;
  int t = threadIdx.x;
#pragma unroll
  for (int i = 0; i < 16; i++) {
    int c = i * 16 + (t >> 4), kk = t & 15;
    wq_s[c][kk] = WQw[(size_t)n * 65536 + c * 256 + kt * 16 + kk];
  }
#pragma unroll
  for (int i = 0; i < 32; i++) {
    int idx = i * 256 + t;
    fw_s[idx >> 5][idx & 31] = fcw[(size_t)n * 24576 + idx];
  }
  __syncthreads();
  int kloc = t >> 4, dp = t & 15;
  float a0 = 0.f, a1v = 0.f;
  for (int c = 0; c < 256; c++) {
    float wv = wq_s[c][kloc];
    a0 = fmaf(wv, fw_s[c][dp * 2], a0);
    a1v = fmaf(wv, fw_s[c][dp * 2 + 1], a1v);
  }
  int k = kt * 16 + kloc;
  Bcat[((size_t)n * 32 + dp * 2) * 512 + k] = f2bf(a0);
  Bcat[((size_t)n * 32 + dp * 2 + 1) * 512 + k] = f2bf(a1v);
}

// ---------------------------------------------------------------------------
// shared rarf tail: rel[] holds relay row b; computes ra1/ra2/rf for (n,b)
__device__ __forceinline__ void rarf_tail(
    int n, int b, int t, const float* rel,
    const float* __restrict__ a1, const float* __restrict__ a2,
    const float* __restrict__ fcw, const float* __restrict__ fcb,
    const float* __restrict__ bqf,
    float* __restrict__ ra1, float* __restrict__ ra2, float* __restrict__ rf,
    float* red1, float* red2, float* pf_s) {
  int lane = t & 63, w = t >> 6;
  float p1 = rel[t] * a1[n * 768 + 257 + 2 * t];
  float p2 = rel[t] * a2[n * 768 + 257 + 2 * t];
#pragma unroll
  for (int o = 32; o; o >>= 1) { p1 += __shfl_xor(p1, o); p2 += __shfl_xor(p2, o); }
  if (lane == 0) { red1[w] = p1; red2[w] = p2; }
  int d = t & 31, seg = t >> 5;
  float pf = 0.f;
  for (int u = 0; u < 32; u++) {
    int k = seg * 32 + u;
    pf = fmaf(rel[k], fcw[((size_t)n * 768 + 257 + 2 * k) * 32 + d], pf);
  }
  pf_s[seg * 33 + d] = pf;
  __syncthreads();
  if (t == 0) {
    ra1[n * 16 + b] = red1[0] + red1[1] + red1[2] + red1[3];
    ra2[n * 16 + b] = red2[0] + red2[1] + red2[2] + red2[3];
  }
  if (t < 32) {
    float s = 0.f;
    for (int gg = 0; gg < 8; gg++) s += pf_s[gg * 33 + t];
    rf[((size_t)n * 16 + b) * 32 + t] = s + fcb[n * 32 + t] + bqf[n * 32 + t];
  }
}

// relay from partials + ktb relay row (n==0) + rarf extras: 128 blocks (n,b)
__global__ __launch_bounds__(256) void relay_rarf_kernel(
    const float* __restrict__ rpart,
    const unsigned short* __restrict__ skw0, const float* __restrict__ skb0,
    const float* __restrict__ a1, const float* __restrict__ a2,
    const float* __restrict__ fcw, const float* __restrict__ fcb,
    const float* __restrict__ bqf,
    float* __restrict__ relay, unsigned short* __restrict__ ktb,
    float* __restrict__ ra1, float* __restrict__ ra2, float* __restrict__ rf) {
  __shared__ float rel[256];
  __shared__ float red1[4], red2[4];
  __shared__ float pf_s[8 * 33];
  int n = blockIdx.x >> 4, b = blockIdx.x & 15;
  int t = threadIdx.x;
  float s = 0.f;
#pragma unroll
  for (int ch = 0; ch < 8; ch++) s += rpart[((size_t)(b * 8 + ch)) * 256 + t];
  s *= (1.0f / 512.0f);
  rel[t] = s;
  __syncthreads();
  if (n == 0) {
    relay[b * 256 + t] = s;
    float acc = 0.f;
    for (int k = 0; k < 256; k++) acc = fmaf(rel[k], bf2f(skw0[(size_t)t * 256 + k]), acc);
    ktb[((size_t)b * LP1) * 256 + t] = f2bf(acc + skb0[t]);
  }
  rarf_tail(n, b, t, rel, a1, a2, fcw, fcb, bqf, ra1, ra2, rf, red1, red2, pf_s);
}

// relay = lrelu(atts @ soT + sob) (+ ktb row + rarf extras when do_extras)
__global__ __launch_bounds__(256) void so_rarf_kernel(
    const float* __restrict__ atts,
    const float* __restrict__ soT_it, const float* __restrict__ sob_it,
    const unsigned short* __restrict__ skw_nx, const float* __restrict__ skb_nx,
    const float* __restrict__ a1, const float* __restrict__ a2,
    const float* __restrict__ fcw, const float* __restrict__ fcb,
    const float* __restrict__ bqf, int do_extras,
    float* __restrict__ relay, unsigned short* __restrict__ ktb,
    float* __restrict__ ra1, float* __restrict__ ra2, float* __restrict__ rf) {
  int n = blockIdx.x >> 4, b = blockIdx.x & 15;
  if (!do_extras && n > 0) return;
  __shared__ float xr[256];
  __shared__ float rel[256];
  __shared__ float red1[4], red2[4];
  __shared__ float pf_s[8 * 33];
  int t = threadIdx.x;
  xr[t] = atts[b * 256 + t];
  __syncthreads();
  float acc = 0.f;
  for (int k = 0; k < 256; k++) acc = fmaf(xr[k], soT_it[(size_t)k * 256 + t], acc);
  float v = acc + sob_it[t];
  v = v > 0.f ? v : 0.01f * v;
  rel[t] = v;
  __syncthreads();
  if (n == 0) relay[b * 256 + t] = v;
  if (!do_extras) return;
  if (n == 0) {
    float a2v = 0.f;
    for (int k = 0; k < 256; k++) a2v = fmaf(rel[k], bf2f(skw_nx[(size_t)t * 256 + k]), a2v);
    ktb[((size_t)b * LP1) * 256 + t] = f2bf(a2v + skb_nx[t]);
  }
  rarf_tail(n, b, t, rel, a1, a2, fcw, fcb, bqf, ra1, ra2, rf, red1, red2, pf_s);
}

// ---------------------------------------------------------------------------
// Fused LayerNorm + ei/ej; src = data (it=0) or nodes; dv from bf16 datab
__global__ __launch_bounds__(256) void lnei_kernel(const float* __restrict__ src,
                                                   const unsigned short* __restrict__ datab,
                                                   const float* __restrict__ g,
                                                   const float* __restrict__ bb,
                                                   const float* __restrict__ w1,
                                                   const float* __restrict__ w2,
                                                   const float* __restrict__ a1o,
                                                   const float* __restrict__ a2o,
                                                   const float* __restrict__ c1,
                                                   const float* __restrict__ c2,
                                                   const float* __restrict__ ra1,
                                                   const float* __restrict__ ra2,
                                                   unsigned short* __restrict__ xnb,
                                                   float* __restrict__ ei,
                                                   float* __restrict__ ej) {
  int r = blockIdx.x * 4 + (threadIdx.x >> 6);
  int b = r >> 9;
  int lane = threadIdx.x & 63;
  float x[4], dv[4];
#pragma unroll
  for (int u = 0; u < 4; u++) {
    int c = lane + 64 * u;
    x[u] = src[(size_t)r * 256 + c];
    dv[u] = bf2f(datab[(size_t)r * 256 + c]);
  }
  float s = x[0] + x[1] + x[2] + x[3];
#pragma unroll
  for (int o = 32; o; o >>= 1) s += __shfl_xor(s, o);
  float mean = s * (1.0f / 256.0f);
  float v = 0.f;
#pragma unroll
  for (int u = 0; u < 4; u++) { x[u] -= mean; v = fmaf(x[u], x[u], v); }
#pragma unroll
  for (int o = 32; o; o >>= 1) v += __shfl_xor(v, o);
  float rstd = rsqrtf(v * (1.0f / 256.0f) + 1e-5f);
  float xv[4];
#pragma unroll
  for (int u = 0; u < 4; u++) {
    int c = lane + 64 * u;
    xv[u] = x[u] * rstd * g[c] + bb[c];
    xnb[(size_t)r * 256 + c] = f2bf(xv[u]);
  }
  float s1a[8], s2a[8];
#pragma unroll
  for (int n = 0; n < 8; n++) {
    float s1 = 0.f, s2 = 0.f;
#pragma unroll
    for (int u = 0; u < 4; u++) {
      int c = lane + 64 * u;
      s1 = fmaf(xv[u], w1[n * 256 + c], s1);
      s1 = fmaf(dv[u], a1o[n * 256 + c], s1);
      s2 = fmaf(xv[u], w2[n * 256 + c], s2);
      s2 = fmaf(dv[u], a2o[n * 256 + c], s2);
    }
    s1a[n] = s1; s2a[n] = s2;
  }
#pragma unroll
  for (int o = 32; o; o >>= 1) {
#pragma unroll
    for (int n = 0; n < 8; n++) {
      s1a[n] += __shfl_xor(s1a[n], o);
      s2a[n] += __shfl_xor(s2a[n], o);
    }
  }
  if (lane == 0) {
#pragma unroll
    for (int n = 0; n < 8; n++) {
      ei[n * 8192 + r] = s1a[n] + c1[n] + ra1[n * 16 + b];
      ej[n * 8192 + r] = s2a[n] + c2[n] + ra2[n * 16 + b];
    }
  }
}

// ---------------------------------------------------------------------------
// G-GEMM: GT[n][b][d][j] = [xn ; data](row j) @ Bcat col (n*32+d)
__global__ __launch_bounds__(256) void g_gemm_kernel(
    const unsigned short* __restrict__ A1, const unsigned short* __restrict__ A2,
    const unsigned short* __restrict__ Bcat, unsigned short* __restrict__ GT) {
  int tileN = blockIdx.x * 64;
  int tileM = blockIdx.y * 128;
  int t = threadIdx.x;
  int wv = t >> 6, lane = t & 63;
  int lo = lane & 15, quad = lane >> 4;
  int rowBase0 = tileM + wv * 32;
  const unsigned short* ap1[2];
  const unsigned short* ap2[2];
#pragma unroll
  for (int rt = 0; rt < 2; rt++) {
    int arow = rowBase0 + rt * 16 + lo;
    ap1[rt] = A1 + (size_t)arow * 256 + quad * 8;
    ap2[rt] = A2 + (size_t)arow * 256 + quad * 8;
  }
  f32x4 acc[2][4] = {};
  for (int k0 = 0; k0 < 512; k0 += 32) {
    bf16x8 af[2];
#pragma unroll
    for (int rt = 0; rt < 2; rt++)
      af[rt] = (k0 < 256) ? *(const bf16x8*)(ap1[rt] + k0)
                          : *(const bf16x8*)(ap2[rt] + k0 - 256);
#pragma unroll
    for (int ct = 0; ct < 4; ct++) {
      bf16x8 bf_ = *(const bf16x8*)(Bcat + (size_t)(tileN + ct * 16 + lo) * 512 + k0 + quad * 8);
#pragma unroll
      for (int rt = 0; rt < 2; rt++)
        acc[rt][ct] = __builtin_amdgcn_mfma_f32_16x16x32_bf16(af[rt], bf_, acc[rt][ct], 0, 0, 0);
    }
  }
#pragma unroll
  for (int rt = 0; rt < 2; rt++) {
#pragma unroll
    for (int ct = 0; ct < 4; ct++) {
      int co = tileN + ct * 16 + lo;
      int n = co >> 5, d = co & 31;
      int jrow = rowBase0 + rt * 16 + quad * 4;
      int b2 = jrow >> 9, jj = jrow & 511;
      ushort4 pk;
      pk.x = f2bf(acc[rt][ct][0]);
      pk.y = f2bf(acc[rt][ct][1]);
      pk.z = f2bf(acc[rt][ct][2]);
      pk.w = f2bf(acc[rt][ct][3]);
      *(ushort4*)&GT[(((size_t)(n * 16 + b2) * 32 + d) << 9) + jj] = pk;
    }
  }
}

// ---------------------------------------------------------------------------
// GAT: reduction-free softmax (upper-bound max, MFMA ones-column denominator)
__global__ __launch_bounds__(256) void gat_agg_kernel(
    const unsigned short* __restrict__ GT,
    const float* __restrict__ ei, const float* __restrict__ ej,
    const unsigned char* __restrict__ ep,
    const float* __restrict__ rf,
    unsigned short* __restrict__ tempb) {
  __shared__ unsigned short W[32][512];
  __shared__ float denom_s[32];
  int blk = blockIdx.x;
  int n = blk >> 8;
  int b = (blk >> 4) & 15;
  int i0 = (blk & 15) << 5;
  int t = threadIdx.x;
  int wv = t >> 6, lane = t & 63;
  int lo = lane & 15, quad = lane >> 4;

  const float* ejrow = ej + n * 8192 + b * 512;
  float ejv[8];
#pragma unroll
  for (int u = 0; u < 8; u++) ejv[u] = ejrow[lane + 64 * u];
  float mm = ejv[0];
#pragma unroll
  for (int u = 1; u < 8; u++) mm = fmaxf(mm, ejv[u]);
#pragma unroll
  for (int o = 32; o; o >>= 1) mm = fmaxf(mm, __shfl_xor(mm, o));

  for (int rr = 0; rr < 8; rr++) {
    int row = wv * 8 + rr;
    float eiv = ei[n * 8192 + b * 512 + i0 + row];
    float M = eiv + mm;
    M = M > 0.f ? M : 0.2f * M;
    unsigned pb = ep[(((size_t)(b * 512 + i0 + row)) << 6) + lane];
    int rx = (row & 7) << 3;
#pragma unroll
    for (int u = 0; u < 8; u++) {
      float e = eiv + ejv[u];
      e = e > 0.f ? e : 0.2f * e;
      float w = ((pb >> u) & 1) ? __expf(e - M) : 0.f;
      int col = lane + 64 * u;
      W[row][((col >> 3 << 3) ^ rx) + (col & 7)] = f2bf(w);
    }
  }
  __syncthreads();

  int rt = wv >> 1, dh = wv & 1;
  int arow = rt * 16 + lo;
  int rx = arow & 7;
  const unsigned short* gtb = GT + (((size_t)(n * 16 + b) * 32) << 9);
  bf16x8 bones;
  {
    short ov = (lo == 0) ? (short)0x3F80 : (short)0;
#pragma unroll
    for (int j = 0; j < 8; j++) bones[j] = ov;
  }
  f32x4 acc = {}, accd = {};
  for (int k0 = 0; k0 < 512; k0 += 32) {
    int chunk = (k0 >> 3) + quad;
    bf16x8 a0 = *(const bf16x8*)&W[arow][(chunk ^ rx) << 3];
    bf16x8 bf_ = *(const bf16x8*)(gtb + (((size_t)(dh * 16 + lo)) << 9) + k0 + quad * 8);
    acc = __builtin_amdgcn_mfma_f32_16x16x32_bf16(a0, bf_, acc, 0, 0, 0);
    if (dh == 0)
      accd = __builtin_amdgcn_mfma_f32_16x16x32_bf16(a0, bones, accd, 0, 0, 0);
  }
  if (dh == 0 && lo == 0) {
#pragma unroll
    for (int r = 0; r < 4; r++) denom_s[rt * 16 + quad * 4 + r] = accd[r];
  }
  __syncthreads();
  int d = dh * 16 + lo;
  float base = rf[((size_t)n * 16 + b) * 32 + d];
#pragma unroll
  for (int r = 0; r < 4; r++) {
    int row = rt * 16 + quad * 4 + r;
    float inv = 1.0f / fmaxf(denom_s[row], 1e-35f);
    float v = acc[r] * inv + base;
    v = v > 0.f ? v : expm1f(v);
    tempb[((size_t)(b * 512 + i0 + row)) * 256 + n * 32 + d] = f2bf(v);
  }
}

// ---------------------------------------------------------------------------
// Fused fc + kt GEMMs: block = (b, 32-row group), 256 blocks
__global__ __launch_bounds__(256) void fc_kt_kernel(
    const unsigned short* __restrict__ tempb,
    const unsigned short* __restrict__ fcwT,
    const float* __restrict__ fc_b,
    const unsigned short* __restrict__ skw_it,
    const float* __restrict__ skb_it,
    const int* __restrict__ mask,
    const float* __restrict__ resid,
    float* __restrict__ nodes,
    unsigned short* __restrict__ ktb) {
  __shared__ unsigned short tmp[32][264];
  int blk = blockIdx.x;
  int b = blk >> 4;
  int i0 = (blk & 15) << 5;
  int t = threadIdx.x;
  int wv = t >> 6, lane = t & 63;
  int lo = lane & 15, quad = lane >> 4;
  int ch = wv >> 1, rt2 = wv & 1;

  const unsigned short* arow_p = tempb + ((size_t)(b * 512 + i0 + rt2 * 16 + lo)) * 256 + quad * 8;
  f32x4 facc[8] = {};
  for (int k0 = 0; k0 < 256; k0 += 32) {
    bf16x8 a0 = *(const bf16x8*)(arow_p + k0);
#pragma unroll
    for (int ct = 0; ct < 8; ct++) {
      int co = ch * 128 + ct * 16 + lo;
      bf16x8 bf_ = *(const bf16x8*)(fcwT + (size_t)co * 256 + k0 + quad * 8);
      facc[ct] = __builtin_amdgcn_mfma_f32_16x16x32_bf16(a0, bf_, facc[ct], 0, 0, 0);
    }
  }
#pragma unroll
  for (int ct = 0; ct < 8; ct++) {
    int co = ch * 128 + ct * 16 + lo;
    float bv = fc_b[co];
#pragma unroll
    for (int r = 0; r < 4; r++) {
      int row = rt2 * 16 + quad * 4 + r;
      int grow = b * 512 + i0 + row;
      float v = facc[ct][r] + bv;
      v = v > 0.f ? v : 0.01f * v;
      v = (mask[grow] != 0) ? resid[(size_t)grow * 256 + co] + v : 0.f;
      nodes[(size_t)grow * 256 + co] = v;
      tmp[row][co] = f2bf(v);
    }
  }
  __syncthreads();

  f32x4 kacc[8] = {};
  for (int k0 = 0; k0 < 256; k0 += 32) {
    bf16x8 a0 = *(const bf16x8*)&tmp[rt2 * 16 + lo][k0 + quad * 8];
#pragma unroll
    for (int ct = 0; ct < 8; ct++) {
      int co = ch * 128 + ct * 16 + lo;
      bf16x8 bf_ = *(const bf16x8*)(skw_it + (size_t)co * 256 + k0 + quad * 8);
      kacc[ct] = __builtin_amdgcn_mfma_f32_16x16x32_bf16(a0, bf_, kacc[ct], 0, 0, 0);
    }
  }
#pragma unroll
  for (int ct = 0; ct < 8; ct++) {
    int co = ch * 128 + ct * 16 + lo;
    float bv = skb_it[co];
#pragma unroll
    for (int r = 0; r < 4; r++) {
      int row = rt2 * 16 + quad * 4 + r;
      int yrow = b * LP1 + 1 + i0 + row;
      ktb[(size_t)yrow * 256 + co] = f2bf(kacc[ct][r] + bv);
    }
  }
}

// ---------------------------------------------------------------------------
// star attention on bf16 kt, q computed in-block from relay
__global__ __launch_bounds__(256) void star_attn_kernel(const float* __restrict__ relay,
                                                        const float* __restrict__ sqT_it,
                                                        const float* __restrict__ sqb_it,
                                                        const unsigned short* __restrict__ ktb,
                                                        const int* __restrict__ mask,
                                                        float* __restrict__ attstar) {
  int b = blockIdx.x >> 3, n = blockIdx.x & 7;
  int t = threadIdx.x;
  int lane = t & 63, w = t >> 6;
  __shared__ float relb[256];
  __shared__ float qv[32];
  __shared__ float pre[LP1];
  __shared__ float red[4];
  __shared__ float par[8][33];
  relb[t] = relay[b * 256 + t];
  __syncthreads();
  {
    int d = t & 31, g = t >> 5;
    float qp = 0.f;
    for (int k = 0; k < 32; k++)
      qp = fmaf(relb[g * 32 + k], sqT_it[(size_t)(g * 32 + k) * 256 + n * 32 + d], qp);
    par[g][d] = qp;
  }
  __syncthreads();
  if (t < 32) {
    float q = 0.f;
#pragma unroll
    for (int gg = 0; gg < 8; gg++) q += par[gg][t];
    qv[t] = q + sqb_it[n * 32 + t];
  }
  __syncthreads();
  const float scale = 0.17677669529663687f;
  for (int l = t; l < LP1; l += 256) {
    bool masked = (l > 0) && (mask[b * LL + l - 1] == 0);
    float p;
    if (masked) p = -3.4e38f;
    else {
      p = 0.f;
      const unsigned short* krow = ktb + ((size_t)b * LP1 + l) * 256 + n * 32;
#pragma unroll
      for (int d = 0; d < 32; d++) p = fmaf(qv[d], bf2f(krow[d]), p);
      p *= scale;
    }
    pre[l] = p;
  }
  __syncthreads();
  float m = -3.4e38f;
  for (int l = t; l < LP1; l += 256) m = fmaxf(m, pre[l]);
#pragma unroll
  for (int o = 32; o; o >>= 1) m = fmaxf(m, __shfl_xor(m, o));
  if (lane == 0) red[w] = m;
  __syncthreads();
  m = fmaxf(fmaxf(red[0], red[1]), fmaxf(red[2], red[3]));
  __syncthreads();
  float s = 0.f;
  for (int l = t; l < LP1; l += 256) {
    float wv = __expf(pre[l] - m);
    pre[l] = wv;
    s += wv;
  }
#pragma unroll
  for (int o = 32; o; o >>= 1) s += __shfl_xor(s, o);
  if (lane == 0) red[w] = s;
  __syncthreads();
  float denom = red[0] + red[1] + red[2] + red[3];
  int d = t & 31, g = t >> 5;
  float acc = 0.f;
  for (int l = g; l < LP1; l += 8)
    acc = fmaf(pre[l], bf2f(ktb[((size_t)b * LP1 + l) * 256 + n * 32 + d]), acc);
  par[g][d] = acc;
  __syncthreads();
  if (t < 32) {
    float a = 0.f;
    for (int gg = 0; gg < 8; gg++) a += par[gg][t];
    attstar[b * 256 + n * 32 + t] = a / denom;
  }
}

// ---------------------------------------------------------------------------
extern "C" void kernel_launch(void* const* d_in, const int* in_sizes, int n_in,
                              void* d_out, int out_size, void* d_ws, size_t ws_size,
                              hipStream_t stream) {
  const float* data  = (const float*)d_in[0];
  const float* WQw   = (const float*)d_in[1];
  const float* WQb   = (const float*)d_in[2];
  const float* a1    = (const float*)d_in[3];
  const float* a2    = (const float*)d_in[4];
  const float* fcw_g = (const float*)d_in[5];
  const float* fcb_g = (const float*)d_in[6];
  const float* ng    = (const float*)d_in[7];
  const float* nb    = (const float*)d_in[8];
  const float* sq_w  = (const float*)d_in[9];
  const float* sq_b  = (const float*)d_in[10];
  const float* sk_w  = (const float*)d_in[11];
  const float* sk_b  = (const float*)d_in[12];
  const float* so_w  = (const float*)d_in[13];
  const float* so_b  = (const float*)d_in[14];
  const float* fc_w  = (const float*)d_in[15];
  const float* fc_b  = (const float*)d_in[16];
  const int*   mask  = (const int*)d_in[17];
  const int*   edge  = (const int*)d_in[18];

  float* nodes = (float*)d_out;
  float* relay = nodes + NODES_ELEMS;

  char* p = (char*)d_ws;
  auto alloc = [&](size_t bytes) -> char* {
    char* r = p; p += (bytes + 255) & ~(size_t)255; return r;
  };
  unsigned short* xnb  = (unsigned short*)alloc((size_t)8192 * 256 * 2);
  unsigned short* datab= (unsigned short*)alloc((size_t)8192 * 256 * 2);
  unsigned short* GT   = (unsigned short*)alloc((size_t)8 * 16 * 32 * 512 * 2);
  unsigned short* tmpb = (unsigned short*)alloc((size_t)8192 * 256 * 2);
  unsigned short* ktb  = (unsigned short*)alloc((size_t)8208 * 256 * 2);
  unsigned char* ep    = (unsigned char*)alloc((size_t)8192 * 64);
  float* ei            = (float*)alloc(65536 * 4);
  float* ej            = (float*)alloc(65536 * 4);
  float* ra1           = (float*)alloc(128 * 4);
  float* ra2           = (float*)alloc(128 * 4);
  float* rf            = (float*)alloc(4096 * 4);
  float* bqf           = (float*)alloc(256 * 4);
  float* w1            = (float*)alloc(2048 * 4);
  float* w2            = (float*)alloc(2048 * 4);
  float* c1            = (float*)alloc(8 * 4);
  float* c2            = (float*)alloc(8 * 4);
  float* a1o           = (float*)alloc(2048 * 4);
  float* a2o           = (float*)alloc(2048 * 4);
  float* rpart         = (float*)alloc(128 * 256 * 4);
  unsigned short* Bcat = (unsigned short*)alloc((size_t)256 * 512 * 2);
  unsigned short* fcwT = (unsigned short*)alloc((size_t)65536 * 2);
  unsigned short* skwb = (unsigned short*)alloc((size_t)131072 * 2);
  float* sqT           = (float*)alloc((size_t)131072 * 4);
  float* soT           = (float*)alloc((size_t)131072 * 4);
  float* atts          = (float*)alloc(4096 * 4);

  // 2 precompute dispatches
  mega_prep_kernel<<<6288, 256, 0, stream>>>(data, edge, fc_w, fcw_g, sk_w, sq_w,
                                             so_w, WQw, WQb, a1, a2,
                                             datab, ep, fcwT, Bcat, skwb, sqT, soT,
                                             rpart, w1, w2, c1, c2, bqf, a1o, a2o);
  bcat_m1_kernel<<<128, 256, 0, stream>>>(WQw, fcw_g, Bcat);
  // relay + rarf extras for it=0
  relay_rarf_kernel<<<128, 256, 0, stream>>>(rpart, skwb, sk_b, a1, a2, fcw_g,
                                             fcb_g, bqf, relay, ktb, ra1, ra2, rf);

  for (int it = 0; it < 2; it++) {
    const float* src = (it == 0) ? data : nodes;
    lnei_kernel<<<2048, 256, 0, stream>>>(src, datab, ng + it * 256, nb + it * 256,
                                          w1, w2, a1o, a2o, c1, c2, ra1, ra2,
                                          xnb, ei, ej);
    g_gemm_kernel<<<dim3(4, 64), 256, 0, stream>>>(xnb, datab, Bcat, GT);
    gat_agg_kernel<<<NHEAD * BB * 16, 256, 0, stream>>>(GT, ei, ej, ep, rf, tmpb);
    fc_kt_kernel<<<256, 256, 0, stream>>>(tmpb, fcwT, fc_b,
                                          skwb + it * 65536, sk_b + it * 256,
                                          mask, src, nodes, ktb);
    star_attn_kernel<<<BB * NHEAD, 256, 0, stream>>>(relay, sqT + it * 65536,
                                                     sq_b + it * 256, ktb, mask, atts);
    so_rarf_kernel<<<128, 256, 0, stream>>>(atts, soT + it * 65536, so_b + it * 256,
                                            skwb + 65536, sk_b + 256,
                                            a1, a2, fcw_g, fcb_g, bqf,
                                            (it == 0) ? 1 : 0,
                                            relay, ktb, ra1, ra2, rf);
  }
}

// Round 12
// 363.586 us; speedup vs baseline: 1.3402x; 1.0625x over previous
//
#include <hip/hip_runtime.h>
#include <hip/hip_bf16.h>
#include <math.h>

#define BB 16
#define LL 512
#define HH 256
#define NHEAD 8
#define HDIM 32
#define LP1 513
#define NODES_ELEMS (BB*LL*HH)

typedef __attribute__((ext_vector_type(8))) short bf16x8;
typedef __attribute__((ext_vector_type(4))) float f32x4;

__device__ __forceinline__ unsigned short f2bf(float f) {
  union { float f; unsigned u; } x; x.f = f;
  unsigned r = x.u + 0x7fffu + ((x.u >> 16) & 1u);
  return (unsigned short)(r >> 16);
}
__device__ __forceinline__ float bf2f(unsigned short u) {
  union { unsigned u; float f; } x; x.u = (unsigned)u << 16; return x.f;
}

// ---------------------------------------------------------------------------
// MEGA-PREP v2: tail-free one-time precomputes (3162 blocks)
// A[0,128): data->bf16 + relay partials | B[128,2176): edge pack
// C[2176,2432): Bcat m2 (d-fastest)    | D[2432,2944): sk cvt
// E[2944,3024): 5 LDS-tiled transposes | F[3024,3152): w1/w2 (n,kc)
// G[3152,3160): bqf per n              | H=3160: c1/c2 | I=3161: a1o/a2o
__global__ __launch_bounds__(256) void mega_prep_kernel(
    const float* __restrict__ data, const int* __restrict__ edge,
    const float* __restrict__ fc_w, const float* __restrict__ fcw,
    const float* __restrict__ sk_w, const float* __restrict__ sq_w,
    const float* __restrict__ so_w, const float* __restrict__ WQw,
    const float* __restrict__ WQb, const float* __restrict__ a1,
    const float* __restrict__ a2,
    unsigned short* __restrict__ datab, unsigned char* __restrict__ ep,
    unsigned short* __restrict__ fcwT, unsigned short* __restrict__ Bcat,
    unsigned short* __restrict__ skwb, float* __restrict__ sqT,
    float* __restrict__ soT, float* __restrict__ rpart,
    float* __restrict__ w1, float* __restrict__ w2,
    float* __restrict__ c1, float* __restrict__ c2,
    float* __restrict__ bqf, float* __restrict__ a1o, float* __restrict__ a2o) {
  __shared__ float smem[64 * 65];   // 16.6 KB, aliased per-branch
  int blk = blockIdx.x, t = threadIdx.x;
  if (blk < 128) {                        // data -> bf16 + relay partial
    int b = blk >> 3, ch = blk & 7;
    const float* pr = data + ((size_t)b * 512 + ch * 64) * 256 + t;
    unsigned short* db = datab + ((size_t)b * 512 + ch * 64) * 256 + t;
    float s = 0.f;
    for (int l = 0; l < 64; l++) {
      float v = pr[(size_t)l * 256];
      db[(size_t)l * 256] = f2bf(v);
      s += v;
    }
    rpart[(size_t)blk * 256 + t] = s;
  } else if (blk < 2176) {                // edge pack
    int row = (blk - 128) * 4 + (t >> 6);
    int lane = t & 63;
    const int* adj = edge + ((size_t)row << 9);
    unsigned v = 0;
#pragma unroll
    for (int u = 0; u < 8; u++) v |= (adj[lane + 64 * u] > 0 ? 1u : 0u) << u;
    ep[((size_t)row << 6) + lane] = (unsigned char)v;
  } else if (blk < 2432) {                // Bcat m2, d-fastest reads
    int idx = (blk - 2176) * 256 + t;     // (n, c, d) with d fastest
    int d = idx & 31;
    int g = idx >> 5;
    int n = g >> 8, c = g & 255;
    Bcat[((size_t)n * 32 + d) * 512 + 256 + c] =
        f2bf(fcw[((size_t)n * 768 + 256 + 2 * c) * 32 + d]);
  } else if (blk < 2944) {                // sk cvt
    int idx = (blk - 2432) * 256 + t;
    skwb[idx] = f2bf(sk_w[idx]);
  } else if (blk < 3024) {                // tiled 64x64 transposes
    int q = blk - 2944;
    int mat = q >> 4, tl = q & 15;
    int r0 = (tl >> 2) * 64, c0 = (tl & 3) * 64;
    const float* in;
    if (mat == 0) in = fc_w;
    else if (mat <= 2) in = sq_w + (mat - 1) * 65536;
    else in = so_w + (mat - 3) * 65536;
    int cc = t & 63, rq = t >> 6;
#pragma unroll
    for (int i = 0; i < 16; i++) {
      int r = rq + i * 4;
      smem[r * 65 + cc] = in[(r0 + r) * 256 + c0 + cc];
    }
    __syncthreads();
#pragma unroll
    for (int i = 0; i < 16; i++) {
      int cp = rq + i * 4;
      float v = smem[cc * 65 + cp];
      if (mat == 0) fcwT[(c0 + cp) * 256 + r0 + cc] = f2bf(v);
      else if (mat <= 2) sqT[(mat - 1) * 65536 + (c0 + cp) * 256 + r0 + cc] = v;
      else soT[(mat - 3) * 65536 + (c0 + cp) * 256 + r0 + cc] = v;
    }
  } else if (blk < 3152) {                // w1/w2: block (n, kc), 16-way c split
    int q = blk - 3024;
    int n = q >> 4, kc = q & 15;
    int k = kc * 16 + (t & 15), cseg = t >> 4;
    float s1 = 0.f, s2 = 0.f;
#pragma unroll
    for (int u = 0; u < 16; u++) {
      int c = cseg * 16 + u;
      float wv = WQw[((size_t)(n * 256 + c)) * 256 + k];
      s1 = fmaf(a1[n * 768 + c], wv, s1);
      s2 = fmaf(a2[n * 768 + c], wv, s2);
    }
    smem[cseg * 16 + (t & 15)] = s1;
    smem[256 + cseg * 16 + (t & 15)] = s2;
    __syncthreads();
    if (cseg == 0) {
      float a = 0.f, b2 = 0.f;
#pragma unroll
      for (int u = 0; u < 16; u++) {
        a += smem[u * 16 + (t & 15)];
        b2 += smem[256 + u * 16 + (t & 15)];
      }
      w1[n * 256 + k] = a;
      w2[n * 256 + k] = b2;
    }
  } else if (blk < 3160) {                // bqf per n, 8-way c split
    int n = blk - 3152;
    int d = t & 31, seg = t >> 5;
    float s = 0.f;
#pragma unroll
    for (int u = 0; u < 32; u++) {
      int c = seg * 32 + u;
      s = fmaf(WQb[n * 256 + c], fcw[((size_t)n * 768 + c) * 32 + d], s);
    }
    smem[seg * 32 + d] = s;
    __syncthreads();
    if (seg == 0) {
      float a = 0.f;
#pragma unroll
      for (int u = 0; u < 8; u++) a += smem[u * 32 + d];
      bqf[n * 32 + d] = a;
    }
  } else if (blk == 3160) {               // c1/c2 all heads
    int n = t >> 5, sl = t & 31;
    float s1 = 0.f, s2 = 0.f;
#pragma unroll
    for (int u = 0; u < 8; u++) {
      int c = sl * 8 + u;
      float wb = WQb[n * 256 + c];
      s1 = fmaf(a1[n * 768 + c], wb, s1);
      s2 = fmaf(a2[n * 768 + c], wb, s2);
    }
    smem[t] = s1; smem[256 + t] = s2;
    __syncthreads();
    if (sl == 0) {
      float a = 0.f, b2 = 0.f;
      for (int u = 0; u < 32; u++) { a += smem[n * 32 + u]; b2 += smem[256 + n * 32 + u]; }
      c1[n] = a; c2[n] = b2;
    }
  } else {                                // a1o/a2o packing
#pragma unroll
    for (int n = 0; n < 8; n++) {
      a1o[n * 256 + t] = a1[n * 768 + 256 + 2 * t];
      a2o[n * 256 + t] = a2[n * 768 + 256 + 2 * t];
    }
  }
}

// Bcat M1: Bcat[(n*32+d)*512 + k] = sum_c WQw[n][c][k] * Fw[n][c][d]
__global__ __launch_bounds__(256) void bcat_m1_kernel(const float* __restrict__ WQw,
                                                      const float* __restrict__ fcw,
                                                      unsigned short* __restrict__ Bcat) {
  __shared__ float wq_s[256][16];
  __shared__ float fw_s[256][32];
  int n = blockIdx.x >> 4, kt = blockIdx.x & 15;
  int t = threadIdx.x;
#pragma unroll
  for (int i = 0; i < 16; i++) {
    int c = i * 16 + (t >> 4), kk = t & 15;
    wq_s[c][kk] = WQw[(size_t)n * 65536 + c * 256 + kt * 16 + kk];
  }
#pragma unroll
  for (int i = 0; i < 32; i++) {
    int idx = i * 256 + t;
    fw_s[idx >> 5][idx & 31] = fcw[(size_t)n * 24576 + idx];
  }
  __syncthreads();
  int kloc = t >> 4, dp = t & 15;
  float a0 = 0.f, a1v = 0.f;
  for (int c = 0; c < 256; c++) {
    float wv = wq_s[c][kloc];
    a0 = fmaf(wv, fw_s[c][dp * 2], a0);
    a1v = fmaf(wv, fw_s[c][dp * 2 + 1], a1v);
  }
  int k = kt * 16 + kloc;
  Bcat[((size_t)n * 32 + dp * 2) * 512 + k] = f2bf(a0);
  Bcat[((size_t)n * 32 + dp * 2 + 1) * 512 + k] = f2bf(a1v);
}

// ---------------------------------------------------------------------------
// shared rarf tail
__device__ __forceinline__ void rarf_tail(
    int n, int b, int t, const float* rel,
    const float* __restrict__ a1, const float* __restrict__ a2,
    const float* __restrict__ fcw, const float* __restrict__ fcb,
    const float* __restrict__ bqf,
    float* __restrict__ ra1, float* __restrict__ ra2, float* __restrict__ rf,
    float* red1, float* red2, float* pf_s) {
  int lane = t & 63, w = t >> 6;
  float p1 = rel[t] * a1[n * 768 + 257 + 2 * t];
  float p2 = rel[t] * a2[n * 768 + 257 + 2 * t];
#pragma unroll
  for (int o = 32; o; o >>= 1) { p1 += __shfl_xor(p1, o); p2 += __shfl_xor(p2, o); }
  if (lane == 0) { red1[w] = p1; red2[w] = p2; }
  int d = t & 31, seg = t >> 5;
  float pf = 0.f;
  for (int u = 0; u < 32; u++) {
    int k = seg * 32 + u;
    pf = fmaf(rel[k], fcw[((size_t)n * 768 + 257 + 2 * k) * 32 + d], pf);
  }
  pf_s[seg * 33 + d] = pf;
  __syncthreads();
  if (t == 0) {
    ra1[n * 16 + b] = red1[0] + red1[1] + red1[2] + red1[3];
    ra2[n * 16 + b] = red2[0] + red2[1] + red2[2] + red2[3];
  }
  if (t < 32) {
    float s = 0.f;
    for (int gg = 0; gg < 8; gg++) s += pf_s[gg * 33 + t];
    rf[((size_t)n * 16 + b) * 32 + t] = s + fcb[n * 32 + t] + bqf[n * 32 + t];
  }
}

// relay from partials + ktb relay row (n==0) + rarf extras: 128 blocks (n,b)
__global__ __launch_bounds__(256) void relay_rarf_kernel(
    const float* __restrict__ rpart,
    const unsigned short* __restrict__ skw0, const float* __restrict__ skb0,
    const float* __restrict__ a1, const float* __restrict__ a2,
    const float* __restrict__ fcw, const float* __restrict__ fcb,
    const float* __restrict__ bqf,
    float* __restrict__ relay, unsigned short* __restrict__ ktb,
    float* __restrict__ ra1, float* __restrict__ ra2, float* __restrict__ rf) {
  __shared__ float rel[256];
  __shared__ float red1[4], red2[4];
  __shared__ float pf_s[8 * 33];
  int n = blockIdx.x >> 4, b = blockIdx.x & 15;
  int t = threadIdx.x;
  float s = 0.f;
#pragma unroll
  for (int ch = 0; ch < 8; ch++) s += rpart[((size_t)(b * 8 + ch)) * 256 + t];
  s *= (1.0f / 512.0f);
  rel[t] = s;
  __syncthreads();
  if (n == 0) {
    relay[b * 256 + t] = s;
    float acc = 0.f;
    for (int k = 0; k < 256; k++) acc = fmaf(rel[k], bf2f(skw0[(size_t)t * 256 + k]), acc);
    ktb[((size_t)b * LP1) * 256 + t] = f2bf(acc + skb0[t]);
  }
  rarf_tail(n, b, t, rel, a1, a2, fcw, fcb, bqf, ra1, ra2, rf, red1, red2, pf_s);
}

// relay = lrelu(atts @ soT + sob) (+ ktb row + rarf extras when do_extras)
__global__ __launch_bounds__(256) void so_rarf_kernel(
    const float* __restrict__ atts,
    const float* __restrict__ soT_it, const float* __restrict__ sob_it,
    const unsigned short* __restrict__ skw_nx, const float* __restrict__ skb_nx,
    const float* __restrict__ a1, const float* __restrict__ a2,
    const float* __restrict__ fcw, const float* __restrict__ fcb,
    const float* __restrict__ bqf, int do_extras,
    float* __restrict__ relay, unsigned short* __restrict__ ktb,
    float* __restrict__ ra1, float* __restrict__ ra2, float* __restrict__ rf) {
  int n = blockIdx.x >> 4, b = blockIdx.x & 15;
  if (!do_extras && n > 0) return;
  __shared__ float xr[256];
  __shared__ float rel[256];
  __shared__ float red1[4], red2[4];
  __shared__ float pf_s[8 * 33];
  int t = threadIdx.x;
  xr[t] = atts[b * 256 + t];
  __syncthreads();
  float acc = 0.f;
  for (int k = 0; k < 256; k++) acc = fmaf(xr[k], soT_it[(size_t)k * 256 + t], acc);
  float v = acc + sob_it[t];
  v = v > 0.f ? v : 0.01f * v;
  rel[t] = v;
  __syncthreads();
  if (n == 0) relay[b * 256 + t] = v;
  if (!do_extras) return;
  if (n == 0) {
    float a2v = 0.f;
    for (int k = 0; k < 256; k++) a2v = fmaf(rel[k], bf2f(skw_nx[(size_t)t * 256 + k]), a2v);
    ktb[((size_t)b * LP1) * 256 + t] = f2bf(a2v + skb_nx[t]);
  }
  rarf_tail(n, b, t, rel, a1, a2, fcw, fcb, bqf, ra1, ra2, rf, red1, red2, pf_s);
}

// ---------------------------------------------------------------------------
// Fused LayerNorm + ei/ej
__global__ __launch_bounds__(256) void lnei_kernel(const float* __restrict__ src,
                                                   const unsigned short* __restrict__ datab,
                                                   const float* __restrict__ g,
                                                   const float* __restrict__ bb,
                                                   const float* __restrict__ w1,
                                                   const float* __restrict__ w2,
                                                   const float* __restrict__ a1o,
                                                   const float* __restrict__ a2o,
                                                   const float* __restrict__ c1,
                                                   const float* __restrict__ c2,
                                                   const float* __restrict__ ra1,
                                                   const float* __restrict__ ra2,
                                                   unsigned short* __restrict__ xnb,
                                                   float* __restrict__ ei,
                                                   float* __restrict__ ej) {
  int r = blockIdx.x * 4 + (threadIdx.x >> 6);
  int b = r >> 9;
  int lane = threadIdx.x & 63;
  float x[4], dv[4];
#pragma unroll
  for (int u = 0; u < 4; u++) {
    int c = lane + 64 * u;
    x[u] = src[(size_t)r * 256 + c];
    dv[u] = bf2f(datab[(size_t)r * 256 + c]);
  }
  float s = x[0] + x[1] + x[2] + x[3];
#pragma unroll
  for (int o = 32; o; o >>= 1) s += __shfl_xor(s, o);
  float mean = s * (1.0f / 256.0f);
  float v = 0.f;
#pragma unroll
  for (int u = 0; u < 4; u++) { x[u] -= mean; v = fmaf(x[u], x[u], v); }
#pragma unroll
  for (int o = 32; o; o >>= 1) v += __shfl_xor(v, o);
  float rstd = rsqrtf(v * (1.0f / 256.0f) + 1e-5f);
  float xv[4];
#pragma unroll
  for (int u = 0; u < 4; u++) {
    int c = lane + 64 * u;
    xv[u] = x[u] * rstd * g[c] + bb[c];
    xnb[(size_t)r * 256 + c] = f2bf(xv[u]);
  }
  float s1a[8], s2a[8];
#pragma unroll
  for (int n = 0; n < 8; n++) {
    float s1 = 0.f, s2 = 0.f;
#pragma unroll
    for (int u = 0; u < 4; u++) {
      int c = lane + 64 * u;
      s1 = fmaf(xv[u], w1[n * 256 + c], s1);
      s1 = fmaf(dv[u], a1o[n * 256 + c], s1);
      s2 = fmaf(xv[u], w2[n * 256 + c], s2);
      s2 = fmaf(dv[u], a2o[n * 256 + c], s2);
    }
    s1a[n] = s1; s2a[n] = s2;
  }
#pragma unroll
  for (int o = 32; o; o >>= 1) {
#pragma unroll
    for (int n = 0; n < 8; n++) {
      s1a[n] += __shfl_xor(s1a[n], o);
      s2a[n] += __shfl_xor(s2a[n], o);
    }
  }
  if (lane == 0) {
#pragma unroll
    for (int n = 0; n < 8; n++) {
      ei[n * 8192 + r] = s1a[n] + c1[n] + ra1[n * 16 + b];
      ej[n * 8192 + r] = s2a[n] + c2[n] + ra2[n * 16 + b];
    }
  }
}

// ---------------------------------------------------------------------------
// G-GEMM
__global__ __launch_bounds__(256) void g_gemm_kernel(
    const unsigned short* __restrict__ A1, const unsigned short* __restrict__ A2,
    const unsigned short* __restrict__ Bcat, unsigned short* __restrict__ GT) {
  int tileN = blockIdx.x * 64;
  int tileM = blockIdx.y * 128;
  int t = threadIdx.x;
  int wv = t >> 6, lane = t & 63;
  int lo = lane & 15, quad = lane >> 4;
  int rowBase0 = tileM + wv * 32;
  const unsigned short* ap1[2];
  const unsigned short* ap2[2];
#pragma unroll
  for (int rt = 0; rt < 2; rt++) {
    int arow = rowBase0 + rt * 16 + lo;
    ap1[rt] = A1 + (size_t)arow * 256 + quad * 8;
    ap2[rt] = A2 + (size_t)arow * 256 + quad * 8;
  }
  f32x4 acc[2][4] = {};
  for (int k0 = 0; k0 < 512; k0 += 32) {
    bf16x8 af[2];
#pragma unroll
    for (int rt = 0; rt < 2; rt++)
      af[rt] = (k0 < 256) ? *(const bf16x8*)(ap1[rt] + k0)
                          : *(const bf16x8*)(ap2[rt] + k0 - 256);
#pragma unroll
    for (int ct = 0; ct < 4; ct++) {
      bf16x8 bf_ = *(const bf16x8*)(Bcat + (size_t)(tileN + ct * 16 + lo) * 512 + k0 + quad * 8);
#pragma unroll
      for (int rt = 0; rt < 2; rt++)
        acc[rt][ct] = __builtin_amdgcn_mfma_f32_16x16x32_bf16(af[rt], bf_, acc[rt][ct], 0, 0, 0);
    }
  }
#pragma unroll
  for (int rt = 0; rt < 2; rt++) {
#pragma unroll
    for (int ct = 0; ct < 4; ct++) {
      int co = tileN + ct * 16 + lo;
      int n = co >> 5, d = co & 31;
      int jrow = rowBase0 + rt * 16 + quad * 4;
      int b2 = jrow >> 9, jj = jrow & 511;
      ushort4 pk;
      pk.x = f2bf(acc[rt][ct][0]);
      pk.y = f2bf(acc[rt][ct][1]);
      pk.z = f2bf(acc[rt][ct][2]);
      pk.w = f2bf(acc[rt][ct][3]);
      *(ushort4*)&GT[(((size_t)(n * 16 + b2) * 32 + d) << 9) + jj] = pk;
    }
  }
}

// ---------------------------------------------------------------------------
// GAT: reduction-free softmax + MFMA aggregation
__global__ __launch_bounds__(256) void gat_agg_kernel(
    const unsigned short* __restrict__ GT,
    const float* __restrict__ ei, const float* __restrict__ ej,
    const unsigned char* __restrict__ ep,
    const float* __restrict__ rf,
    unsigned short* __restrict__ tempb) {
  __shared__ unsigned short W[32][512];
  __shared__ float denom_s[32];
  int blk = blockIdx.x;
  int n = blk >> 8;
  int b = (blk >> 4) & 15;
  int i0 = (blk & 15) << 5;
  int t = threadIdx.x;
  int wv = t >> 6, lane = t & 63;
  int lo = lane & 15, quad = lane >> 4;

  const float* ejrow = ej + n * 8192 + b * 512;
  float ejv[8];
#pragma unroll
  for (int u = 0; u < 8; u++) ejv[u] = ejrow[lane + 64 * u];
  float mm = ejv[0];
#pragma unroll
  for (int u = 1; u < 8; u++) mm = fmaxf(mm, ejv[u]);
#pragma unroll
  for (int o = 32; o; o >>= 1) mm = fmaxf(mm, __shfl_xor(mm, o));

  for (int rr = 0; rr < 8; rr++) {
    int row = wv * 8 + rr;
    float eiv = ei[n * 8192 + b * 512 + i0 + row];
    float M = eiv + mm;
    M = M > 0.f ? M : 0.2f * M;
    unsigned pb = ep[(((size_t)(b * 512 + i0 + row)) << 6) + lane];
    int rx = (row & 7) << 3;
#pragma unroll
    for (int u = 0; u < 8; u++) {
      float e = eiv + ejv[u];
      e = e > 0.f ? e : 0.2f * e;
      float w = ((pb >> u) & 1) ? __expf(e - M) : 0.f;
      int col = lane + 64 * u;
      W[row][((col >> 3 << 3) ^ rx) + (col & 7)] = f2bf(w);
    }
  }
  __syncthreads();

  int rt = wv >> 1, dh = wv & 1;
  int arow = rt * 16 + lo;
  int rx = arow & 7;
  const unsigned short* gtb = GT + (((size_t)(n * 16 + b) * 32) << 9);
  bf16x8 bones;
  {
    short ov = (lo == 0) ? (short)0x3F80 : (short)0;
#pragma unroll
    for (int j = 0; j < 8; j++) bones[j] = ov;
  }
  f32x4 acc = {}, accd = {};
  for (int k0 = 0; k0 < 512; k0 += 32) {
    int chunk = (k0 >> 3) + quad;
    bf16x8 a0 = *(const bf16x8*)&W[arow][(chunk ^ rx) << 3];
    bf16x8 bf_ = *(const bf16x8*)(gtb + (((size_t)(dh * 16 + lo)) << 9) + k0 + quad * 8);
    acc = __builtin_amdgcn_mfma_f32_16x16x32_bf16(a0, bf_, acc, 0, 0, 0);
    if (dh == 0)
      accd = __builtin_amdgcn_mfma_f32_16x16x32_bf16(a0, bones, accd, 0, 0, 0);
  }
  if (dh == 0 && lo == 0) {
#pragma unroll
    for (int r = 0; r < 4; r++) denom_s[rt * 16 + quad * 4 + r] = accd[r];
  }
  __syncthreads();
  int d = dh * 16 + lo;
  float base = rf[((size_t)n * 16 + b) * 32 + d];
#pragma unroll
  for (int r = 0; r < 4; r++) {
    int row = rt * 16 + quad * 4 + r;
    float inv = 1.0f / fmaxf(denom_s[row], 1e-35f);
    float v = acc[r] * inv + base;
    v = v > 0.f ? v : expm1f(v);
    tempb[((size_t)(b * 512 + i0 + row)) * 256 + n * 32 + d] = f2bf(v);
  }
}

// ---------------------------------------------------------------------------
// Fused fc + kt GEMMs
__global__ __launch_bounds__(256) void fc_kt_kernel(
    const unsigned short* __restrict__ tempb,
    const unsigned short* __restrict__ fcwT,
    const float* __restrict__ fc_b,
    const unsigned short* __restrict__ skw_it,
    const float* __restrict__ skb_it,
    const int* __restrict__ mask,
    const float* __restrict__ resid,
    float* __restrict__ nodes,
    unsigned short* __restrict__ ktb) {
  __shared__ unsigned short tmp[32][264];
  int blk = blockIdx.x;
  int b = blk >> 4;
  int i0 = (blk & 15) << 5;
  int t = threadIdx.x;
  int wv = t >> 6, lane = t & 63;
  int lo = lane & 15, quad = lane >> 4;
  int ch = wv >> 1, rt2 = wv & 1;

  const unsigned short* arow_p = tempb + ((size_t)(b * 512 + i0 + rt2 * 16 + lo)) * 256 + quad * 8;
  f32x4 facc[8] = {};
  for (int k0 = 0; k0 < 256; k0 += 32) {
    bf16x8 a0 = *(const bf16x8*)(arow_p + k0);
#pragma unroll
    for (int ct = 0; ct < 8; ct++) {
      int co = ch * 128 + ct * 16 + lo;
      bf16x8 bf_ = *(const bf16x8*)(fcwT + (size_t)co * 256 + k0 + quad * 8);
      facc[ct] = __builtin_amdgcn_mfma_f32_16x16x32_bf16(a0, bf_, facc[ct], 0, 0, 0);
    }
  }
#pragma unroll
  for (int ct = 0; ct < 8; ct++) {
    int co = ch * 128 + ct * 16 + lo;
    float bv = fc_b[co];
#pragma unroll
    for (int r = 0; r < 4; r++) {
      int row = rt2 * 16 + quad * 4 + r;
      int grow = b * 512 + i0 + row;
      float v = facc[ct][r] + bv;
      v = v > 0.f ? v : 0.01f * v;
      v = (mask[grow] != 0) ? resid[(size_t)grow * 256 + co] + v : 0.f;
      nodes[(size_t)grow * 256 + co] = v;
      tmp[row][co] = f2bf(v);
    }
  }
  __syncthreads();

  f32x4 kacc[8] = {};
  for (int k0 = 0; k0 < 256; k0 += 32) {
    bf16x8 a0 = *(const bf16x8*)&tmp[rt2 * 16 + lo][k0 + quad * 8];
#pragma unroll
    for (int ct = 0; ct < 8; ct++) {
      int co = ch * 128 + ct * 16 + lo;
      bf16x8 bf_ = *(const bf16x8*)(skw_it + (size_t)co * 256 + k0 + quad * 8);
      kacc[ct] = __builtin_amdgcn_mfma_f32_16x16x32_bf16(a0, bf_, kacc[ct], 0, 0, 0);
    }
  }
#pragma unroll
  for (int ct = 0; ct < 8; ct++) {
    int co = ch * 128 + ct * 16 + lo;
    float bv = skb_it[co];
#pragma unroll
    for (int r = 0; r < 4; r++) {
      int row = rt2 * 16 + quad * 4 + r;
      int yrow = b * LP1 + 1 + i0 + row;
      ktb[(size_t)yrow * 256 + co] = f2bf(kacc[ct][r] + bv);
    }
  }
}

// ---------------------------------------------------------------------------
// star attention on bf16 kt
__global__ __launch_bounds__(256) void star_attn_kernel(const float* __restrict__ relay,
                                                        const float* __restrict__ sqT_it,
                                                        const float* __restrict__ sqb_it,
                                                        const unsigned short* __restrict__ ktb,
                                                        const int* __restrict__ mask,
                                                        float* __restrict__ attstar) {
  int b = blockIdx.x >> 3, n = blockIdx.x & 7;
  int t = threadIdx.x;
  int lane = t & 63, w = t >> 6;
  __shared__ float relb[256];
  __shared__ float qv[32];
  __shared__ float pre[LP1];
  __shared__ float red[4];
  __shared__ float par[8][33];
  relb[t] = relay[b * 256 + t];
  __syncthreads();
  {
    int d = t & 31, g = t >> 5;
    float qp = 0.f;
    for (int k = 0; k < 32; k++)
      qp = fmaf(relb[g * 32 + k], sqT_it[(size_t)(g * 32 + k) * 256 + n * 32 + d], qp);
    par[g][d] = qp;
  }
  __syncthreads();
  if (t < 32) {
    float q = 0.f;
#pragma unroll
    for (int gg = 0; gg < 8; gg++) q += par[gg][t];
    qv[t] = q + sqb_it[n * 32 + t];
  }
  __syncthreads();
  const float scale = 0.17677669529663687f;
  for (int l = t; l < LP1; l += 256) {
    bool masked = (l > 0) && (mask[b * LL + l - 1] == 0);
    float p;
    if (masked) p = -3.4e38f;
    else {
      p = 0.f;
      const unsigned short* krow = ktb + ((size_t)b * LP1 + l) * 256 + n * 32;
#pragma unroll
      for (int d = 0; d < 32; d++) p = fmaf(qv[d], bf2f(krow[d]), p);
      p *= scale;
    }
    pre[l] = p;
  }
  __syncthreads();
  float m = -3.4e38f;
  for (int l = t; l < LP1; l += 256) m = fmaxf(m, pre[l]);
#pragma unroll
  for (int o = 32; o; o >>= 1) m = fmaxf(m, __shfl_xor(m, o));
  if (lane == 0) red[w] = m;
  __syncthreads();
  m = fmaxf(fmaxf(red[0], red[1]), fmaxf(red[2], red[3]));
  __syncthreads();
  float s = 0.f;
  for (int l = t; l < LP1; l += 256) {
    float wv = __expf(pre[l] - m);
    pre[l] = wv;
    s += wv;
  }
#pragma unroll
  for (int o = 32; o; o >>= 1) s += __shfl_xor(s, o);
  if (lane == 0) red[w] = s;
  __syncthreads();
  float denom = red[0] + red[1] + red[2] + red[3];
  int d = t & 31, g = t >> 5;
  float acc = 0.f;
  for (int l = g; l < LP1; l += 8)
    acc = fmaf(pre[l], bf2f(ktb[((size_t)b * LP1 + l) * 256 + n * 32 + d]), acc);
  par[g][d] = acc;
  __syncthreads();
  if (t < 32) {
    float a = 0.f;
    for (int gg = 0; gg < 8; gg++) a += par[gg][t];
    attstar[b * 256 + n * 32 + t] = a / denom;
  }
}

// ---------------------------------------------------------------------------
extern "C" void kernel_launch(void* const* d_in, const int* in_sizes, int n_in,
                              void* d_out, int out_size, void* d_ws, size_t ws_size,
                              hipStream_t stream) {
  const float* data  = (const float*)d_in[0];
  const float* WQw   = (const float*)d_in[1];
  const float* WQb   = (const float*)d_in[2];
  const float* a1    = (const float*)d_in[3];
  const float* a2    = (const float*)d_in[4];
  const float* fcw_g = (const float*)d_in[5];
  const float* fcb_g = (const float*)d_in[6];
  const float* ng    = (const float*)d_in[7];
  const float* nb    = (const float*)d_in[8];
  const float* sq_w  = (const float*)d_in[9];
  const float* sq_b  = (const float*)d_in[10];
  const float* sk_w  = (const float*)d_in[11];
  const float* sk_b  = (const float*)d_in[12];
  const float* so_w  = (const float*)d_in[13];
  const float* so_b  = (const float*)d_in[14];
  const float* fc_w  = (const float*)d_in[15];
  const float* fc_b  = (const float*)d_in[16];
  const int*   mask  = (const int*)d_in[17];
  const int*   edge  = (const int*)d_in[18];

  float* nodes = (float*)d_out;
  float* relay = nodes + NODES_ELEMS;

  char* p = (char*)d_ws;
  auto alloc = [&](size_t bytes) -> char* {
    char* r = p; p += (bytes + 255) & ~(size_t)255; return r;
  };
  unsigned short* xnb  = (unsigned short*)alloc((size_t)8192 * 256 * 2);
  unsigned short* datab= (unsigned short*)alloc((size_t)8192 * 256 * 2);
  unsigned short* GT   = (unsigned short*)alloc((size_t)8 * 16 * 32 * 512 * 2);
  unsigned short* tmpb = (unsigned short*)alloc((size_t)8192 * 256 * 2);
  unsigned short* ktb  = (unsigned short*)alloc((size_t)8208 * 256 * 2);
  unsigned char* ep    = (unsigned char*)alloc((size_t)8192 * 64);
  float* ei            = (float*)alloc(65536 * 4);
  float* ej            = (float*)alloc(65536 * 4);
  float* ra1           = (float*)alloc(128 * 4);
  float* ra2           = (float*)alloc(128 * 4);
  float* rf            = (float*)alloc(4096 * 4);
  float* bqf           = (float*)alloc(256 * 4);
  float* w1            = (float*)alloc(2048 * 4);
  float* w2            = (float*)alloc(2048 * 4);
  float* c1            = (float*)alloc(8 * 4);
  float* c2            = (float*)alloc(8 * 4);
  float* a1o           = (float*)alloc(2048 * 4);
  float* a2o           = (float*)alloc(2048 * 4);
  float* rpart         = (float*)alloc(128 * 256 * 4);
  unsigned short* Bcat = (unsigned short*)alloc((size_t)256 * 512 * 2);
  unsigned short* fcwT = (unsigned short*)alloc((size_t)65536 * 2);
  unsigned short* skwb = (unsigned short*)alloc((size_t)131072 * 2);
  float* sqT           = (float*)alloc((size_t)131072 * 4);
  float* soT           = (float*)alloc((size_t)131072 * 4);
  float* atts          = (float*)alloc(4096 * 4);

  mega_prep_kernel<<<3162, 256, 0, stream>>>(data, edge, fc_w, fcw_g, sk_w, sq_w,
                                             so_w, WQw, WQb, a1, a2,
                                             datab, ep, fcwT, Bcat, skwb, sqT, soT,
                                             rpart, w1, w2, c1, c2, bqf, a1o, a2o);
  bcat_m1_kernel<<<128, 256, 0, stream>>>(WQw, fcw_g, Bcat);
  relay_rarf_kernel<<<128, 256, 0, stream>>>(rpart, skwb, sk_b, a1, a2, fcw_g,
                                             fcb_g, bqf, relay, ktb, ra1, ra2, rf);

  for (int it = 0; it < 2; it++) {
    const float* src = (it == 0) ? data : nodes;
    lnei_kernel<<<2048, 256, 0, stream>>>(src, datab, ng + it * 256, nb + it * 256,
                                          w1, w2, a1o, a2o, c1, c2, ra1, ra2,
                                          xnb, ei, ej);
    g_gemm_kernel<<<dim3(4, 64), 256, 0, stream>>>(xnb, datab, Bcat, GT);
    gat_agg_kernel<<<NHEAD * BB * 16, 256, 0, stream>>>(GT, ei, ej, ep, rf, tmpb);
    fc_kt_kernel<<<256, 256, 0, stream>>>(tmpb, fcwT, fc_b,
                                          skwb + it * 65536, sk_b + it * 256,
                                          mask, src, nodes, ktb);
    star_attn_kernel<<<BB * NHEAD, 256, 0, stream>>>(relay, sqT + it * 65536,
                                                     sq_b + it * 256, ktb, mask, atts);
    so_rarf_kernel<<<128, 256, 0, stream>>>(atts, soT + it * 65536, so_b + it * 256,
                                            skwb + 65536, sk_b + 256,
                                            a1, a2, fcw_g, fcb_g, bqf,
                                            (it == 0) ? 1 : 0,
                                            relay, ktb, ra1, ra2, rf);
  }
}

// Round 13
// 353.426 us; speedup vs baseline: 1.3787x; 1.0287x over previous
//
#include <hip/hip_runtime.h>
#include <hip/hip_bf16.h>
#include <math.h>

#define BB 16
#define LL 512
#define HH 256
#define NHEAD 8
#define HDIM 32
#define LP1 513
#define NODES_ELEMS (BB*LL*HH)

typedef __attribute__((ext_vector_type(8))) short bf16x8;
typedef __attribute__((ext_vector_type(4))) float f32x4;

__device__ __forceinline__ unsigned short f2bf(float f) {
  union { float f; unsigned u; } x; x.f = f;
  unsigned r = x.u + 0x7fffu + ((x.u >> 16) & 1u);
  return (unsigned short)(r >> 16);
}
__device__ __forceinline__ float bf2f(unsigned short u) {
  union { unsigned u; float f; } x; x.u = (unsigned)u << 16; return x.f;
}

// ---------------------------------------------------------------------------
// MEGA-PREP v2 (3162 blocks) — unchanged from R12
__global__ __launch_bounds__(256) void mega_prep_kernel(
    const float* __restrict__ data, const int* __restrict__ edge,
    const float* __restrict__ fc_w, const float* __restrict__ fcw,
    const float* __restrict__ sk_w, const float* __restrict__ sq_w,
    const float* __restrict__ so_w, const float* __restrict__ WQw,
    const float* __restrict__ WQb, const float* __restrict__ a1,
    const float* __restrict__ a2,
    unsigned short* __restrict__ datab, unsigned char* __restrict__ ep,
    unsigned short* __restrict__ fcwT, unsigned short* __restrict__ Bcat,
    unsigned short* __restrict__ skwb, float* __restrict__ sqT,
    float* __restrict__ soT, float* __restrict__ rpart,
    float* __restrict__ w1, float* __restrict__ w2,
    float* __restrict__ c1, float* __restrict__ c2,
    float* __restrict__ bqf, float* __restrict__ a1o, float* __restrict__ a2o) {
  __shared__ float smem[64 * 65];
  int blk = blockIdx.x, t = threadIdx.x;
  if (blk < 128) {
    int b = blk >> 3, ch = blk & 7;
    const float* pr = data + ((size_t)b * 512 + ch * 64) * 256 + t;
    unsigned short* db = datab + ((size_t)b * 512 + ch * 64) * 256 + t;
    float s = 0.f;
    for (int l = 0; l < 64; l++) {
      float v = pr[(size_t)l * 256];
      db[(size_t)l * 256] = f2bf(v);
      s += v;
    }
    rpart[(size_t)blk * 256 + t] = s;
  } else if (blk < 2176) {
    int row = (blk - 128) * 4 + (t >> 6);
    int lane = t & 63;
    const int* adj = edge + ((size_t)row << 9);
    unsigned v = 0;
#pragma unroll
    for (int u = 0; u < 8; u++) v |= (adj[lane + 64 * u] > 0 ? 1u : 0u) << u;
    ep[((size_t)row << 6) + lane] = (unsigned char)v;
  } else if (blk < 2432) {
    int idx = (blk - 2176) * 256 + t;
    int d = idx & 31;
    int g = idx >> 5;
    int n = g >> 8, c = g & 255;
    Bcat[((size_t)n * 32 + d) * 512 + 256 + c] =
        f2bf(fcw[((size_t)n * 768 + 256 + 2 * c) * 32 + d]);
  } else if (blk < 2944) {
    int idx = (blk - 2432) * 256 + t;
    skwb[idx] = f2bf(sk_w[idx]);
  } else if (blk < 3024) {
    int q = blk - 2944;
    int mat = q >> 4, tl = q & 15;
    int r0 = (tl >> 2) * 64, c0 = (tl & 3) * 64;
    const float* in;
    if (mat == 0) in = fc_w;
    else if (mat <= 2) in = sq_w + (mat - 1) * 65536;
    else in = so_w + (mat - 3) * 65536;
    int cc = t & 63, rq = t >> 6;
#pragma unroll
    for (int i = 0; i < 16; i++) {
      int r = rq + i * 4;
      smem[r * 65 + cc] = in[(r0 + r) * 256 + c0 + cc];
    }
    __syncthreads();
#pragma unroll
    for (int i = 0; i < 16; i++) {
      int cp = rq + i * 4;
      float v = smem[cc * 65 + cp];
      if (mat == 0) fcwT[(c0 + cp) * 256 + r0 + cc] = f2bf(v);
      else if (mat <= 2) sqT[(mat - 1) * 65536 + (c0 + cp) * 256 + r0 + cc] = v;
      else soT[(mat - 3) * 65536 + (c0 + cp) * 256 + r0 + cc] = v;
    }
  } else if (blk < 3152) {
    int q = blk - 3024;
    int n = q >> 4, kc = q & 15;
    int k = kc * 16 + (t & 15), cseg = t >> 4;
    float s1 = 0.f, s2 = 0.f;
#pragma unroll
    for (int u = 0; u < 16; u++) {
      int c = cseg * 16 + u;
      float wv = WQw[((size_t)(n * 256 + c)) * 256 + k];
      s1 = fmaf(a1[n * 768 + c], wv, s1);
      s2 = fmaf(a2[n * 768 + c], wv, s2);
    }
    smem[cseg * 16 + (t & 15)] = s1;
    smem[256 + cseg * 16 + (t & 15)] = s2;
    __syncthreads();
    if (cseg == 0) {
      float a = 0.f, b2 = 0.f;
#pragma unroll
      for (int u = 0; u < 16; u++) {
        a += smem[u * 16 + (t & 15)];
        b2 += smem[256 + u * 16 + (t & 15)];
      }
      w1[n * 256 + k] = a;
      w2[n * 256 + k] = b2;
    }
  } else if (blk < 3160) {
    int n = blk - 3152;
    int d = t & 31, seg = t >> 5;
    float s = 0.f;
#pragma unroll
    for (int u = 0; u < 32; u++) {
      int c = seg * 32 + u;
      s = fmaf(WQb[n * 256 + c], fcw[((size_t)n * 768 + c) * 32 + d], s);
    }
    smem[seg * 32 + d] = s;
    __syncthreads();
    if (seg == 0) {
      float a = 0.f;
#pragma unroll
      for (int u = 0; u < 8; u++) a += smem[u * 32 + d];
      bqf[n * 32 + d] = a;
    }
  } else if (blk == 3160) {
    int n = t >> 5, sl = t & 31;
    float s1 = 0.f, s2 = 0.f;
#pragma unroll
    for (int u = 0; u < 8; u++) {
      int c = sl * 8 + u;
      float wb = WQb[n * 256 + c];
      s1 = fmaf(a1[n * 768 + c], wb, s1);
      s2 = fmaf(a2[n * 768 + c], wb, s2);
    }
    smem[t] = s1; smem[256 + t] = s2;
    __syncthreads();
    if (sl == 0) {
      float a = 0.f, b2 = 0.f;
      for (int u = 0; u < 32; u++) { a += smem[n * 32 + u]; b2 += smem[256 + n * 32 + u]; }
      c1[n] = a; c2[n] = b2;
    }
  } else {
#pragma unroll
    for (int n = 0; n < 8; n++) {
      a1o[n * 256 + t] = a1[n * 768 + 256 + 2 * t];
      a2o[n * 256 + t] = a2[n * 768 + 256 + 2 * t];
    }
  }
}

// ---------------------------------------------------------------------------
// shared rarf tail
__device__ __forceinline__ void rarf_tail(
    int n, int b, int t, const float* rel,
    const float* __restrict__ a1, const float* __restrict__ a2,
    const float* __restrict__ fcw, const float* __restrict__ fcb,
    const float* __restrict__ bqf,
    float* __restrict__ ra1, float* __restrict__ ra2, float* __restrict__ rf,
    float* red1, float* red2, float* pf_s) {
  int lane = t & 63, w = t >> 6;
  float p1 = rel[t] * a1[n * 768 + 257 + 2 * t];
  float p2 = rel[t] * a2[n * 768 + 257 + 2 * t];
#pragma unroll
  for (int o = 32; o; o >>= 1) { p1 += __shfl_xor(p1, o); p2 += __shfl_xor(p2, o); }
  if (lane == 0) { red1[w] = p1; red2[w] = p2; }
  int d = t & 31, seg = t >> 5;
  float pf = 0.f;
  for (int u = 0; u < 32; u++) {
    int k = seg * 32 + u;
    pf = fmaf(rel[k], fcw[((size_t)n * 768 + 257 + 2 * k) * 32 + d], pf);
  }
  pf_s[seg * 33 + d] = pf;
  __syncthreads();
  if (t == 0) {
    ra1[n * 16 + b] = red1[0] + red1[1] + red1[2] + red1[3];
    ra2[n * 16 + b] = red2[0] + red2[1] + red2[2] + red2[3];
  }
  if (t < 32) {
    float s = 0.f;
    for (int gg = 0; gg < 8; gg++) s += pf_s[gg * 33 + t];
    rf[((size_t)n * 16 + b) * 32 + t] = s + fcb[n * 32 + t] + bqf[n * 32 + t];
  }
}

// ---------------------------------------------------------------------------
// MERGED: blocks 0-127 = Bcat M1; blocks 128-255 = relay + rarf extras
__global__ __launch_bounds__(256) void prep2_kernel(
    const float* __restrict__ WQw, const float* __restrict__ fcw,
    unsigned short* __restrict__ Bcat,
    const float* __restrict__ rpart,
    const unsigned short* __restrict__ skw0, const float* __restrict__ skb0,
    const float* __restrict__ a1, const float* __restrict__ a2,
    const float* __restrict__ fcb, const float* __restrict__ bqf,
    float* __restrict__ relay, unsigned short* __restrict__ ktb,
    float* __restrict__ ra1, float* __restrict__ ra2, float* __restrict__ rf) {
  __shared__ float smem[12288];   // 48KB union
  int blk = blockIdx.x, t = threadIdx.x;
  if (blk < 128) {
    // ---- Bcat M1
    float* wq_s = smem;           // [256][16]
    float* fw_s = smem + 4096;    // [256][32]
    int n = blk >> 4, kt = blk & 15;
#pragma unroll
    for (int i = 0; i < 16; i++) {
      int c = i * 16 + (t >> 4), kk = t & 15;
      wq_s[c * 16 + kk] = WQw[(size_t)n * 65536 + c * 256 + kt * 16 + kk];
    }
#pragma unroll
    for (int i = 0; i < 32; i++) {
      int idx = i * 256 + t;
      fw_s[(idx >> 5) * 32 + (idx & 31)] = fcw[(size_t)n * 24576 + idx];
    }
    __syncthreads();
    int kloc = t >> 4, dp = t & 15;
    float a0 = 0.f, a1v = 0.f;
    for (int c = 0; c < 256; c++) {
      float wv = wq_s[c * 16 + kloc];
      a0 = fmaf(wv, fw_s[c * 32 + dp * 2], a0);
      a1v = fmaf(wv, fw_s[c * 32 + dp * 2 + 1], a1v);
    }
    int k = kt * 16 + kloc;
    Bcat[((size_t)n * 32 + dp * 2) * 512 + k] = f2bf(a0);
    Bcat[((size_t)n * 32 + dp * 2 + 1) * 512 + k] = f2bf(a1v);
  } else {
    // ---- relay + rarf
    float* rel = smem;
    float* red1 = smem + 256;
    float* red2 = smem + 264;
    float* pf_s = smem + 272;
    int id = blk - 128;
    int n = id >> 4, b = id & 15;
    float s = 0.f;
#pragma unroll
    for (int ch = 0; ch < 8; ch++) s += rpart[((size_t)(b * 8 + ch)) * 256 + t];
    s *= (1.0f / 512.0f);
    rel[t] = s;
    __syncthreads();
    if (n == 0) {
      relay[b * 256 + t] = s;
      float acc = 0.f;
      for (int k = 0; k < 256; k++) acc = fmaf(rel[k], bf2f(skw0[(size_t)t * 256 + k]), acc);
      ktb[((size_t)b * LP1) * 256 + t] = f2bf(acc + skb0[t]);
    }
    rarf_tail(n, b, t, rel, a1, a2, fcw, fcb, bqf, ra1, ra2, rf, red1, red2, pf_s);
  }
}

// relay = lrelu(atts @ soT + sob) (+ ktb row + rarf extras when do_extras)
__global__ __launch_bounds__(256) void so_rarf_kernel(
    const float* __restrict__ atts,
    const float* __restrict__ soT_it, const float* __restrict__ sob_it,
    const unsigned short* __restrict__ skw_nx, const float* __restrict__ skb_nx,
    const float* __restrict__ a1, const float* __restrict__ a2,
    const float* __restrict__ fcw, const float* __restrict__ fcb,
    const float* __restrict__ bqf, int do_extras,
    float* __restrict__ relay, unsigned short* __restrict__ ktb,
    float* __restrict__ ra1, float* __restrict__ ra2, float* __restrict__ rf) {
  int n = blockIdx.x >> 4, b = blockIdx.x & 15;
  if (!do_extras && n > 0) return;
  __shared__ float xr[256];
  __shared__ float rel[256];
  __shared__ float red1[4], red2[4];
  __shared__ float pf_s[8 * 33];
  int t = threadIdx.x;
  xr[t] = atts[b * 256 + t];
  __syncthreads();
  float acc = 0.f;
  for (int k = 0; k < 256; k++) acc = fmaf(xr[k], soT_it[(size_t)k * 256 + t], acc);
  float v = acc + sob_it[t];
  v = v > 0.f ? v : 0.01f * v;
  rel[t] = v;
  __syncthreads();
  if (n == 0) relay[b * 256 + t] = v;
  if (!do_extras) return;
  if (n == 0) {
    float a2v = 0.f;
    for (int k = 0; k < 256; k++) a2v = fmaf(rel[k], bf2f(skw_nx[(size_t)t * 256 + k]), a2v);
    ktb[((size_t)b * LP1) * 256 + t] = f2bf(a2v + skb_nx[t]);
  }
  rarf_tail(n, b, t, rel, a1, a2, fcw, fcb, bqf, ra1, ra2, rf, red1, red2, pf_s);
}

// ---------------------------------------------------------------------------
// Fused LayerNorm + ei/ej
__global__ __launch_bounds__(256) void lnei_kernel(const float* __restrict__ src,
                                                   const unsigned short* __restrict__ datab,
                                                   const float* __restrict__ g,
                                                   const float* __restrict__ bb,
                                                   const float* __restrict__ w1,
                                                   const float* __restrict__ w2,
                                                   const float* __restrict__ a1o,
                                                   const float* __restrict__ a2o,
                                                   const float* __restrict__ c1,
                                                   const float* __restrict__ c2,
                                                   const float* __restrict__ ra1,
                                                   const float* __restrict__ ra2,
                                                   unsigned short* __restrict__ xnb,
                                                   float* __restrict__ ei,
                                                   float* __restrict__ ej) {
  int r = blockIdx.x * 4 + (threadIdx.x >> 6);
  int b = r >> 9;
  int lane = threadIdx.x & 63;
  float x[4], dv[4];
#pragma unroll
  for (int u = 0; u < 4; u++) {
    int c = lane + 64 * u;
    x[u] = src[(size_t)r * 256 + c];
    dv[u] = bf2f(datab[(size_t)r * 256 + c]);
  }
  float s = x[0] + x[1] + x[2] + x[3];
#pragma unroll
  for (int o = 32; o; o >>= 1) s += __shfl_xor(s, o);
  float mean = s * (1.0f / 256.0f);
  float v = 0.f;
#pragma unroll
  for (int u = 0; u < 4; u++) { x[u] -= mean; v = fmaf(x[u], x[u], v); }
#pragma unroll
  for (int o = 32; o; o >>= 1) v += __shfl_xor(v, o);
  float rstd = rsqrtf(v * (1.0f / 256.0f) + 1e-5f);
  float xv[4];
#pragma unroll
  for (int u = 0; u < 4; u++) {
    int c = lane + 64 * u;
    xv[u] = x[u] * rstd * g[c] + bb[c];
    xnb[(size_t)r * 256 + c] = f2bf(xv[u]);
  }
  float s1a[8], s2a[8];
#pragma unroll
  for (int n = 0; n < 8; n++) {
    float s1 = 0.f, s2 = 0.f;
#pragma unroll
    for (int u = 0; u < 4; u++) {
      int c = lane + 64 * u;
      s1 = fmaf(xv[u], w1[n * 256 + c], s1);
      s1 = fmaf(dv[u], a1o[n * 256 + c], s1);
      s2 = fmaf(xv[u], w2[n * 256 + c], s2);
      s2 = fmaf(dv[u], a2o[n * 256 + c], s2);
    }
    s1a[n] = s1; s2a[n] = s2;
  }
#pragma unroll
  for (int o = 32; o; o >>= 1) {
#pragma unroll
    for (int n = 0; n < 8; n++) {
      s1a[n] += __shfl_xor(s1a[n], o);
      s2a[n] += __shfl_xor(s2a[n], o);
    }
  }
  if (lane == 0) {
#pragma unroll
    for (int n = 0; n < 8; n++) {
      ei[n * 8192 + r] = s1a[n] + c1[n] + ra1[n * 16 + b];
      ej[n * 8192 + r] = s2a[n] + c2[n] + ra2[n * 16 + b];
    }
  }
}

// ---------------------------------------------------------------------------
// G-GEMM
__global__ __launch_bounds__(256) void g_gemm_kernel(
    const unsigned short* __restrict__ A1, const unsigned short* __restrict__ A2,
    const unsigned short* __restrict__ Bcat, unsigned short* __restrict__ GT) {
  int tileN = blockIdx.x * 64;
  int tileM = blockIdx.y * 128;
  int t = threadIdx.x;
  int wv = t >> 6, lane = t & 63;
  int lo = lane & 15, quad = lane >> 4;
  int rowBase0 = tileM + wv * 32;
  const unsigned short* ap1[2];
  const unsigned short* ap2[2];
#pragma unroll
  for (int rt = 0; rt < 2; rt++) {
    int arow = rowBase0 + rt * 16 + lo;
    ap1[rt] = A1 + (size_t)arow * 256 + quad * 8;
    ap2[rt] = A2 + (size_t)arow * 256 + quad * 8;
  }
  f32x4 acc[2][4] = {};
  for (int k0 = 0; k0 < 512; k0 += 32) {
    bf16x8 af[2];
#pragma unroll
    for (int rt = 0; rt < 2; rt++)
      af[rt] = (k0 < 256) ? *(const bf16x8*)(ap1[rt] + k0)
                          : *(const bf16x8*)(ap2[rt] + k0 - 256);
#pragma unroll
    for (int ct = 0; ct < 4; ct++) {
      bf16x8 bf_ = *(const bf16x8*)(Bcat + (size_t)(tileN + ct * 16 + lo) * 512 + k0 + quad * 8);
#pragma unroll
      for (int rt = 0; rt < 2; rt++)
        acc[rt][ct] = __builtin_amdgcn_mfma_f32_16x16x32_bf16(af[rt], bf_, acc[rt][ct], 0, 0, 0);
    }
  }
#pragma unroll
  for (int rt = 0; rt < 2; rt++) {
#pragma unroll
    for (int ct = 0; ct < 4; ct++) {
      int co = tileN + ct * 16 + lo;
      int n = co >> 5, d = co & 31;
      int jrow = rowBase0 + rt * 16 + quad * 4;
      int b2 = jrow >> 9, jj = jrow & 511;
      ushort4 pk;
      pk.x = f2bf(acc[rt][ct][0]);
      pk.y = f2bf(acc[rt][ct][1]);
      pk.z = f2bf(acc[rt][ct][2]);
      pk.w = f2bf(acc[rt][ct][3]);
      *(ushort4*)&GT[(((size_t)(n * 16 + b2) * 32 + d) << 9) + jj] = pk;
    }
  }
}

// ---------------------------------------------------------------------------
// GAT: reduction-free softmax + MFMA aggregation; XCD-swizzled block map:
// sib (i0 idx) = blk>>7, g = blk&127 -> all 16 siblings of (n,b) and all
// heads of a batch land on the same XCD (ids congruent mod 8).
__global__ __launch_bounds__(256) void gat_agg_kernel(
    const unsigned short* __restrict__ GT,
    const float* __restrict__ ei, const float* __restrict__ ej,
    const unsigned char* __restrict__ ep,
    const float* __restrict__ rf,
    unsigned short* __restrict__ tempb) {
  __shared__ unsigned short W[32][512];
  __shared__ float denom_s[32];
  int blk = blockIdx.x;
  int sib = blk >> 7;
  int g = blk & 127;
  int n = g >> 4;
  int b = g & 15;
  int i0 = sib << 5;
  int t = threadIdx.x;
  int wv = t >> 6, lane = t & 63;
  int lo = lane & 15, quad = lane >> 4;

  const float* ejrow = ej + n * 8192 + b * 512;
  float ejv[8];
#pragma unroll
  for (int u = 0; u < 8; u++) ejv[u] = ejrow[lane + 64 * u];
  float mm = ejv[0];
#pragma unroll
  for (int u = 1; u < 8; u++) mm = fmaxf(mm, ejv[u]);
#pragma unroll
  for (int o = 32; o; o >>= 1) mm = fmaxf(mm, __shfl_xor(mm, o));

  for (int rr = 0; rr < 8; rr++) {
    int row = wv * 8 + rr;
    float eiv = ei[n * 8192 + b * 512 + i0 + row];
    float M = eiv + mm;
    M = M > 0.f ? M : 0.2f * M;
    unsigned pb = ep[(((size_t)(b * 512 + i0 + row)) << 6) + lane];
    int rx = (row & 7) << 3;
#pragma unroll
    for (int u = 0; u < 8; u++) {
      float e = eiv + ejv[u];
      e = e > 0.f ? e : 0.2f * e;
      float w = ((pb >> u) & 1) ? __expf(e - M) : 0.f;
      int col = lane + 64 * u;
      W[row][((col >> 3 << 3) ^ rx) + (col & 7)] = f2bf(w);
    }
  }
  __syncthreads();

  int rt = wv >> 1, dh = wv & 1;
  int arow = rt * 16 + lo;
  int rx = arow & 7;
  const unsigned short* gtb = GT + (((size_t)(n * 16 + b) * 32) << 9);
  bf16x8 bones;
  {
    short ov = (lo == 0) ? (short)0x3F80 : (short)0;
#pragma unroll
    for (int j = 0; j < 8; j++) bones[j] = ov;
  }
  f32x4 acc = {}, accd = {};
  for (int k0 = 0; k0 < 512; k0 += 32) {
    int chunk = (k0 >> 3) + quad;
    bf16x8 a0 = *(const bf16x8*)&W[arow][(chunk ^ rx) << 3];
    bf16x8 bf_ = *(const bf16x8*)(gtb + (((size_t)(dh * 16 + lo)) << 9) + k0 + quad * 8);
    acc = __builtin_amdgcn_mfma_f32_16x16x32_bf16(a0, bf_, acc, 0, 0, 0);
    if (dh == 0)
      accd = __builtin_amdgcn_mfma_f32_16x16x32_bf16(a0, bones, accd, 0, 0, 0);
  }
  if (dh == 0 && lo == 0) {
#pragma unroll
    for (int r = 0; r < 4; r++) denom_s[rt * 16 + quad * 4 + r] = accd[r];
  }
  __syncthreads();
  int d = dh * 16 + lo;
  float base = rf[((size_t)n * 16 + b) * 32 + d];
#pragma unroll
  for (int r = 0; r < 4; r++) {
    int row = rt * 16 + quad * 4 + r;
    float inv = 1.0f / fmaxf(denom_s[row], 1e-35f);
    float v = acc[r] * inv + base;
    v = v > 0.f ? v : expm1f(v);
    tempb[((size_t)(b * 512 + i0 + row)) * 256 + n * 32 + d] = f2bf(v);
  }
}

// ---------------------------------------------------------------------------
// Fused fc + kt GEMMs
__global__ __launch_bounds__(256) void fc_kt_kernel(
    const unsigned short* __restrict__ tempb,
    const unsigned short* __restrict__ fcwT,
    const float* __restrict__ fc_b,
    const unsigned short* __restrict__ skw_it,
    const float* __restrict__ skb_it,
    const int* __restrict__ mask,
    const float* __restrict__ resid,
    float* __restrict__ nodes,
    unsigned short* __restrict__ ktb) {
  __shared__ unsigned short tmp[32][264];
  int blk = blockIdx.x;
  int b = blk >> 4;
  int i0 = (blk & 15) << 5;
  int t = threadIdx.x;
  int wv = t >> 6, lane = t & 63;
  int lo = lane & 15, quad = lane >> 4;
  int ch = wv >> 1, rt2 = wv & 1;

  const unsigned short* arow_p = tempb + ((size_t)(b * 512 + i0 + rt2 * 16 + lo)) * 256 + quad * 8;
  f32x4 facc[8] = {};
  for (int k0 = 0; k0 < 256; k0 += 32) {
    bf16x8 a0 = *(const bf16x8*)(arow_p + k0);
#pragma unroll
    for (int ct = 0; ct < 8; ct++) {
      int co = ch * 128 + ct * 16 + lo;
      bf16x8 bf_ = *(const bf16x8*)(fcwT + (size_t)co * 256 + k0 + quad * 8);
      facc[ct] = __builtin_amdgcn_mfma_f32_16x16x32_bf16(a0, bf_, facc[ct], 0, 0, 0);
    }
  }
#pragma unroll
  for (int ct = 0; ct < 8; ct++) {
    int co = ch * 128 + ct * 16 + lo;
    float bv = fc_b[co];
#pragma unroll
    for (int r = 0; r < 4; r++) {
      int row = rt2 * 16 + quad * 4 + r;
      int grow = b * 512 + i0 + row;
      float v = facc[ct][r] + bv;
      v = v > 0.f ? v : 0.01f * v;
      v = (mask[grow] != 0) ? resid[(size_t)grow * 256 + co] + v : 0.f;
      nodes[(size_t)grow * 256 + co] = v;
      tmp[row][co] = f2bf(v);
    }
  }
  __syncthreads();

  f32x4 kacc[8] = {};
  for (int k0 = 0; k0 < 256; k0 += 32) {
    bf16x8 a0 = *(const bf16x8*)&tmp[rt2 * 16 + lo][k0 + quad * 8];
#pragma unroll
    for (int ct = 0; ct < 8; ct++) {
      int co = ch * 128 + ct * 16 + lo;
      bf16x8 bf_ = *(const bf16x8*)(skw_it + (size_t)co * 256 + k0 + quad * 8);
      kacc[ct] = __builtin_amdgcn_mfma_f32_16x16x32_bf16(a0, bf_, kacc[ct], 0, 0, 0);
    }
  }
#pragma unroll
  for (int ct = 0; ct < 8; ct++) {
    int co = ch * 128 + ct * 16 + lo;
    float bv = skb_it[co];
#pragma unroll
    for (int r = 0; r < 4; r++) {
      int row = rt2 * 16 + quad * 4 + r;
      int yrow = b * LP1 + 1 + i0 + row;
      ktb[(size_t)yrow * 256 + co] = f2bf(kacc[ct][r] + bv);
    }
  }
}

// ---------------------------------------------------------------------------
// star attention on bf16 kt; XCD-swizzled: n = blk>>4, b = blk&15
__global__ __launch_bounds__(256) void star_attn_kernel(const float* __restrict__ relay,
                                                        const float* __restrict__ sqT_it,
                                                        const float* __restrict__ sqb_it,
                                                        const unsigned short* __restrict__ ktb,
                                                        const int* __restrict__ mask,
                                                        float* __restrict__ attstar) {
  int n = blockIdx.x >> 4, b = blockIdx.x & 15;
  int t = threadIdx.x;
  int lane = t & 63, w = t >> 6;
  __shared__ float relb[256];
  __shared__ float qv[32];
  __shared__ float pre[LP1];
  __shared__ float red[4];
  __shared__ float par[8][33];
  relb[t] = relay[b * 256 + t];
  __syncthreads();
  {
    int d = t & 31, g = t >> 5;
    float qp = 0.f;
    for (int k = 0; k < 32; k++)
      qp = fmaf(relb[g * 32 + k], sqT_it[(size_t)(g * 32 + k) * 256 + n * 32 + d], qp);
    par[g][d] = qp;
  }
  __syncthreads();
  if (t < 32) {
    float q = 0.f;
#pragma unroll
    for (int gg = 0; gg < 8; gg++) q += par[gg][t];
    qv[t] = q + sqb_it[n * 32 + t];
  }
  __syncthreads();
  const float scale = 0.17677669529663687f;
  for (int l = t; l < LP1; l += 256) {
    bool masked = (l > 0) && (mask[b * LL + l - 1] == 0);
    float p;
    if (masked) p = -3.4e38f;
    else {
      p = 0.f;
      const unsigned short* krow = ktb + ((size_t)b * LP1 + l) * 256 + n * 32;
#pragma unroll
      for (int d = 0; d < 32; d++) p = fmaf(qv[d], bf2f(krow[d]), p);
      p *= scale;
    }
    pre[l] = p;
  }
  __syncthreads();
  float m = -3.4e38f;
  for (int l = t; l < LP1; l += 256) m = fmaxf(m, pre[l]);
#pragma unroll
  for (int o = 32; o; o >>= 1) m = fmaxf(m, __shfl_xor(m, o));
  if (lane == 0) red[w] = m;
  __syncthreads();
  m = fmaxf(fmaxf(red[0], red[1]), fmaxf(red[2], red[3]));
  __syncthreads();
  float s = 0.f;
  for (int l = t; l < LP1; l += 256) {
    float wv = __expf(pre[l] - m);
    pre[l] = wv;
    s += wv;
  }
#pragma unroll
  for (int o = 32; o; o >>= 1) s += __shfl_xor(s, o);
  if (lane == 0) red[w] = s;
  __syncthreads();
  float denom = red[0] + red[1] + red[2] + red[3];
  int d = t & 31, g = t >> 5;
  float acc = 0.f;
  for (int l = g; l < LP1; l += 8)
    acc = fmaf(pre[l], bf2f(ktb[((size_t)b * LP1 + l) * 256 + n * 32 + d]), acc);
  par[g][d] = acc;
  __syncthreads();
  if (t < 32) {
    float a = 0.f;
    for (int gg = 0; gg < 8; gg++) a += par[gg][t];
    attstar[b * 256 + n * 32 + t] = a / denom;
  }
}

// ---------------------------------------------------------------------------
extern "C" void kernel_launch(void* const* d_in, const int* in_sizes, int n_in,
                              void* d_out, int out_size, void* d_ws, size_t ws_size,
                              hipStream_t stream) {
  const float* data  = (const float*)d_in[0];
  const float* WQw   = (const float*)d_in[1];
  const float* WQb   = (const float*)d_in[2];
  const float* a1    = (const float*)d_in[3];
  const float* a2    = (const float*)d_in[4];
  const float* fcw_g = (const float*)d_in[5];
  const float* fcb_g = (const float*)d_in[6];
  const float* ng    = (const float*)d_in[7];
  const float* nb    = (const float*)d_in[8];
  const float* sq_w  = (const float*)d_in[9];
  const float* sq_b  = (const float*)d_in[10];
  const float* sk_w  = (const float*)d_in[11];
  const float* sk_b  = (const float*)d_in[12];
  const float* so_w  = (const float*)d_in[13];
  const float* so_b  = (const float*)d_in[14];
  const float* fc_w  = (const float*)d_in[15];
  const float* fc_b  = (const float*)d_in[16];
  const int*   mask  = (const int*)d_in[17];
  const int*   edge  = (const int*)d_in[18];

  float* nodes = (float*)d_out;
  float* relay = nodes + NODES_ELEMS;

  char* p = (char*)d_ws;
  auto alloc = [&](size_t bytes) -> char* {
    char* r = p; p += (bytes + 255) & ~(size_t)255; return r;
  };
  unsigned short* xnb  = (unsigned short*)alloc((size_t)8192 * 256 * 2);
  unsigned short* datab= (unsigned short*)alloc((size_t)8192 * 256 * 2);
  unsigned short* GT   = (unsigned short*)alloc((size_t)8 * 16 * 32 * 512 * 2);
  unsigned short* tmpb = (unsigned short*)alloc((size_t)8192 * 256 * 2);
  unsigned short* ktb  = (unsigned short*)alloc((size_t)8208 * 256 * 2);
  unsigned char* ep    = (unsigned char*)alloc((size_t)8192 * 64);
  float* ei            = (float*)alloc(65536 * 4);
  float* ej            = (float*)alloc(65536 * 4);
  float* ra1           = (float*)alloc(128 * 4);
  float* ra2           = (float*)alloc(128 * 4);
  float* rf            = (float*)alloc(4096 * 4);
  float* bqf           = (float*)alloc(256 * 4);
  float* w1            = (float*)alloc(2048 * 4);
  float* w2            = (float*)alloc(2048 * 4);
  float* c1            = (float*)alloc(8 * 4);
  float* c2            = (float*)alloc(8 * 4);
  float* a1o           = (float*)alloc(2048 * 4);
  float* a2o           = (float*)alloc(2048 * 4);
  float* rpart         = (float*)alloc(128 * 256 * 4);
  unsigned short* Bcat = (unsigned short*)alloc((size_t)256 * 512 * 2);
  unsigned short* fcwT = (unsigned short*)alloc((size_t)65536 * 2);
  unsigned short* skwb = (unsigned short*)alloc((size_t)131072 * 2);
  float* sqT           = (float*)alloc((size_t)131072 * 4);
  float* soT           = (float*)alloc((size_t)131072 * 4);
  float* atts          = (float*)alloc(4096 * 4);

  mega_prep_kernel<<<3162, 256, 0, stream>>>(data, edge, fc_w, fcw_g, sk_w, sq_w,
                                             so_w, WQw, WQb, a1, a2,
                                             datab, ep, fcwT, Bcat, skwb, sqT, soT,
                                             rpart, w1, w2, c1, c2, bqf, a1o, a2o);
  prep2_kernel<<<256, 256, 0, stream>>>(WQw, fcw_g, Bcat, rpart, skwb, sk_b,
                                        a1, a2, fcb_g, bqf,
                                        relay, ktb, ra1, ra2, rf);

  for (int it = 0; it < 2; it++) {
    const float* src = (it == 0) ? data : nodes;
    lnei_kernel<<<2048, 256, 0, stream>>>(src, datab, ng + it * 256, nb + it * 256,
                                          w1, w2, a1o, a2o, c1, c2, ra1, ra2,
                                          xnb, ei, ej);
    g_gemm_kernel<<<dim3(4, 64), 256, 0, stream>>>(xnb, datab, Bcat, GT);
    gat_agg_kernel<<<NHEAD * BB * 16, 256, 0, stream>>>(GT, ei, ej, ep, rf, tmpb);
    fc_kt_kernel<<<256, 256, 0, stream>>>(tmpb, fcwT, fc_b,
                                          skwb + it * 65536, sk_b + it * 256,
                                          mask, src, nodes, ktb);
    star_attn_kernel<<<BB * NHEAD, 256, 0, stream>>>(relay, sqT + it * 65536,
                                                     sq_b + it * 256, ktb, mask, atts);
    so_rarf_kernel<<<128, 256, 0, stream>>>(atts, soT + it * 65536, so_b + it * 256,
                                            skwb + 65536, sk_b + 256,
                                            a1, a2, fcw_g, fcb_g, bqf,
                                            (it == 0) ? 1 : 0,
                                            relay, ktb, ra1, ra2, rf);
  }
}

// Round 14
// 328.321 us; speedup vs baseline: 1.4841x; 1.0765x over previous
//
#include <hip/hip_runtime.h>
#include <hip/hip_bf16.h>
#include <math.h>

#define BB 16
#define LL 512
#define HH 256
#define NHEAD 8
#define HDIM 32
#define LP1 513
#define NODES_ELEMS (BB*LL*HH)

typedef __attribute__((ext_vector_type(8))) short bf16x8;
typedef __attribute__((ext_vector_type(4))) float f32x4;

__device__ __forceinline__ unsigned short f2bf(float f) {
  union { float f; unsigned u; } x; x.f = f;
  unsigned r = x.u + 0x7fffu + ((x.u >> 16) & 1u);
  return (unsigned short)(r >> 16);
}
__device__ __forceinline__ float bf2f(unsigned short u) {
  union { unsigned u; float f; } x; x.u = (unsigned)u << 16; return x.f;
}

// ---------------------------------------------------------------------------
// MEGA-PREP (3162 blocks) — as R13
__global__ __launch_bounds__(256) void mega_prep_kernel(
    const float* __restrict__ data, const int* __restrict__ edge,
    const float* __restrict__ fc_w, const float* __restrict__ fcw,
    const float* __restrict__ sk_w, const float* __restrict__ sq_w,
    const float* __restrict__ so_w, const float* __restrict__ WQw,
    const float* __restrict__ WQb, const float* __restrict__ a1,
    const float* __restrict__ a2,
    unsigned short* __restrict__ datab, unsigned char* __restrict__ ep,
    unsigned short* __restrict__ fcwT, unsigned short* __restrict__ Bcat,
    unsigned short* __restrict__ skwb, float* __restrict__ sqT,
    float* __restrict__ soT, float* __restrict__ rpart,
    float* __restrict__ w1, float* __restrict__ w2,
    float* __restrict__ c1, float* __restrict__ c2,
    float* __restrict__ bqf, float* __restrict__ a1o, float* __restrict__ a2o) {
  __shared__ float smem[64 * 65];
  int blk = blockIdx.x, t = threadIdx.x;
  if (blk < 128) {
    int b = blk >> 3, ch = blk & 7;
    const float* pr = data + ((size_t)b * 512 + ch * 64) * 256 + t;
    unsigned short* db = datab + ((size_t)b * 512 + ch * 64) * 256 + t;
    float s = 0.f;
    for (int l = 0; l < 64; l++) {
      float v = pr[(size_t)l * 256];
      db[(size_t)l * 256] = f2bf(v);
      s += v;
    }
    rpart[(size_t)blk * 256 + t] = s;
  } else if (blk < 2176) {
    int row = (blk - 128) * 4 + (t >> 6);
    int lane = t & 63;
    const int* adj = edge + ((size_t)row << 9);
    unsigned v = 0;
#pragma unroll
    for (int u = 0; u < 8; u++) v |= (adj[lane + 64 * u] > 0 ? 1u : 0u) << u;
    ep[((size_t)row << 6) + lane] = (unsigned char)v;
  } else if (blk < 2432) {
    int idx = (blk - 2176) * 256 + t;
    int d = idx & 31;
    int g = idx >> 5;
    int n = g >> 8, c = g & 255;
    Bcat[((size_t)n * 32 + d) * 512 + 256 + c] =
        f2bf(fcw[((size_t)n * 768 + 256 + 2 * c) * 32 + d]);
  } else if (blk < 2944) {
    int idx = (blk - 2432) * 256 + t;
    skwb[idx] = f2bf(sk_w[idx]);
  } else if (blk < 3024) {
    int q = blk - 2944;
    int mat = q >> 4, tl = q & 15;
    int r0 = (tl >> 2) * 64, c0 = (tl & 3) * 64;
    const float* in;
    if (mat == 0) in = fc_w;
    else if (mat <= 2) in = sq_w + (mat - 1) * 65536;
    else in = so_w + (mat - 3) * 65536;
    int cc = t & 63, rq = t >> 6;
#pragma unroll
    for (int i = 0; i < 16; i++) {
      int r = rq + i * 4;
      smem[r * 65 + cc] = in[(r0 + r) * 256 + c0 + cc];
    }
    __syncthreads();
#pragma unroll
    for (int i = 0; i < 16; i++) {
      int cp = rq + i * 4;
      float v = smem[cc * 65 + cp];
      if (mat == 0) fcwT[(c0 + cp) * 256 + r0 + cc] = f2bf(v);
      else if (mat <= 2) sqT[(mat - 1) * 65536 + (c0 + cp) * 256 + r0 + cc] = v;
      else soT[(mat - 3) * 65536 + (c0 + cp) * 256 + r0 + cc] = v;
    }
  } else if (blk < 3152) {
    int q = blk - 3024;
    int n = q >> 4, kc = q & 15;
    int k = kc * 16 + (t & 15), cseg = t >> 4;
    float s1 = 0.f, s2 = 0.f;
#pragma unroll
    for (int u = 0; u < 16; u++) {
      int c = cseg * 16 + u;
      float wv = WQw[((size_t)(n * 256 + c)) * 256 + k];
      s1 = fmaf(a1[n * 768 + c], wv, s1);
      s2 = fmaf(a2[n * 768 + c], wv, s2);
    }
    smem[cseg * 16 + (t & 15)] = s1;
    smem[256 + cseg * 16 + (t & 15)] = s2;
    __syncthreads();
    if (cseg == 0) {
      float a = 0.f, b2 = 0.f;
#pragma unroll
      for (int u = 0; u < 16; u++) {
        a += smem[u * 16 + (t & 15)];
        b2 += smem[256 + u * 16 + (t & 15)];
      }
      w1[n * 256 + k] = a;
      w2[n * 256 + k] = b2;
    }
  } else if (blk < 3160) {
    int n = blk - 3152;
    int d = t & 31, seg = t >> 5;
    float s = 0.f;
#pragma unroll
    for (int u = 0; u < 32; u++) {
      int c = seg * 32 + u;
      s = fmaf(WQb[n * 256 + c], fcw[((size_t)n * 768 + c) * 32 + d], s);
    }
    smem[seg * 32 + d] = s;
    __syncthreads();
    if (seg == 0) {
      float a = 0.f;
#pragma unroll
      for (int u = 0; u < 8; u++) a += smem[u * 32 + d];
      bqf[n * 32 + d] = a;
    }
  } else if (blk == 3160) {
    int n = t >> 5, sl = t & 31;
    float s1 = 0.f, s2 = 0.f;
#pragma unroll
    for (int u = 0; u < 8; u++) {
      int c = sl * 8 + u;
      float wb = WQb[n * 256 + c];
      s1 = fmaf(a1[n * 768 + c], wb, s1);
      s2 = fmaf(a2[n * 768 + c], wb, s2);
    }
    smem[t] = s1; smem[256 + t] = s2;
    __syncthreads();
    if (sl == 0) {
      float a = 0.f, b2 = 0.f;
      for (int u = 0; u < 32; u++) { a += smem[n * 32 + u]; b2 += smem[256 + n * 32 + u]; }
      c1[n] = a; c2[n] = b2;
    }
  } else {
#pragma unroll
    for (int n = 0; n < 8; n++) {
      a1o[n * 256 + t] = a1[n * 768 + 256 + 2 * t];
      a2o[n * 256 + t] = a2[n * 768 + 256 + 2 * t];
    }
  }
}

// ---------------------------------------------------------------------------
__device__ __forceinline__ void rarf_tail(
    int n, int b, int t, const float* rel,
    const float* __restrict__ a1, const float* __restrict__ a2,
    const float* __restrict__ fcw, const float* __restrict__ fcb,
    const float* __restrict__ bqf,
    float* __restrict__ ra1, float* __restrict__ ra2, float* __restrict__ rf,
    float* red1, float* red2, float* pf_s) {
  int lane = t & 63, w = t >> 6;
  float p1 = rel[t] * a1[n * 768 + 257 + 2 * t];
  float p2 = rel[t] * a2[n * 768 + 257 + 2 * t];
#pragma unroll
  for (int o = 32; o; o >>= 1) { p1 += __shfl_xor(p1, o); p2 += __shfl_xor(p2, o); }
  if (lane == 0) { red1[w] = p1; red2[w] = p2; }
  int d = t & 31, seg = t >> 5;
  float pf = 0.f;
  for (int u = 0; u < 32; u++) {
    int k = seg * 32 + u;
    pf = fmaf(rel[k], fcw[((size_t)n * 768 + 257 + 2 * k) * 32 + d], pf);
  }
  pf_s[seg * 33 + d] = pf;
  __syncthreads();
  if (t == 0) {
    ra1[n * 16 + b] = red1[0] + red1[1] + red1[2] + red1[3];
    ra2[n * 16 + b] = red2[0] + red2[1] + red2[2] + red2[3];
  }
  if (t < 32) {
    float s = 0.f;
    for (int gg = 0; gg < 8; gg++) s += pf_s[gg * 33 + t];
    rf[((size_t)n * 16 + b) * 32 + t] = s + fcb[n * 32 + t] + bqf[n * 32 + t];
  }
}

// ---------------------------------------------------------------------------
// prep2 (272 blocks): 0-127 Bcat M1 | 128-255 relay+rarf | 256-271 ei/ej cols
__global__ __launch_bounds__(256) void prep2_kernel(
    const float* __restrict__ WQw, const float* __restrict__ fcw,
    unsigned short* __restrict__ Bcat,
    const float* __restrict__ rpart,
    const unsigned short* __restrict__ skw0, const float* __restrict__ skb0,
    const float* __restrict__ a1, const float* __restrict__ a2,
    const float* __restrict__ fcb, const float* __restrict__ bqf,
    const float* __restrict__ w1, const float* __restrict__ w2,
    const float* __restrict__ a1o, const float* __restrict__ a2o,
    float* __restrict__ relay, unsigned short* __restrict__ ktb,
    float* __restrict__ ra1, float* __restrict__ ra2, float* __restrict__ rf) {
  __shared__ float smem[12288];
  int blk = blockIdx.x, t = threadIdx.x;
  if (blk < 128) {
    float* wq_s = smem;
    float* fw_s = smem + 4096;
    int n = blk >> 4, kt = blk & 15;
#pragma unroll
    for (int i = 0; i < 16; i++) {
      int c = i * 16 + (t >> 4), kk = t & 15;
      wq_s[c * 16 + kk] = WQw[(size_t)n * 65536 + c * 256 + kt * 16 + kk];
    }
#pragma unroll
    for (int i = 0; i < 32; i++) {
      int idx = i * 256 + t;
      fw_s[(idx >> 5) * 32 + (idx & 31)] = fcw[(size_t)n * 24576 + idx];
    }
    __syncthreads();
    int kloc = t >> 4, dp = t & 15;
    float a0 = 0.f, a1v = 0.f;
    for (int c = 0; c < 256; c++) {
      float wv = wq_s[c * 16 + kloc];
      a0 = fmaf(wv, fw_s[c * 32 + dp * 2], a0);
      a1v = fmaf(wv, fw_s[c * 32 + dp * 2 + 1], a1v);
    }
    int k = kt * 16 + kloc;
    Bcat[((size_t)n * 32 + dp * 2) * 512 + k] = f2bf(a0);
    Bcat[((size_t)n * 32 + dp * 2 + 1) * 512 + k] = f2bf(a1v);
  } else if (blk < 256) {
    float* rel = smem;
    float* red1 = smem + 256;
    float* red2 = smem + 264;
    float* pf_s = smem + 272;
    int id = blk - 128;
    int n = id >> 4, b = id & 15;
    float s = 0.f;
#pragma unroll
    for (int ch = 0; ch < 8; ch++) s += rpart[((size_t)(b * 8 + ch)) * 256 + t];
    s *= (1.0f / 512.0f);
    rel[t] = s;
    __syncthreads();
    if (n == 0) {
      relay[b * 256 + t] = s;
      float acc = 0.f;
      for (int k = 0; k < 256; k++) acc = fmaf(rel[k], bf2f(skw0[(size_t)t * 256 + k]), acc);
      ktb[((size_t)b * LP1) * 256 + t] = f2bf(acc + skb0[t]);
    }
    rarf_tail(n, b, t, rel, a1, a2, fcw, fcb, bqf, ra1, ra2, rf, red1, red2, pf_s);
  } else {
    // ei/ej columns of Bcat: col = 256 + q
    int q = blk - 256;
    int n = q & 7, isEj = q >> 3;
    const float* wsrc = isEj ? w2 : w1;
    const float* asrc = isEj ? a2o : a1o;
#pragma unroll
    for (int h = 0; h < 2; h++) {
      int k = h * 256 + t;
      float v = (k < 256) ? wsrc[n * 256 + k] : asrc[n * 256 + k - 256];
      Bcat[((size_t)(256 + q)) * 512 + k] = f2bf(v);
    }
  }
}

// relay = lrelu(atts @ soT + sob) (+ ktb row + rarf extras when do_extras)
__global__ __launch_bounds__(256) void so_rarf_kernel(
    const float* __restrict__ atts,
    const float* __restrict__ soT_it, const float* __restrict__ sob_it,
    const unsigned short* __restrict__ skw_nx, const float* __restrict__ skb_nx,
    const float* __restrict__ a1, const float* __restrict__ a2,
    const float* __restrict__ fcw, const float* __restrict__ fcb,
    const float* __restrict__ bqf, int do_extras,
    float* __restrict__ relay, unsigned short* __restrict__ ktb,
    float* __restrict__ ra1, float* __restrict__ ra2, float* __restrict__ rf) {
  int n = blockIdx.x >> 4, b = blockIdx.x & 15;
  if (!do_extras && n > 0) return;
  __shared__ float xr[256];
  __shared__ float rel[256];
  __shared__ float red1[4], red2[4];
  __shared__ float pf_s[8 * 33];
  int t = threadIdx.x;
  xr[t] = atts[b * 256 + t];
  __syncthreads();
  float acc = 0.f;
  for (int k = 0; k < 256; k++) acc = fmaf(xr[k], soT_it[(size_t)k * 256 + t], acc);
  float v = acc + sob_it[t];
  v = v > 0.f ? v : 0.01f * v;
  rel[t] = v;
  __syncthreads();
  if (n == 0) relay[b * 256 + t] = v;
  if (!do_extras) return;
  if (n == 0) {
    float a2v = 0.f;
    for (int k = 0; k < 256; k++) a2v = fmaf(rel[k], bf2f(skw_nx[(size_t)t * 256 + k]), a2v);
    ktb[((size_t)b * LP1) * 256 + t] = f2bf(a2v + skb_nx[t]);
  }
  rarf_tail(n, b, t, rel, a1, a2, fcw, fcb, bqf, ra1, ra2, rf, red1, red2, pf_s);
}

// ---------------------------------------------------------------------------
// LNG-GEMM: fused LayerNorm + [xn;data] @ Bcat(272 cols) -> GT + ei/ej
// block = (b, 32-row group): 256 blocks, 4 waves
__global__ __launch_bounds__(256) void lng_gemm_kernel(
    const float* __restrict__ src,            // nodes or data (fp32 LN input)
    const unsigned short* __restrict__ datab, // [8192][256] bf16
    const unsigned short* __restrict__ Bcat,  // [272][512] bf16
    const float* __restrict__ g, const float* __restrict__ bb,
    const float* __restrict__ c1, const float* __restrict__ c2,
    const float* __restrict__ ra1, const float* __restrict__ ra2,
    unsigned short* __restrict__ GT,          // [8][16][32][512] bf16
    float* __restrict__ ei, float* __restrict__ ej) {
  __shared__ unsigned short A[32][520];       // [row][k]: k<256 xn, k>=256 data
  int blk = blockIdx.x;
  int b = blk >> 4;
  int i0 = (blk & 15) << 5;
  int t = threadIdx.x;
  int wv = t >> 6, lane = t & 63;
  int lo = lane & 15, quad = lane >> 4;

  // ---- Phase 1: LN for rows wv*8..+7, stage bf16 into A; stage datab too
  float4 g4 = *(const float4*)(g + lane * 4);
  float4 b4 = *(const float4*)(bb + lane * 4);
  float xs[8][4];
  float sum[8], sq[8];
#pragma unroll
  for (int rr = 0; rr < 8; rr++) {
    int grow = b * 512 + i0 + wv * 8 + rr;
    float4 v = *(const float4*)(src + (size_t)grow * 256 + lane * 4);
    xs[rr][0] = v.x; xs[rr][1] = v.y; xs[rr][2] = v.z; xs[rr][3] = v.w;
    sum[rr] = v.x + v.y + v.z + v.w;
    sq[rr] = v.x * v.x + v.y * v.y + v.z * v.z + v.w * v.w;
    // stage data half
    ushort4 dv4 = *(const ushort4*)(datab + (size_t)grow * 256 + lane * 4);
    *(ushort4*)&A[wv * 8 + rr][256 + lane * 4] = dv4;
  }
#pragma unroll
  for (int o = 32; o; o >>= 1) {
#pragma unroll
    for (int rr = 0; rr < 8; rr++) {
      sum[rr] += __shfl_xor(sum[rr], o);
      sq[rr] += __shfl_xor(sq[rr], o);
    }
  }
#pragma unroll
  for (int rr = 0; rr < 8; rr++) {
    float mean = sum[rr] * (1.0f / 256.0f);
    float var = sq[rr] * (1.0f / 256.0f) - mean * mean;
    float rstd = rsqrtf(var + 1e-5f);
    ushort4 pk;
    pk.x = f2bf((xs[rr][0] - mean) * rstd * g4.x + b4.x);
    pk.y = f2bf((xs[rr][1] - mean) * rstd * g4.y + b4.y);
    pk.z = f2bf((xs[rr][2] - mean) * rstd * g4.z + b4.z);
    pk.w = f2bf((xs[rr][3] - mean) * rstd * g4.w + b4.w);
    *(ushort4*)&A[wv * 8 + rr][lane * 4] = pk;
  }
  __syncthreads();

  // ---- Phase 2: MFMA. wave wv owns col-tiles {wv, wv+4, wv+8, wv+12} (+16 for wv==0)
  f32x4 acc[2][4] = {};
  f32x4 acce[2] = {};
  for (int k0 = 0; k0 < 512; k0 += 32) {
    bf16x8 af[2];
#pragma unroll
    for (int rt = 0; rt < 2; rt++)
      af[rt] = *(const bf16x8*)&A[rt * 16 + lo][k0 + quad * 8];
#pragma unroll
    for (int j = 0; j < 4; j++) {
      int tile = j * 4 + wv;
      bf16x8 bf_ = *(const bf16x8*)(Bcat + (size_t)(tile * 16 + lo) * 512 + k0 + quad * 8);
#pragma unroll
      for (int rt = 0; rt < 2; rt++)
        acc[rt][j] = __builtin_amdgcn_mfma_f32_16x16x32_bf16(af[rt], bf_, acc[rt][j], 0, 0, 0);
    }
    if (wv == 0) {
      bf16x8 bf_ = *(const bf16x8*)(Bcat + (size_t)(256 + lo) * 512 + k0 + quad * 8);
#pragma unroll
      for (int rt = 0; rt < 2; rt++)
        acce[rt] = __builtin_amdgcn_mfma_f32_16x16x32_bf16(af[rt], bf_, acce[rt], 0, 0, 0);
    }
  }
  // ---- Epilogue: GT tiles
#pragma unroll
  for (int j = 0; j < 4; j++) {
    int tile = j * 4 + wv;
    int co = tile * 16 + lo;
    int n = co >> 5, d = co & 31;
#pragma unroll
    for (int rt = 0; rt < 2; rt++) {
      int jj = i0 + rt * 16 + quad * 4;
      ushort4 pk;
      pk.x = f2bf(acc[rt][j][0]);
      pk.y = f2bf(acc[rt][j][1]);
      pk.z = f2bf(acc[rt][j][2]);
      pk.w = f2bf(acc[rt][j][3]);
      *(ushort4*)&GT[(((size_t)(n * 16 + b) * 32 + d) << 9) + jj] = pk;
    }
  }
  // ei/ej tile (wave 0): lo<8 -> ei head lo; lo>=8 -> ej head lo-8
  if (wv == 0) {
    int n = lo & 7, isEj = lo >> 3;
    float cst = isEj ? (c2[n] + ra2[n * 16 + b]) : (c1[n] + ra1[n * 16 + b]);
    float* outp = isEj ? ej : ei;
#pragma unroll
    for (int rt = 0; rt < 2; rt++) {
#pragma unroll
      for (int r = 0; r < 4; r++) {
        int row = i0 + rt * 16 + quad * 4 + r;
        outp[n * 8192 + b * 512 + row] = acce[rt][r] + cst;
      }
    }
  }
}

// ---------------------------------------------------------------------------
// GAT: reduction-free softmax + MFMA aggregation; XCD-swizzled
__global__ __launch_bounds__(256) void gat_agg_kernel(
    const unsigned short* __restrict__ GT,
    const float* __restrict__ ei, const float* __restrict__ ej,
    const unsigned char* __restrict__ ep,
    const float* __restrict__ rf,
    unsigned short* __restrict__ tempb) {
  __shared__ unsigned short W[32][512];
  __shared__ float denom_s[32];
  int blk = blockIdx.x;
  int sib = blk >> 7;
  int g = blk & 127;
  int n = g >> 4;
  int b = g & 15;
  int i0 = sib << 5;
  int t = threadIdx.x;
  int wv = t >> 6, lane = t & 63;
  int lo = lane & 15, quad = lane >> 4;

  const float* ejrow = ej + n * 8192 + b * 512;
  float ejv[8];
#pragma unroll
  for (int u = 0; u < 8; u++) ejv[u] = ejrow[lane + 64 * u];
  float mm = ejv[0];
#pragma unroll
  for (int u = 1; u < 8; u++) mm = fmaxf(mm, ejv[u]);
#pragma unroll
  for (int o = 32; o; o >>= 1) mm = fmaxf(mm, __shfl_xor(mm, o));

  for (int rr = 0; rr < 8; rr++) {
    int row = wv * 8 + rr;
    float eiv = ei[n * 8192 + b * 512 + i0 + row];
    float M = eiv + mm;
    M = M > 0.f ? M : 0.2f * M;
    unsigned pb = ep[(((size_t)(b * 512 + i0 + row)) << 6) + lane];
    int rx = (row & 7) << 3;
#pragma unroll
    for (int u = 0; u < 8; u++) {
      float e = eiv + ejv[u];
      e = e > 0.f ? e : 0.2f * e;
      float w = ((pb >> u) & 1) ? __expf(e - M) : 0.f;
      int col = lane + 64 * u;
      W[row][((col >> 3 << 3) ^ rx) + (col & 7)] = f2bf(w);
    }
  }
  __syncthreads();

  int rt = wv >> 1, dh = wv & 1;
  int arow = rt * 16 + lo;
  int rx = arow & 7;
  const unsigned short* gtb = GT + (((size_t)(n * 16 + b) * 32) << 9);
  bf16x8 bones;
  {
    short ov = (lo == 0) ? (short)0x3F80 : (short)0;
#pragma unroll
    for (int j = 0; j < 8; j++) bones[j] = ov;
  }
  f32x4 acc = {}, accd = {};
  for (int k0 = 0; k0 < 512; k0 += 32) {
    int chunk = (k0 >> 3) + quad;
    bf16x8 a0 = *(const bf16x8*)&W[arow][(chunk ^ rx) << 3];
    bf16x8 bf_ = *(const bf16x8*)(gtb + (((size_t)(dh * 16 + lo)) << 9) + k0 + quad * 8);
    acc = __builtin_amdgcn_mfma_f32_16x16x32_bf16(a0, bf_, acc, 0, 0, 0);
    if (dh == 0)
      accd = __builtin_amdgcn_mfma_f32_16x16x32_bf16(a0, bones, accd, 0, 0, 0);
  }
  if (dh == 0 && lo == 0) {
#pragma unroll
    for (int r = 0; r < 4; r++) denom_s[rt * 16 + quad * 4 + r] = accd[r];
  }
  __syncthreads();
  int d = dh * 16 + lo;
  float base = rf[((size_t)n * 16 + b) * 32 + d];
#pragma unroll
  for (int r = 0; r < 4; r++) {
    int row = rt * 16 + quad * 4 + r;
    float inv = 1.0f / fmaxf(denom_s[row], 1e-35f);
    float v = acc[r] * inv + base;
    v = v > 0.f ? v : expm1f(v);
    tempb[((size_t)(b * 512 + i0 + row)) * 256 + n * 32 + d] = f2bf(v);
  }
}

// ---------------------------------------------------------------------------
// Fused fc + kt GEMMs
__global__ __launch_bounds__(256) void fc_kt_kernel(
    const unsigned short* __restrict__ tempb,
    const unsigned short* __restrict__ fcwT,
    const float* __restrict__ fc_b,
    const unsigned short* __restrict__ skw_it,
    const float* __restrict__ skb_it,
    const int* __restrict__ mask,
    const float* __restrict__ resid,
    float* __restrict__ nodes,
    unsigned short* __restrict__ ktb) {
  __shared__ unsigned short tmp[32][264];
  int blk = blockIdx.x;
  int b = blk >> 4;
  int i0 = (blk & 15) << 5;
  int t = threadIdx.x;
  int wv = t >> 6, lane = t & 63;
  int lo = lane & 15, quad = lane >> 4;
  int ch = wv >> 1, rt2 = wv & 1;

  const unsigned short* arow_p = tempb + ((size_t)(b * 512 + i0 + rt2 * 16 + lo)) * 256 + quad * 8;
  f32x4 facc[8] = {};
  for (int k0 = 0; k0 < 256; k0 += 32) {
    bf16x8 a0 = *(const bf16x8*)(arow_p + k0);
#pragma unroll
    for (int ct = 0; ct < 8; ct++) {
      int co = ch * 128 + ct * 16 + lo;
      bf16x8 bf_ = *(const bf16x8*)(fcwT + (size_t)co * 256 + k0 + quad * 8);
      facc[ct] = __builtin_amdgcn_mfma_f32_16x16x32_bf16(a0, bf_, facc[ct], 0, 0, 0);
    }
  }
#pragma unroll
  for (int ct = 0; ct < 8; ct++) {
    int co = ch * 128 + ct * 16 + lo;
    float bv = fc_b[co];
#pragma unroll
    for (int r = 0; r < 4; r++) {
      int row = rt2 * 16 + quad * 4 + r;
      int grow = b * 512 + i0 + row;
      float v = facc[ct][r] + bv;
      v = v > 0.f ? v : 0.01f * v;
      v = (mask[grow] != 0) ? resid[(size_t)grow * 256 + co] + v : 0.f;
      nodes[(size_t)grow * 256 + co] = v;
      tmp[row][co] = f2bf(v);
    }
  }
  __syncthreads();

  f32x4 kacc[8] = {};
  for (int k0 = 0; k0 < 256; k0 += 32) {
    bf16x8 a0 = *(const bf16x8*)&tmp[rt2 * 16 + lo][k0 + quad * 8];
#pragma unroll
    for (int ct = 0; ct < 8; ct++) {
      int co = ch * 128 + ct * 16 + lo;
      bf16x8 bf_ = *(const bf16x8*)(skw_it + (size_t)co * 256 + k0 + quad * 8);
      kacc[ct] = __builtin_amdgcn_mfma_f32_16x16x32_bf16(a0, bf_, kacc[ct], 0, 0, 0);
    }
  }
#pragma unroll
  for (int ct = 0; ct < 8; ct++) {
    int co = ch * 128 + ct * 16 + lo;
    float bv = skb_it[co];
#pragma unroll
    for (int r = 0; r < 4; r++) {
      int row = rt2 * 16 + quad * 4 + r;
      int yrow = b * LP1 + 1 + i0 + row;
      ktb[(size_t)yrow * 256 + co] = f2bf(kacc[ct][r] + bv);
    }
  }
}

// ---------------------------------------------------------------------------
// star attention on bf16 kt; XCD-swizzled
__global__ __launch_bounds__(256) void star_attn_kernel(const float* __restrict__ relay,
                                                        const float* __restrict__ sqT_it,
                                                        const float* __restrict__ sqb_it,
                                                        const unsigned short* __restrict__ ktb,
                                                        const int* __restrict__ mask,
                                                        float* __restrict__ attstar) {
  int n = blockIdx.x >> 4, b = blockIdx.x & 15;
  int t = threadIdx.x;
  int lane = t & 63, w = t >> 6;
  __shared__ float relb[256];
  __shared__ float qv[32];
  __shared__ float pre[LP1];
  __shared__ float red[4];
  __shared__ float par[8][33];
  relb[t] = relay[b * 256 + t];
  __syncthreads();
  {
    int d = t & 31, g = t >> 5;
    float qp = 0.f;
    for (int k = 0; k < 32; k++)
      qp = fmaf(relb[g * 32 + k], sqT_it[(size_t)(g * 32 + k) * 256 + n * 32 + d], qp);
    par[g][d] = qp;
  }
  __syncthreads();
  if (t < 32) {
    float q = 0.f;
#pragma unroll
    for (int gg = 0; gg < 8; gg++) q += par[gg][t];
    qv[t] = q + sqb_it[n * 32 + t];
  }
  __syncthreads();
  const float scale = 0.17677669529663687f;
  for (int l = t; l < LP1; l += 256) {
    bool masked = (l > 0) && (mask[b * LL + l - 1] == 0);
    float p;
    if (masked) p = -3.4e38f;
    else {
      p = 0.f;
      const unsigned short* krow = ktb + ((size_t)b * LP1 + l) * 256 + n * 32;
#pragma unroll
      for (int d = 0; d < 32; d++) p = fmaf(qv[d], bf2f(krow[d]), p);
      p *= scale;
    }
    pre[l] = p;
  }
  __syncthreads();
  float m = -3.4e38f;
  for (int l = t; l < LP1; l += 256) m = fmaxf(m, pre[l]);
#pragma unroll
  for (int o = 32; o; o >>= 1) m = fmaxf(m, __shfl_xor(m, o));
  if (lane == 0) red[w] = m;
  __syncthreads();
  m = fmaxf(fmaxf(red[0], red[1]), fmaxf(red[2], red[3]));
  __syncthreads();
  float s = 0.f;
  for (int l = t; l < LP1; l += 256) {
    float wv = __expf(pre[l] - m);
    pre[l] = wv;
    s += wv;
  }
#pragma unroll
  for (int o = 32; o; o >>= 1) s += __shfl_xor(s, o);
  if (lane == 0) red[w] = s;
  __syncthreads();
  float denom = red[0] + red[1] + red[2] + red[3];
  int d = t & 31, g = t >> 5;
  float acc = 0.f;
  for (int l = g; l < LP1; l += 8)
    acc = fmaf(pre[l], bf2f(ktb[((size_t)b * LP1 + l) * 256 + n * 32 + d]), acc);
  par[g][d] = acc;
  __syncthreads();
  if (t < 32) {
    float a = 0.f;
    for (int gg = 0; gg < 8; gg++) a += par[gg][t];
    attstar[b * 256 + n * 32 + t] = a / denom;
  }
}

// ---------------------------------------------------------------------------
extern "C" void kernel_launch(void* const* d_in, const int* in_sizes, int n_in,
                              void* d_out, int out_size, void* d_ws, size_t ws_size,
                              hipStream_t stream) {
  const float* data  = (const float*)d_in[0];
  const float* WQw   = (const float*)d_in[1];
  const float* WQb   = (const float*)d_in[2];
  const float* a1    = (const float*)d_in[3];
  const float* a2    = (const float*)d_in[4];
  const float* fcw_g = (const float*)d_in[5];
  const float* fcb_g = (const float*)d_in[6];
  const float* ng    = (const float*)d_in[7];
  const float* nb    = (const float*)d_in[8];
  const float* sq_w  = (const float*)d_in[9];
  const float* sq_b  = (const float*)d_in[10];
  const float* sk_w  = (const float*)d_in[11];
  const float* sk_b  = (const float*)d_in[12];
  const float* so_w  = (const float*)d_in[13];
  const float* so_b  = (const float*)d_in[14];
  const float* fc_w  = (const float*)d_in[15];
  const float* fc_b  = (const float*)d_in[16];
  const int*   mask  = (const int*)d_in[17];
  const int*   edge  = (const int*)d_in[18];

  float* nodes = (float*)d_out;
  float* relay = nodes + NODES_ELEMS;

  char* p = (char*)d_ws;
  auto alloc = [&](size_t bytes) -> char* {
    char* r = p; p += (bytes + 255) & ~(size_t)255; return r;
  };
  unsigned short* datab= (unsigned short*)alloc((size_t)8192 * 256 * 2);
  unsigned short* GT   = (unsigned short*)alloc((size_t)8 * 16 * 32 * 512 * 2);
  unsigned short* tmpb = (unsigned short*)alloc((size_t)8192 * 256 * 2);
  unsigned short* ktb  = (unsigned short*)alloc((size_t)8208 * 256 * 2);
  unsigned char* ep    = (unsigned char*)alloc((size_t)8192 * 64);
  float* ei            = (float*)alloc(65536 * 4);
  float* ej            = (float*)alloc(65536 * 4);
  float* ra1           = (float*)alloc(128 * 4);
  float* ra2           = (float*)alloc(128 * 4);
  float* rf            = (float*)alloc(4096 * 4);
  float* bqf           = (float*)alloc(256 * 4);
  float* w1            = (float*)alloc(2048 * 4);
  float* w2            = (float*)alloc(2048 * 4);
  float* c1            = (float*)alloc(8 * 4);
  float* c2            = (float*)alloc(8 * 4);
  float* a1o           = (float*)alloc(2048 * 4);
  float* a2o           = (float*)alloc(2048 * 4);
  float* rpart         = (float*)alloc(128 * 256 * 4);
  unsigned short* Bcat = (unsigned short*)alloc((size_t)288 * 512 * 2);
  unsigned short* fcwT = (unsigned short*)alloc((size_t)65536 * 2);
  unsigned short* skwb = (unsigned short*)alloc((size_t)131072 * 2);
  float* sqT           = (float*)alloc((size_t)131072 * 4);
  float* soT           = (float*)alloc((size_t)131072 * 4);
  float* atts          = (float*)alloc(4096 * 4);

  mega_prep_kernel<<<3162, 256, 0, stream>>>(data, edge, fc_w, fcw_g, sk_w, sq_w,
                                             so_w, WQw, WQb, a1, a2,
                                             datab, ep, fcwT, Bcat, skwb, sqT, soT,
                                             rpart, w1, w2, c1, c2, bqf, a1o, a2o);
  prep2_kernel<<<272, 256, 0, stream>>>(WQw, fcw_g, Bcat, rpart, skwb, sk_b,
                                        a1, a2, fcb_g, bqf, w1, w2, a1o, a2o,
                                        relay, ktb, ra1, ra2, rf);

  for (int it = 0; it < 2; it++) {
    const float* src = (it == 0) ? data : nodes;
    lng_gemm_kernel<<<256, 256, 0, stream>>>(src, datab, Bcat,
                                             ng + it * 256, nb + it * 256,
                                             c1, c2, ra1, ra2, GT, ei, ej);
    gat_agg_kernel<<<NHEAD * BB * 16, 256, 0, stream>>>(GT, ei, ej, ep, rf, tmpb);
    fc_kt_kernel<<<256, 256, 0, stream>>>(tmpb, fcwT, fc_b,
                                          skwb + it * 65536, sk_b + it * 256,
                                          mask, src, nodes, ktb);
    star_attn_kernel<<<BB * NHEAD, 256, 0, stream>>>(relay, sqT + it * 65536,
                                                     sq_b + it * 256, ktb, mask, atts);
    so_rarf_kernel<<<128, 256, 0, stream>>>(atts, soT + it * 65536, so_b + it * 256,
                                            skwb + 65536, sk_b + 256,
                                            a1, a2, fcw_g, fcb_g, bqf,
                                            (it == 0) ? 1 : 0,
                                            relay, ktb, ra1, ra2, rf);
  }
}

// Round 15
// 321.069 us; speedup vs baseline: 1.5176x; 1.0226x over previous
//
#include <hip/hip_runtime.h>
#include <hip/hip_bf16.h>
#include <math.h>

#define BB 16
#define LL 512
#define HH 256
#define NHEAD 8
#define HDIM 32
#define LP1 513
#define NODES_ELEMS (BB*LL*HH)

typedef __attribute__((ext_vector_type(8))) short bf16x8;
typedef __attribute__((ext_vector_type(4))) float f32x4;

__device__ __forceinline__ unsigned short f2bf(float f) {
  union { float f; unsigned u; } x; x.f = f;
  unsigned r = x.u + 0x7fffu + ((x.u >> 16) & 1u);
  return (unsigned short)(r >> 16);
}
__device__ __forceinline__ float bf2f(unsigned short u) {
  union { unsigned u; float f; } x; x.u = (unsigned)u << 16; return x.f;
}

// ---------------------------------------------------------------------------
// MEGA-PREP (3162 blocks); edge pack: bit u <-> col lane*8+u (vector-friendly)
__global__ __launch_bounds__(256) void mega_prep_kernel(
    const float* __restrict__ data, const int* __restrict__ edge,
    const float* __restrict__ fc_w, const float* __restrict__ fcw,
    const float* __restrict__ sk_w, const float* __restrict__ sq_w,
    const float* __restrict__ so_w, const float* __restrict__ WQw,
    const float* __restrict__ WQb, const float* __restrict__ a1,
    const float* __restrict__ a2,
    unsigned short* __restrict__ datab, unsigned char* __restrict__ ep,
    unsigned short* __restrict__ fcwT, unsigned short* __restrict__ Bcat,
    unsigned short* __restrict__ skwb, float* __restrict__ sqT,
    float* __restrict__ soT, float* __restrict__ rpart,
    float* __restrict__ w1, float* __restrict__ w2,
    float* __restrict__ c1, float* __restrict__ c2,
    float* __restrict__ bqf, float* __restrict__ a1o, float* __restrict__ a2o) {
  __shared__ float smem[64 * 65];
  int blk = blockIdx.x, t = threadIdx.x;
  if (blk < 128) {
    int b = blk >> 3, ch = blk & 7;
    const float* pr = data + ((size_t)b * 512 + ch * 64) * 256 + t;
    unsigned short* db = datab + ((size_t)b * 512 + ch * 64) * 256 + t;
    float s = 0.f;
    for (int l = 0; l < 64; l++) {
      float v = pr[(size_t)l * 256];
      db[(size_t)l * 256] = f2bf(v);
      s += v;
    }
    rpart[(size_t)blk * 256 + t] = s;
  } else if (blk < 2176) {
    int row = (blk - 128) * 4 + (t >> 6);
    int lane = t & 63;
    const int* adj = edge + ((size_t)row << 9) + lane * 8;
    unsigned v = 0;
#pragma unroll
    for (int u = 0; u < 8; u++) v |= (adj[u] > 0 ? 1u : 0u) << u;
    ep[((size_t)row << 6) + lane] = (unsigned char)v;
  } else if (blk < 2432) {
    int idx = (blk - 2176) * 256 + t;
    int d = idx & 31;
    int g = idx >> 5;
    int n = g >> 8, c = g & 255;
    Bcat[((size_t)n * 32 + d) * 512 + 256 + c] =
        f2bf(fcw[((size_t)n * 768 + 256 + 2 * c) * 32 + d]);
  } else if (blk < 2944) {
    int idx = (blk - 2432) * 256 + t;
    skwb[idx] = f2bf(sk_w[idx]);
  } else if (blk < 3024) {
    int q = blk - 2944;
    int mat = q >> 4, tl = q & 15;
    int r0 = (tl >> 2) * 64, c0 = (tl & 3) * 64;
    const float* in;
    if (mat == 0) in = fc_w;
    else if (mat <= 2) in = sq_w + (mat - 1) * 65536;
    else in = so_w + (mat - 3) * 65536;
    int cc = t & 63, rq = t >> 6;
#pragma unroll
    for (int i = 0; i < 16; i++) {
      int r = rq + i * 4;
      smem[r * 65 + cc] = in[(r0 + r) * 256 + c0 + cc];
    }
    __syncthreads();
#pragma unroll
    for (int i = 0; i < 16; i++) {
      int cp = rq + i * 4;
      float v = smem[cc * 65 + cp];
      if (mat == 0) fcwT[(c0 + cp) * 256 + r0 + cc] = f2bf(v);
      else if (mat <= 2) sqT[(mat - 1) * 65536 + (c0 + cp) * 256 + r0 + cc] = v;
      else soT[(mat - 3) * 65536 + (c0 + cp) * 256 + r0 + cc] = v;
    }
  } else if (blk < 3152) {
    int q = blk - 3024;
    int n = q >> 4, kc = q & 15;
    int k = kc * 16 + (t & 15), cseg = t >> 4;
    float s1 = 0.f, s2 = 0.f;
#pragma unroll
    for (int u = 0; u < 16; u++) {
      int c = cseg * 16 + u;
      float wv = WQw[((size_t)(n * 256 + c)) * 256 + k];
      s1 = fmaf(a1[n * 768 + c], wv, s1);
      s2 = fmaf(a2[n * 768 + c], wv, s2);
    }
    smem[cseg * 16 + (t & 15)] = s1;
    smem[256 + cseg * 16 + (t & 15)] = s2;
    __syncthreads();
    if (cseg == 0) {
      float a = 0.f, b2 = 0.f;
#pragma unroll
      for (int u = 0; u < 16; u++) {
        a += smem[u * 16 + (t & 15)];
        b2 += smem[256 + u * 16 + (t & 15)];
      }
      w1[n * 256 + k] = a;
      w2[n * 256 + k] = b2;
    }
  } else if (blk < 3160) {
    int n = blk - 3152;
    int d = t & 31, seg = t >> 5;
    float s = 0.f;
#pragma unroll
    for (int u = 0; u < 32; u++) {
      int c = seg * 32 + u;
      s = fmaf(WQb[n * 256 + c], fcw[((size_t)n * 768 + c) * 32 + d], s);
    }
    smem[seg * 32 + d] = s;
    __syncthreads();
    if (seg == 0) {
      float a = 0.f;
#pragma unroll
      for (int u = 0; u < 8; u++) a += smem[u * 32 + d];
      bqf[n * 32 + d] = a;
    }
  } else if (blk == 3160) {
    int n = t >> 5, sl = t & 31;
    float s1 = 0.f, s2 = 0.f;
#pragma unroll
    for (int u = 0; u < 8; u++) {
      int c = sl * 8 + u;
      float wb = WQb[n * 256 + c];
      s1 = fmaf(a1[n * 768 + c], wb, s1);
      s2 = fmaf(a2[n * 768 + c], wb, s2);
    }
    smem[t] = s1; smem[256 + t] = s2;
    __syncthreads();
    if (sl == 0) {
      float a = 0.f, b2 = 0.f;
      for (int u = 0; u < 32; u++) { a += smem[n * 32 + u]; b2 += smem[256 + n * 32 + u]; }
      c1[n] = a; c2[n] = b2;
    }
  } else {
#pragma unroll
    for (int n = 0; n < 8; n++) {
      a1o[n * 256 + t] = a1[n * 768 + 256 + 2 * t];
      a2o[n * 256 + t] = a2[n * 768 + 256 + 2 * t];
    }
  }
}

// ---------------------------------------------------------------------------
__device__ __forceinline__ void rarf_tail(
    int n, int b, int t, const float* rel,
    const float* __restrict__ a1, const float* __restrict__ a2,
    const float* __restrict__ fcw, const float* __restrict__ fcb,
    const float* __restrict__ bqf,
    float* __restrict__ ra1, float* __restrict__ ra2, float* __restrict__ rf,
    float* red1, float* red2, float* pf_s) {
  int lane = t & 63, w = t >> 6;
  float p1 = rel[t] * a1[n * 768 + 257 + 2 * t];
  float p2 = rel[t] * a2[n * 768 + 257 + 2 * t];
#pragma unroll
  for (int o = 32; o; o >>= 1) { p1 += __shfl_xor(p1, o); p2 += __shfl_xor(p2, o); }
  if (lane == 0) { red1[w] = p1; red2[w] = p2; }
  int d = t & 31, seg = t >> 5;
  float pf = 0.f;
  for (int u = 0; u < 32; u++) {
    int k = seg * 32 + u;
    pf = fmaf(rel[k], fcw[((size_t)n * 768 + 257 + 2 * k) * 32 + d], pf);
  }
  pf_s[seg * 33 + d] = pf;
  __syncthreads();
  if (t == 0) {
    ra1[n * 16 + b] = red1[0] + red1[1] + red1[2] + red1[3];
    ra2[n * 16 + b] = red2[0] + red2[1] + red2[2] + red2[3];
  }
  if (t < 32) {
    float s = 0.f;
    for (int gg = 0; gg < 8; gg++) s += pf_s[gg * 33 + t];
    rf[((size_t)n * 16 + b) * 32 + t] = s + fcb[n * 32 + t] + bqf[n * 32 + t];
  }
}

// ---------------------------------------------------------------------------
// prep2 (272 blocks): 0-127 Bcat M1 | 128-255 relay+rarf | 256-271 ei/ej cols
__global__ __launch_bounds__(256) void prep2_kernel(
    const float* __restrict__ WQw, const float* __restrict__ fcw,
    unsigned short* __restrict__ Bcat,
    const float* __restrict__ rpart,
    const unsigned short* __restrict__ skw0, const float* __restrict__ skb0,
    const float* __restrict__ a1, const float* __restrict__ a2,
    const float* __restrict__ fcb, const float* __restrict__ bqf,
    const float* __restrict__ w1, const float* __restrict__ w2,
    const float* __restrict__ a1o, const float* __restrict__ a2o,
    float* __restrict__ relay, unsigned short* __restrict__ ktb,
    float* __restrict__ ra1, float* __restrict__ ra2, float* __restrict__ rf) {
  __shared__ float smem[12288];
  int blk = blockIdx.x, t = threadIdx.x;
  if (blk < 128) {
    float* wq_s = smem;
    float* fw_s = smem + 4096;
    int n = blk >> 4, kt = blk & 15;
#pragma unroll
    for (int i = 0; i < 16; i++) {
      int c = i * 16 + (t >> 4), kk = t & 15;
      wq_s[c * 16 + kk] = WQw[(size_t)n * 65536 + c * 256 + kt * 16 + kk];
    }
#pragma unroll
    for (int i = 0; i < 32; i++) {
      int idx = i * 256 + t;
      fw_s[(idx >> 5) * 32 + (idx & 31)] = fcw[(size_t)n * 24576 + idx];
    }
    __syncthreads();
    int kloc = t >> 4, dp = t & 15;
    float a0 = 0.f, a1v = 0.f;
    for (int c = 0; c < 256; c++) {
      float wv = wq_s[c * 16 + kloc];
      a0 = fmaf(wv, fw_s[c * 32 + dp * 2], a0);
      a1v = fmaf(wv, fw_s[c * 32 + dp * 2 + 1], a1v);
    }
    int k = kt * 16 + kloc;
    Bcat[((size_t)n * 32 + dp * 2) * 512 + k] = f2bf(a0);
    Bcat[((size_t)n * 32 + dp * 2 + 1) * 512 + k] = f2bf(a1v);
  } else if (blk < 256) {
    float* rel = smem;
    float* red1 = smem + 256;
    float* red2 = smem + 264;
    float* pf_s = smem + 272;
    int id = blk - 128;
    int n = id >> 4, b = id & 15;
    float s = 0.f;
#pragma unroll
    for (int ch = 0; ch < 8; ch++) s += rpart[((size_t)(b * 8 + ch)) * 256 + t];
    s *= (1.0f / 512.0f);
    rel[t] = s;
    __syncthreads();
    if (n == 0) {
      relay[b * 256 + t] = s;
      float acc = 0.f;
      for (int k = 0; k < 256; k++) acc = fmaf(rel[k], bf2f(skw0[(size_t)t * 256 + k]), acc);
      ktb[((size_t)b * LP1) * 256 + t] = f2bf(acc + skb0[t]);
    }
    rarf_tail(n, b, t, rel, a1, a2, fcw, fcb, bqf, ra1, ra2, rf, red1, red2, pf_s);
  } else {
    int q = blk - 256;
    int n = q & 7, isEj = q >> 3;
    const float* wsrc = isEj ? w2 : w1;
    const float* asrc = isEj ? a2o : a1o;
#pragma unroll
    for (int h = 0; h < 2; h++) {
      int k = h * 256 + t;
      float v = (k < 256) ? wsrc[n * 256 + k] : asrc[n * 256 + k - 256];
      Bcat[((size_t)(256 + q)) * 512 + k] = f2bf(v);
    }
  }
}

// relay = lrelu(atts @ soT + sob) (+ ktb row + rarf extras when do_extras)
__global__ __launch_bounds__(256) void so_rarf_kernel(
    const float* __restrict__ atts,
    const float* __restrict__ soT_it, const float* __restrict__ sob_it,
    const unsigned short* __restrict__ skw_nx, const float* __restrict__ skb_nx,
    const float* __restrict__ a1, const float* __restrict__ a2,
    const float* __restrict__ fcw, const float* __restrict__ fcb,
    const float* __restrict__ bqf, int do_extras,
    float* __restrict__ relay, unsigned short* __restrict__ ktb,
    float* __restrict__ ra1, float* __restrict__ ra2, float* __restrict__ rf) {
  int n = blockIdx.x >> 4, b = blockIdx.x & 15;
  if (!do_extras && n > 0) return;
  __shared__ float xr[256];
  __shared__ float rel[256];
  __shared__ float red1[4], red2[4];
  __shared__ float pf_s[8 * 33];
  int t = threadIdx.x;
  xr[t] = atts[b * 256 + t];
  __syncthreads();
  float acc = 0.f;
  for (int k = 0; k < 256; k++) acc = fmaf(xr[k], soT_it[(size_t)k * 256 + t], acc);
  float v = acc + sob_it[t];
  v = v > 0.f ? v : 0.01f * v;
  rel[t] = v;
  __syncthreads();
  if (n == 0) relay[b * 256 + t] = v;
  if (!do_extras) return;
  if (n == 0) {
    float a2v = 0.f;
    for (int k = 0; k < 256; k++) a2v = fmaf(rel[k], bf2f(skw_nx[(size_t)t * 256 + k]), a2v);
    ktb[((size_t)b * LP1) * 256 + t] = f2bf(a2v + skb_nx[t]);
  }
  rarf_tail(n, b, t, rel, a1, a2, fcw, fcb, bqf, ra1, ra2, rf, red1, red2, pf_s);
}

// ---------------------------------------------------------------------------
// LNG-GEMM: fused LN + [xn;data] @ Bcat(272) -> GT + ei/ej
// XCD-swizzled: b = blk&15 (siblings of b share XCD b%8)
__global__ __launch_bounds__(256) void lng_gemm_kernel(
    const float* __restrict__ src,
    const unsigned short* __restrict__ datab,
    const unsigned short* __restrict__ Bcat,
    const float* __restrict__ g, const float* __restrict__ bb,
    const float* __restrict__ c1, const float* __restrict__ c2,
    const float* __restrict__ ra1, const float* __restrict__ ra2,
    unsigned short* __restrict__ GT,
    float* __restrict__ ei, float* __restrict__ ej) {
  __shared__ unsigned short A[32][520];
  int blk = blockIdx.x;
  int b = blk & 15;
  int i0 = (blk >> 4) << 5;
  int t = threadIdx.x;
  int wv = t >> 6, lane = t & 63;
  int lo = lane & 15, quad = lane >> 4;

  float4 g4 = *(const float4*)(g + lane * 4);
  float4 b4 = *(const float4*)(bb + lane * 4);
  float xs[8][4];
  float sum[8], sq[8];
#pragma unroll
  for (int rr = 0; rr < 8; rr++) {
    int grow = b * 512 + i0 + wv * 8 + rr;
    float4 v = *(const float4*)(src + (size_t)grow * 256 + lane * 4);
    xs[rr][0] = v.x; xs[rr][1] = v.y; xs[rr][2] = v.z; xs[rr][3] = v.w;
    sum[rr] = v.x + v.y + v.z + v.w;
    sq[rr] = v.x * v.x + v.y * v.y + v.z * v.z + v.w * v.w;
    ushort4 dv4 = *(const ushort4*)(datab + (size_t)grow * 256 + lane * 4);
    *(ushort4*)&A[wv * 8 + rr][256 + lane * 4] = dv4;
  }
#pragma unroll
  for (int o = 32; o; o >>= 1) {
#pragma unroll
    for (int rr = 0; rr < 8; rr++) {
      sum[rr] += __shfl_xor(sum[rr], o);
      sq[rr] += __shfl_xor(sq[rr], o);
    }
  }
#pragma unroll
  for (int rr = 0; rr < 8; rr++) {
    float mean = sum[rr] * (1.0f / 256.0f);
    float var = sq[rr] * (1.0f / 256.0f) - mean * mean;
    float rstd = rsqrtf(var + 1e-5f);
    ushort4 pk;
    pk.x = f2bf((xs[rr][0] - mean) * rstd * g4.x + b4.x);
    pk.y = f2bf((xs[rr][1] - mean) * rstd * g4.y + b4.y);
    pk.z = f2bf((xs[rr][2] - mean) * rstd * g4.z + b4.z);
    pk.w = f2bf((xs[rr][3] - mean) * rstd * g4.w + b4.w);
    *(ushort4*)&A[wv * 8 + rr][lane * 4] = pk;
  }
  __syncthreads();

  f32x4 acc[2][4] = {};
  f32x4 acce[2] = {};
  for (int k0 = 0; k0 < 512; k0 += 32) {
    bf16x8 af[2];
#pragma unroll
    for (int rt = 0; rt < 2; rt++)
      af[rt] = *(const bf16x8*)&A[rt * 16 + lo][k0 + quad * 8];
#pragma unroll
    for (int j = 0; j < 4; j++) {
      int tile = j * 4 + wv;
      bf16x8 bf_ = *(const bf16x8*)(Bcat + (size_t)(tile * 16 + lo) * 512 + k0 + quad * 8);
#pragma unroll
      for (int rt = 0; rt < 2; rt++)
        acc[rt][j] = __builtin_amdgcn_mfma_f32_16x16x32_bf16(af[rt], bf_, acc[rt][j], 0, 0, 0);
    }
    if (wv == 0) {
      bf16x8 bf_ = *(const bf16x8*)(Bcat + (size_t)(256 + lo) * 512 + k0 + quad * 8);
#pragma unroll
      for (int rt = 0; rt < 2; rt++)
        acce[rt] = __builtin_amdgcn_mfma_f32_16x16x32_bf16(af[rt], bf_, acce[rt], 0, 0, 0);
    }
  }
#pragma unroll
  for (int j = 0; j < 4; j++) {
    int tile = j * 4 + wv;
    int co = tile * 16 + lo;
    int n = co >> 5, d = co & 31;
#pragma unroll
    for (int rt = 0; rt < 2; rt++) {
      int jj = i0 + rt * 16 + quad * 4;
      ushort4 pk;
      pk.x = f2bf(acc[rt][j][0]);
      pk.y = f2bf(acc[rt][j][1]);
      pk.z = f2bf(acc[rt][j][2]);
      pk.w = f2bf(acc[rt][j][3]);
      *(ushort4*)&GT[(((size_t)(n * 16 + b) * 32 + d) << 9) + jj] = pk;
    }
  }
  if (wv == 0) {
    int n = lo & 7, isEj = lo >> 3;
    float cst = isEj ? (c2[n] + ra2[n * 16 + b]) : (c1[n] + ra1[n * 16 + b]);
    float* outp = isEj ? ej : ei;
#pragma unroll
    for (int rt = 0; rt < 2; rt++) {
#pragma unroll
      for (int r = 0; r < 4; r++) {
        int row = i0 + rt * 16 + quad * 4 + r;
        outp[n * 8192 + b * 512 + row] = acce[rt][r] + cst;
      }
    }
  }
}

// ---------------------------------------------------------------------------
// GAT: reduction-free softmax + MFMA aggregation; XCD-swizzled; vector Phase A
__global__ __launch_bounds__(256) void gat_agg_kernel(
    const unsigned short* __restrict__ GT,
    const float* __restrict__ ei, const float* __restrict__ ej,
    const unsigned char* __restrict__ ep,     // bit u <-> col lane*8+u
    const float* __restrict__ rf,
    unsigned short* __restrict__ tempb) {
  __shared__ unsigned short W[32][512];
  __shared__ float denom_s[32];
  int blk = blockIdx.x;
  int sib = blk >> 7;
  int g = blk & 127;
  int n = g >> 4;
  int b = g & 15;
  int i0 = sib << 5;
  int t = threadIdx.x;
  int wv = t >> 6, lane = t & 63;
  int lo = lane & 15, quad = lane >> 4;

  const float* ejrow = ej + n * 8192 + b * 512;
  float ejv[8];
  {
    float4 e0 = *(const float4*)(ejrow + lane * 8);
    float4 e1 = *(const float4*)(ejrow + lane * 8 + 4);
    ejv[0] = e0.x; ejv[1] = e0.y; ejv[2] = e0.z; ejv[3] = e0.w;
    ejv[4] = e1.x; ejv[5] = e1.y; ejv[6] = e1.z; ejv[7] = e1.w;
  }
  float mm = ejv[0];
#pragma unroll
  for (int u = 1; u < 8; u++) mm = fmaxf(mm, ejv[u]);
#pragma unroll
  for (int o = 32; o; o >>= 1) mm = fmaxf(mm, __shfl_xor(mm, o));

  for (int rr = 0; rr < 8; rr++) {
    int row = wv * 8 + rr;
    float eiv = ei[n * 8192 + b * 512 + i0 + row];
    float M = eiv + mm;
    M = M > 0.f ? M : 0.2f * M;
    unsigned pbv = ep[(((size_t)(b * 512 + i0 + row)) << 6) + lane];
    bf16x8 wpack;
#pragma unroll
    for (int u = 0; u < 8; u++) {
      float e = eiv + ejv[u];
      e = e > 0.f ? e : 0.2f * e;
      float w = ((pbv >> u) & 1) ? __expf(e - M) : 0.f;
      wpack[u] = (short)f2bf(w);
    }
    *(bf16x8*)&W[row][(lane ^ (row & 7)) << 3] = wpack;
  }
  __syncthreads();

  int rt = wv >> 1, dh = wv & 1;
  int arow = rt * 16 + lo;
  int rx = arow & 7;
  const unsigned short* gtb = GT + (((size_t)(n * 16 + b) * 32) << 9);
  bf16x8 bones;
  {
    short ov = (lo == 0) ? (short)0x3F80 : (short)0;
#pragma unroll
    for (int j = 0; j < 8; j++) bones[j] = ov;
  }
  f32x4 acc = {}, accd = {};
  for (int k0 = 0; k0 < 512; k0 += 32) {
    int chunk = (k0 >> 3) + quad;
    bf16x8 a0 = *(const bf16x8*)&W[arow][(chunk ^ rx) << 3];
    bf16x8 bf_ = *(const bf16x8*)(gtb + (((size_t)(dh * 16 + lo)) << 9) + k0 + quad * 8);
    acc = __builtin_amdgcn_mfma_f32_16x16x32_bf16(a0, bf_, acc, 0, 0, 0);
    if (dh == 0)
      accd = __builtin_amdgcn_mfma_f32_16x16x32_bf16(a0, bones, accd, 0, 0, 0);
  }
  if (dh == 0 && lo == 0) {
#pragma unroll
    for (int r = 0; r < 4; r++) denom_s[rt * 16 + quad * 4 + r] = accd[r];
  }
  __syncthreads();
  int d = dh * 16 + lo;
  float base = rf[((size_t)n * 16 + b) * 32 + d];
#pragma unroll
  for (int r = 0; r < 4; r++) {
    int row = rt * 16 + quad * 4 + r;
    float inv = 1.0f / fmaxf(denom_s[row], 1e-35f);
    float v = acc[r] * inv + base;
    v = v > 0.f ? v : expm1f(v);
    tempb[((size_t)(b * 512 + i0 + row)) * 256 + n * 32 + d] = f2bf(v);
  }
}

// ---------------------------------------------------------------------------
// Fused fc + kt GEMMs; XCD-swizzled: b = blk&15
__global__ __launch_bounds__(256) void fc_kt_kernel(
    const unsigned short* __restrict__ tempb,
    const unsigned short* __restrict__ fcwT,
    const float* __restrict__ fc_b,
    const unsigned short* __restrict__ skw_it,
    const float* __restrict__ skb_it,
    const int* __restrict__ mask,
    const float* __restrict__ resid,
    float* __restrict__ nodes,
    unsigned short* __restrict__ ktb) {
  __shared__ unsigned short tmp[32][264];
  int blk = blockIdx.x;
  int b = blk & 15;
  int i0 = (blk >> 4) << 5;
  int t = threadIdx.x;
  int wv = t >> 6, lane = t & 63;
  int lo = lane & 15, quad = lane >> 4;
  int ch = wv >> 1, rt2 = wv & 1;

  const unsigned short* arow_p = tempb + ((size_t)(b * 512 + i0 + rt2 * 16 + lo)) * 256 + quad * 8;
  f32x4 facc[8] = {};
  for (int k0 = 0; k0 < 256; k0 += 32) {
    bf16x8 a0 = *(const bf16x8*)(arow_p + k0);
#pragma unroll
    for (int ct = 0; ct < 8; ct++) {
      int co = ch * 128 + ct * 16 + lo;
      bf16x8 bf_ = *(const bf16x8*)(fcwT + (size_t)co * 256 + k0 + quad * 8);
      facc[ct] = __builtin_amdgcn_mfma_f32_16x16x32_bf16(a0, bf_, facc[ct], 0, 0, 0);
    }
  }
#pragma unroll
  for (int ct = 0; ct < 8; ct++) {
    int co = ch * 128 + ct * 16 + lo;
    float bv = fc_b[co];
#pragma unroll
    for (int r = 0; r < 4; r++) {
      int row = rt2 * 16 + quad * 4 + r;
      int grow = b * 512 + i0 + row;
      float v = facc[ct][r] + bv;
      v = v > 0.f ? v : 0.01f * v;
      v = (mask[grow] != 0) ? resid[(size_t)grow * 256 + co] + v : 0.f;
      nodes[(size_t)grow * 256 + co] = v;
      tmp[row][co] = f2bf(v);
    }
  }
  __syncthreads();

  f32x4 kacc[8] = {};
  for (int k0 = 0; k0 < 256; k0 += 32) {
    bf16x8 a0 = *(const bf16x8*)&tmp[rt2 * 16 + lo][k0 + quad * 8];
#pragma unroll
    for (int ct = 0; ct < 8; ct++) {
      int co = ch * 128 + ct * 16 + lo;
      bf16x8 bf_ = *(const bf16x8*)(skw_it + (size_t)co * 256 + k0 + quad * 8);
      kacc[ct] = __builtin_amdgcn_mfma_f32_16x16x32_bf16(a0, bf_, kacc[ct], 0, 0, 0);
    }
  }
#pragma unroll
  for (int ct = 0; ct < 8; ct++) {
    int co = ch * 128 + ct * 16 + lo;
    float bv = skb_it[co];
#pragma unroll
    for (int r = 0; r < 4; r++) {
      int row = rt2 * 16 + quad * 4 + r;
      int yrow = b * LP1 + 1 + i0 + row;
      ktb[(size_t)yrow * 256 + co] = f2bf(kacc[ct][r] + bv);
    }
  }
}

// ---------------------------------------------------------------------------
// star attention on bf16 kt; XCD-swizzled; vectorized k loads
__global__ __launch_bounds__(256) void star_attn_kernel(const float* __restrict__ relay,
                                                        const float* __restrict__ sqT_it,
                                                        const float* __restrict__ sqb_it,
                                                        const unsigned short* __restrict__ ktb,
                                                        const int* __restrict__ mask,
                                                        float* __restrict__ attstar) {
  int n = blockIdx.x >> 4, b = blockIdx.x & 15;
  int t = threadIdx.x;
  int lane = t & 63, w = t >> 6;
  __shared__ float relb[256];
  __shared__ float qv[32];
  __shared__ float pre[LP1];
  __shared__ float red[4];
  __shared__ float par[8][33];
  relb[t] = relay[b * 256 + t];
  __syncthreads();
  {
    int d = t & 31, g = t >> 5;
    float qp = 0.f;
    for (int k = 0; k < 32; k++)
      qp = fmaf(relb[g * 32 + k], sqT_it[(size_t)(g * 32 + k) * 256 + n * 32 + d], qp);
    par[g][d] = qp;
  }
  __syncthreads();
  if (t < 32) {
    float q = 0.f;
#pragma unroll
    for (int gg = 0; gg < 8; gg++) q += par[gg][t];
    qv[t] = q + sqb_it[n * 32 + t];
  }
  __syncthreads();
  const float scale = 0.17677669529663687f;
  for (int l = t; l < LP1; l += 256) {
    bool masked = (l > 0) && (mask[b * LL + l - 1] == 0);
    float p;
    if (masked) p = -3.4e38f;
    else {
      p = 0.f;
      const bf16x8* krow8 = (const bf16x8*)(ktb + ((size_t)b * LP1 + l) * 256 + n * 32);
#pragma unroll
      for (int dd = 0; dd < 4; dd++) {
        bf16x8 kv = krow8[dd];
#pragma unroll
        for (int j = 0; j < 8; j++)
          p = fmaf(qv[dd * 8 + j], bf2f((unsigned short)kv[j]), p);
      }
      p *= scale;
    }
    pre[l] = p;
  }
  __syncthreads();
  float m = -3.4e38f;
  for (int l = t; l < LP1; l += 256) m = fmaxf(m, pre[l]);
#pragma unroll
  for (int o = 32; o; o >>= 1) m = fmaxf(m, __shfl_xor(m, o));
  if (lane == 0) red[w] = m;
  __syncthreads();
  m = fmaxf(fmaxf(red[0], red[1]), fmaxf(red[2], red[3]));
  __syncthreads();
  float s = 0.f;
  for (int l = t; l < LP1; l += 256) {
    float wv = __expf(pre[l] - m);
    pre[l] = wv;
    s += wv;
  }
#pragma unroll
  for (int o = 32; o; o >>= 1) s += __shfl_xor(s, o);
  if (lane == 0) red[w] = s;
  __syncthreads();
  float denom = red[0] + red[1] + red[2] + red[3];
  int d = t & 31, g = t >> 5;
  float acc = 0.f;
  for (int l = g; l < LP1; l += 8)
    acc = fmaf(pre[l], bf2f(ktb[((size_t)b * LP1 + l) * 256 + n * 32 + d]), acc);
  par[g][d] = acc;
  __syncthreads();
  if (t < 32) {
    float a = 0.f;
    for (int gg = 0; gg < 8; gg++) a += par[gg][t];
    attstar[b * 256 + n * 32 + t] = a / denom;
  }
}

// ---------------------------------------------------------------------------
extern "C" void kernel_launch(void* const* d_in, const int* in_sizes, int n_in,
                              void* d_out, int out_size, void* d_ws, size_t ws_size,
                              hipStream_t stream) {
  const float* data  = (const float*)d_in[0];
  const float* WQw   = (const float*)d_in[1];
  const float* WQb   = (const float*)d_in[2];
  const float* a1    = (const float*)d_in[3];
  const float* a2    = (const float*)d_in[4];
  const float* fcw_g = (const float*)d_in[5];
  const float* fcb_g = (const float*)d_in[6];
  const float* ng    = (const float*)d_in[7];
  const float* nb    = (const float*)d_in[8];
  const float* sq_w  = (const float*)d_in[9];
  const float* sq_b  = (const float*)d_in[10];
  const float* sk_w  = (const float*)d_in[11];
  const float* sk_b  = (const float*)d_in[12];
  const float* so_w  = (const float*)d_in[13];
  const float* so_b  = (const float*)d_in[14];
  const float* fc_w  = (const float*)d_in[15];
  const float* fc_b  = (const float*)d_in[16];
  const int*   mask  = (const int*)d_in[17];
  const int*   edge  = (const int*)d_in[18];

  float* nodes = (float*)d_out;
  float* relay = nodes + NODES_ELEMS;

  char* p = (char*)d_ws;
  auto alloc = [&](size_t bytes) -> char* {
    char* r = p; p += (bytes + 255) & ~(size_t)255; return r;
  };
  unsigned short* datab= (unsigned short*)alloc((size_t)8192 * 256 * 2);
  unsigned short* GT   = (unsigned short*)alloc((size_t)8 * 16 * 32 * 512 * 2);
  unsigned short* tmpb = (unsigned short*)alloc((size_t)8192 * 256 * 2);
  unsigned short* ktb  = (unsigned short*)alloc((size_t)8208 * 256 * 2);
  unsigned char* ep    = (unsigned char*)alloc((size_t)8192 * 64);
  float* ei            = (float*)alloc(65536 * 4);
  float* ej            = (float*)alloc(65536 * 4);
  float* ra1           = (float*)alloc(128 * 4);
  float* ra2           = (float*)alloc(128 * 4);
  float* rf            = (float*)alloc(4096 * 4);
  float* bqf           = (float*)alloc(256 * 4);
  float* w1            = (float*)alloc(2048 * 4);
  float* w2            = (float*)alloc(2048 * 4);
  float* c1            = (float*)alloc(8 * 4);
  float* c2            = (float*)alloc(8 * 4);
  float* a1o           = (float*)alloc(2048 * 4);
  float* a2o           = (float*)alloc(2048 * 4);
  float* rpart         = (float*)alloc(128 * 256 * 4);
  unsigned short* Bcat = (unsigned short*)alloc((size_t)288 * 512 * 2);
  unsigned short* fcwT = (unsigned short*)alloc((size_t)65536 * 2);
  unsigned short* skwb = (unsigned short*)alloc((size_t)131072 * 2);
  float* sqT           = (float*)alloc((size_t)131072 * 4);
  float* soT           = (float*)alloc((size_t)131072 * 4);
  float* atts          = (float*)alloc(4096 * 4);

  mega_prep_kernel<<<3162, 256, 0, stream>>>(data, edge, fc_w, fcw_g, sk_w, sq_w,
                                             so_w, WQw, WQb, a1, a2,
                                             datab, ep, fcwT, Bcat, skwb, sqT, soT,
                                             rpart, w1, w2, c1, c2, bqf, a1o, a2o);
  prep2_kernel<<<272, 256, 0, stream>>>(WQw, fcw_g, Bcat, rpart, skwb, sk_b,
                                        a1, a2, fcb_g, bqf, w1, w2, a1o, a2o,
                                        relay, ktb, ra1, ra2, rf);

  for (int it = 0; it < 2; it++) {
    const float* src = (it == 0) ? data : nodes;
    lng_gemm_kernel<<<256, 256, 0, stream>>>(src, datab, Bcat,
                                             ng + it * 256, nb + it * 256,
                                             c1, c2, ra1, ra2, GT, ei, ej);
    gat_agg_kernel<<<NHEAD * BB * 16, 256, 0, stream>>>(GT, ei, ej, ep, rf, tmpb);
    fc_kt_kernel<<<256, 256, 0, stream>>>(tmpb, fcwT, fc_b,
                                          skwb + it * 65536, sk_b + it * 256,
                                          mask, src, nodes, ktb);
    star_attn_kernel<<<BB * NHEAD, 256, 0, stream>>>(relay, sqT + it * 65536,
                                                     sq_b + it * 256, ktb, mask, atts);
    so_rarf_kernel<<<128, 256, 0, stream>>>(atts, soT + it * 65536, so_b + it * 256,
                                            skwb + 65536, sk_b + 256,
                                            a1, a2, fcw_g, fcb_g, bqf,
                                            (it == 0) ? 1 : 0,
                                            relay, ktb, ra1, ra2, rf);
  }
}